// Round 13
// baseline (382.155 us; speedup 1.0000x reference)
//
#include <hip/hip_runtime.h>
#include <hip/hip_bf16.h>

typedef __attribute__((ext_vector_type(8))) short short8;
typedef __attribute__((ext_vector_type(4))) short short4v;
typedef __attribute__((ext_vector_type(4))) float f32x4;
typedef unsigned short u16;

#define T_ 4096
#define D_ 1024
#define ISSL2E (0.08838834764831845f * 1.4426950408889634f)   // 1/sqrt(128) * log2(e)

__device__ __forceinline__ u16 f2bf(float f) {
  union { float f; unsigned u; } v; v.f = f;
  unsigned r = v.u + 0x7FFFu + ((v.u >> 16) & 1u);
  return (u16)(r >> 16);
}

// ---------- fused prep: pooling + weight transposes + irfft, ONE launch ----------
__global__ __launch_bounds__(256) void prep_all(const float* __restrict__ x,
    const float* __restrict__ Wq, const float* __restrict__ Wk, const float* __restrict__ Wv,
    const float* __restrict__ rW1, const float* __restrict__ Wout, const float* __restrict__ bg,
    u16* __restrict__ p1, u16* __restrict__ p2, u16* __restrict__ p4, u16* __restrict__ p8,
    u16* __restrict__ wqT, u16* __restrict__ kvT, u16* __restrict__ rw1T, u16* __restrict__ woutT,
    u16* __restrict__ crep) {
  const int blk = blockIdx.x;
  const int tid = threadIdx.x;
  if (blk < 1024) {                          // ---- pooling ----
    const int b = blk >> 9, t0 = (blk & 511) << 3;
    const float* src = x + ((long)b * T_ + t0) * D_;
#pragma unroll
    for (int j = 0; j < 4; ++j) {
      const int c = tid + j * 256;
      float v[8];
#pragma unroll
      for (int r = 0; r < 8; ++r) v[r] = src[r * D_ + c];
#pragma unroll
      for (int r = 0; r < 8; ++r) p1[((long)b * 4096 + t0 + r) * D_ + c] = f2bf(v[r]);
#pragma unroll
      for (int r = 0; r < 4; ++r)
        p2[((long)b * 2048 + (t0 >> 1) + r) * D_ + c] = f2bf((v[2*r] + v[2*r+1]) * 0.5f);
#pragma unroll
      for (int r = 0; r < 2; ++r)
        p4[((long)b * 1024 + (t0 >> 2) + r) * D_ + c] =
            f2bf((v[4*r] + v[4*r+1] + v[4*r+2] + v[4*r+3]) * 0.25f);
      p8[((long)b * 512 + (t0 >> 3)) * D_ + c] =
          f2bf((v[0]+v[1]+v[2]+v[3]+v[4]+v[5]+v[6]+v[7]) * 0.125f);
    }
    return;
  }
  if (blk < 14848) {                         // ---- weight transposes ----
    const int idx = (blk - 1024) * 256 + tid;
    if (idx < 1048576) {
      const int h = idx >> 17, wi = idx & 131071;
      const int c = wi >> 10, k = wi & 1023;
      wqT[idx] = f2bf(Wq[(long)h * 131072 + k * 128 + c]);
    } else if (idx < 3145728) {
      const int lid = idx - 1048576;
      const int g = lid >> 19, wi = lid & 524287;
      const int n = wi >> 10, k = wi & 1023;
      const int kv = n >> 8, hh = (n >> 7) & 1, c = n & 127;
      const float* W = kv ? Wv : Wk;
      kvT[lid] = f2bf(W[(long)(2 * g + hh) * 131072 + k * 128 + c]);
    } else if (idx < 3407872) {
      const int lid = idx - 3145728;
      const int n = lid >> 10, k = lid & 1023;
      rw1T[lid] = f2bf(rW1[(long)k * 256 + n]);
    } else if (idx < 3538944) {
      const int lid = idx - 3407872;
      const int n = lid >> 7, k = lid & 127;
      woutT[lid] = f2bf(Wout[(long)k * 1024 + n]);
    }
    return;
  }
  // ---- irfft: conv kernel c per head, 4 phase-shifted replicas ----
  const int rel = blk - 14848;
  const int h = rel >> 4, xi = rel & 15;
  const int Tk = 4096 >> (h >> 1);
  const int mask = Tk - 1;
  if (xi * 256 >= Tk) return;
  const int nb = (Tk >> 1) + 1;
  __shared__ float ct[4096];
  __shared__ float wm[2049];
  const float w0 = 6.283185307179586f / (float)Tk;
  for (int j = tid; j < Tk; j += 256) ct[j] = cosf(w0 * (float)j);
  for (int m = tid; m < nb; m += 256) {
    int band = (m * 8) / nb; if (band > 7) band = 7;
    const float g = 1.f / (1.f + expf(-bg[h * 8 + band]));
    const float sc = (m == 0 || m == nb - 1) ? 1.f : 2.f;
    wm[m] = g * sc / (float)Tk;
  }
  __syncthreads();
  const int n = xi * 256 + tid;
  float acc = 0.f;
  int idx = 0;
  for (int m = 0; m < nb; ++m) {
    acc += wm[m] * ct[idx];
    idx += n;
    if (idx >= Tk) idx -= Tk;
  }
  const u16 bf = f2bf(acc);
  u16* hb = crep + (long)h * 16416;
#pragma unroll
  for (int p = 0; p < 4; ++p) {
    const int q = (n - p) & mask;
    hb[p * 4104 + q] = bf;
    if (q < 8) hb[p * 4104 + q + Tk] = bf;
  }
}

// ---------- bf16 tiled transpose for K,V slices (V keys PV-permuted) ----------
__global__ __launch_bounds__(256) void tpose_all(const u16* __restrict__ KV,
                                                 u16* __restrict__ KT, u16* __restrict__ VT) {
  const int xt = blockIdx.x;
  int g, lx;
  if (xt < 128)      { g = 0; lx = xt; }
  else if (xt < 192) { g = 1; lx = xt - 128; }
  else if (xt < 224) { g = 2; lx = xt - 192; }
  else               { g = 3; lx = xt - 224; }
  const int Tk = 4096 >> g;
  const long kvrow[4] = {0, 8192, 12288, 14336};
  const long ktoff[4] = {0, 2097152, 3145728, 3670016};
  __shared__ u16 tile[32][33];
  const int z = blockIdx.z;
  const int b = z & 1, hh = (z >> 1) & 1, kv = z >> 2;
  const u16* src = KV + kvrow[g] * 512 + (long)b * Tk * 512 + kv * 256 + hh * 128;
  u16* dst = (kv ? VT : KT) + ktoff[g] + (long)(hh * 2 + b) * 128 * Tk;
  const int r0 = lx * 32, c0 = blockIdx.y * 32;
  const int ci = threadIdx.x & 31, ri = threadIdx.x >> 5;
#pragma unroll
  for (int j = 0; j < 4; ++j)
    tile[ri + 8 * j][ci] = src[(long)(r0 + ri + 8 * j) * 512 + c0 + ci];
  __syncthreads();
  const int key = r0 + ci;
  const int col = kv ? ((key & ~63) | (((key >> 4) & 1) << 5) | (((key >> 2) & 3) << 3)
                                    | (((key >> 5) & 1) << 2) | (key & 3))
                     : key;
#pragma unroll
  for (int j = 0; j < 4; ++j)
    dst[(long)(c0 + ri + 8 * j) * Tk + col] = tile[ci][ri + 8 * j];
}

// ---------- async global->LDS ----------
__device__ __forceinline__ void gll16(const void* g, void* l) {
  __builtin_amdgcn_global_load_lds((const __attribute__((address_space(1))) void*)g,
                                   (__attribute__((address_space(3))) void*)l, 16, 0, 0);
}

// ---------- shared bf16 MFMA GEMM core (XOR-swizzled LDS) ----------
__device__ __forceinline__ void gemm_core(const u16* __restrict__ A, const u16* __restrict__ Bt,
    void* __restrict__ Cv, int K, int lda, int ldb, int ldc, int tm, int tn, float alpha,
    bool obf, u16 (*lds)[2][128][32]) {
  const int tid = threadIdx.x, lane = tid & 63, wid = tid >> 6;
  const int wr = wid >> 1, wc = wid & 1;
  const int srow = lane >> 2;
  const int scol = ((lane & 3) ^ ((lane >> 3) & 3)) * 8;
  const u16* ga0 = A + (long)(tm + 32 * wid + srow) * lda + scol;
  const u16* ga1 = ga0 + (long)16 * lda;
  const u16* gb0 = Bt + (long)(tn + 32 * wid + srow) * ldb + scol;
  const u16* gb1 = gb0 + (long)16 * ldb;
  f32x4 acc[4][4] = {};
  const int nk = K >> 5;
  gll16(ga0, &lds[0][0][32 * wid][0]);
  gll16(ga1, &lds[0][0][32 * wid + 16][0]);
  gll16(gb0, &lds[0][1][32 * wid][0]);
  gll16(gb1, &lds[0][1][32 * wid + 16][0]);
  int buf = 0;
  const int fr = lane & 15;
  const int fo2 = (((lane >> 4) & 3) ^ ((lane >> 1) & 3)) * 8;
  for (int kt = 0; kt < nk; ++kt) {
    __syncthreads();
    if (kt + 1 < nk) {
      const long ko = (long)(kt + 1) * 32;
      gll16(ga0 + ko, &lds[buf ^ 1][0][32 * wid][0]);
      gll16(ga1 + ko, &lds[buf ^ 1][0][32 * wid + 16][0]);
      gll16(gb0 + ko, &lds[buf ^ 1][1][32 * wid][0]);
      gll16(gb1 + ko, &lds[buf ^ 1][1][32 * wid + 16][0]);
    }
    short8 af[4], bfr[4];
#pragma unroll
    for (int i = 0; i < 4; ++i) {
      af[i]  = *(const short8*)&lds[buf][0][wr * 64 + i * 16 + fr][fo2];
      bfr[i] = *(const short8*)&lds[buf][1][wc * 64 + i * 16 + fr][fo2];
    }
#pragma unroll
    for (int i = 0; i < 4; ++i)
#pragma unroll
      for (int j = 0; j < 4; ++j)
        acc[i][j] = __builtin_amdgcn_mfma_f32_16x16x32_bf16(af[i], bfr[j], acc[i][j], 0, 0, 0);
    buf ^= 1;
  }
  const int er = (lane >> 4) * 4, ec = lane & 15;
  if (obf) {
    u16* C = (u16*)Cv;
#pragma unroll
    for (int i = 0; i < 4; ++i)
#pragma unroll
      for (int j = 0; j < 4; ++j)
#pragma unroll
        for (int r = 0; r < 4; ++r)
          C[(long)(tm + wr * 64 + i * 16 + er + r) * ldc + (tn + wc * 64 + j * 16 + ec)] =
              f2bf(acc[i][j][r] * alpha);
  } else {
    float* C = (float*)Cv;
#pragma unroll
    for (int i = 0; i < 4; ++i)
#pragma unroll
      for (int j = 0; j < 4; ++j)
#pragma unroll
        for (int r = 0; r < 4; ++r)
          C[(long)(tm + wr * 64 + i * 16 + er + r) * ldc + (tn + wc * 64 + j * 16 + ec)] =
              acc[i][j][r] * alpha;
  }
}

template <bool OBF>
__global__ __launch_bounds__(256) void gemm_bt(const u16* __restrict__ A, const u16* __restrict__ Bt,
                                               void* __restrict__ Cv, int K, int lda, int ldb, int ldc,
                                               long abs_, long bbs, long cbs, float alpha) {
  __shared__ u16 lds[2][2][128][32];
  const u16* Az = A + (long)blockIdx.z * abs_;
  const u16* Bz = Bt + (long)blockIdx.z * bbs;
  void* Cz = OBF ? (void*)((u16*)Cv + (long)blockIdx.z * cbs)
                 : (void*)((float*)Cv + (long)blockIdx.z * cbs);
  gemm_core(Az, Bz, Cz, K, lda, ldb, ldc, blockIdx.x * 128, blockIdx.y * 128, alpha, OBF, lds);
}

// ---------- mega-GEMM: Q + KV + router hidden (XCD-swizzled job order) ----------
__global__ __launch_bounds__(256) void gemm_p1(const u16* __restrict__ xbf,
    const u16* __restrict__ wqT, const u16* __restrict__ kvT, const u16* __restrict__ rw1T,
    u16* __restrict__ Qb, u16* __restrict__ KV, float* __restrict__ hid) {
  __shared__ u16 lds[2][2][128][32];
  const int bid = blockIdx.x;
  const int id = (bid & 7) * 140 + (bid >> 3);   // bijective: 1120 = 8 XCDs x 140 jobs
  if (id < 512) {
    gemm_core(xbf, wqT, Qb, 1024, 1024, 1024, 1024,
              (id >> 3) * 128, (id & 7) * 128, 1.f, true, lds);
  } else if (id < 992) {
    const int lid = id - 512;
    const int rt = lid >> 2, y = lid & 3;
    int g, lr;
    if (rt < 64)       { g = 0; lr = rt; }
    else if (rt < 96)  { g = 1; lr = rt - 64; }
    else if (rt < 112) { g = 2; lr = rt - 96; }
    else               { g = 3; lr = rt - 112; }
    const long xofs[4] = {0, 8388608, 12582912, 14680064};
    const long kvrow[4] = {0, 8192, 12288, 14336};
    gemm_core(xbf + xofs[g], kvT + (long)g * 524288, KV + kvrow[g] * 512,
              1024, 1024, 1024, 512, lr * 128, y * 128, 1.f, true, lds);
  } else {
    const int lid = id - 992;
    gemm_core(xbf, rw1T, hid, 1024, 1024, 1024, 256,
              (lid >> 1) * 128, (lid & 1) * 128, 1.f, false, lds);
  }
}

// ---------- circulant conv GEMM, BK=128 ----------
__global__ __launch_bounds__(256) void conv_k(const u16* __restrict__ crep,
    const u16* __restrict__ KT, u16* __restrict__ Kp) {
  const int z = blockIdx.z, h = z >> 1, b = z & 1, g = h >> 1;
  const int Tk = 4096 >> g, mask = Tk - 1;
  const int tm = blockIdx.x << 7;
  if (tm >= Tk) return;
  __shared__ u16 clds[16416];
  __shared__ u16 blds[2][4][128][32];
  const int tid = threadIdx.x, lane = tid & 63, wid = tid >> 6;
  const int wr = wid >> 1, wc = wid & 1;
  const int srow = lane >> 2;
  const int scol = ((lane & 3) ^ ((lane >> 3) & 3)) * 8;
  const int fr = lane & 15, fo = (lane >> 4) * 8;
  const int fo2 = (((lane >> 4) & 3) ^ ((lane >> 1) & 3)) * 8;
  {
    const short8* src = (const short8*)(crep + (long)h * 16416);
    short8* dst = (short8*)clds;
    for (int j = tid; j < 2052; j += 256) dst[j] = src[j];
  }
  const long ktofs = 4194304 - (4194304 >> g);
  const u16* Bt = KT + ktofs + (long)((h & 1) * 2 + b) * 128 * Tk;
  u16* out = Kp + ktofs + ((long)(h & 1) << 8) * Tk + ((long)b << 7) * Tk;
  const u16* gb0 = Bt + (long)(32 * wid + srow) * Tk + scol;
  const u16* gb1 = gb0 + (long)16 * Tk;
  f32x4 acc[4][4] = {};
  int base[4];
#pragma unroll
  for (int i = 0; i < 4; ++i) base[i] = (fo - (tm + wr * 64 + i * 16 + fr)) & mask;
  const int p = base[0] & 3;
  const u16* crow = clds + p * 4104;
  const int nk = Tk >> 7;
#pragma unroll
  for (int c = 0; c < 4; ++c) {
    gll16(gb0 + c * 32, &blds[0][c][32 * wid][0]);
    gll16(gb1 + c * 32, &blds[0][c][32 * wid + 16][0]);
  }
  int buf = 0;
  for (int kt = 0; kt < nk; ++kt) {
    __syncthreads();
    if (kt + 1 < nk) {
      const long ko = (long)(kt + 1) * 128;
#pragma unroll
      for (int c = 0; c < 4; ++c) {
        gll16(gb0 + ko + c * 32, &blds[buf ^ 1][c][32 * wid][0]);
        gll16(gb1 + ko + c * 32, &blds[buf ^ 1][c][32 * wid + 16][0]);
      }
    }
#pragma unroll
    for (int c = 0; c < 4; ++c) {
      short8 af[4], bfr[4];
#pragma unroll
      for (int i = 0; i < 4; ++i) {
        const int a0 = base[i] ^ p;
        short4v lo = *(const short4v*)(crow + a0);
        short4v hi = *(const short4v*)(crow + a0 + 4);
        af[i][0] = lo[0]; af[i][1] = lo[1]; af[i][2] = lo[2]; af[i][3] = lo[3];
        af[i][4] = hi[0]; af[i][5] = hi[1]; af[i][6] = hi[2]; af[i][7] = hi[3];
        base[i] = (base[i] + 32) & mask;
        bfr[i] = *(const short8*)&blds[buf][c][wc * 64 + i * 16 + fr][fo2];
      }
#pragma unroll
      for (int i = 0; i < 4; ++i)
#pragma unroll
        for (int j = 0; j < 4; ++j)
          acc[i][j] = __builtin_amdgcn_mfma_f32_16x16x32_bf16(af[i], bfr[j], acc[i][j], 0, 0, 0);
    }
    buf ^= 1;
  }
  const int er = (lane >> 4) * 4, ec = lane & 15;
#pragma unroll
  for (int i = 0; i < 4; ++i)
#pragma unroll
    for (int j = 0; j < 4; ++j)
#pragma unroll
      for (int r = 0; r < 4; ++r)
        out[(long)(tm + wr * 64 + i * 16 + er + r) * 128 + (wc * 64 + j * 16 + ec)] =
            f2bf(acc[i][j][r] * ISSL2E);
}

// ---------- flash v6: v4 + single-buffered V -> 48KB LDS, 3 blocks/CU ----------
__global__ __launch_bounds__(256, 3) void flash(const u16* __restrict__ Qb,
    const u16* __restrict__ Kp, const u16* __restrict__ VT, float* __restrict__ O) {
  const int wg = blockIdx.x;
  const int x = wg & 7, s = wg >> 3;
  const int t4 = s >> 4;
  const int lvl = t4 ^ (t4 >> 1);
  const int hh = x >> 2, b = (x >> 1) & 1;
  const int h = lvl * 2 + hh;
  const int qtm = (((x & 1) << 4) + (s & 15)) << 7;
  const int Tk = 4096 >> lvl;
  const int nt = Tk >> 6;

  __shared__ __align__(16) char smem[49152];
  u16 (*Kl)[4][64][32] = (u16(*)[4][64][32])smem;          // 2 x 16 KB double-buffered
  u16 (*Vl)[64]        = (u16(*)[64])(smem + 32768);       // 16 KB single buffer

  const int tid = threadIdx.x, lane = tid & 63, wid = tid >> 6;
  const int fr = lane & 15, gs = lane >> 4;
  const int fo = gs * 8;
  const int fo2 = ((gs & 3) ^ ((lane >> 1) & 3)) * 8;

  const long ktofs = 4194304 - (4194304 >> lvl);
  const u16* kbase = Kp + ktofs + (long)(hh * 2 + b) * 128 * Tk;
  const u16* vbase = VT + ktofs + (long)(hh * 2 + b) * 128 * Tk;

  short8 aq[2][4];
#pragma unroll
  for (int m = 0; m < 2; ++m)
#pragma unroll
    for (int kk = 0; kk < 4; ++kk)
      aq[m][kk] = *(const short8*)(Qb +
          ((long)(b * 4096 + qtm + wid * 32 + m * 16 + fr)) * 1024 + h * 128 + kk * 32 + fo);

  const u16* kptr = kbase + (long)(lane >> 2) * 128 + wid * 32 +
                    (((lane & 3) ^ ((lane >> 3) & 3)) << 3);
  const u16* vptr = vbase + (long)(32 * wid + (lane >> 3)) * Tk +
                    (((lane & 7) ^ ((lane >> 3) & 7)) << 3);

  const char* kbL  = smem + fr * 64 + fo2 * 2;
  const char* vbL0 = smem + 32768 + fr * 128 + ((((gs    ) ^ (fr & 7)) & 7) << 4);
  const char* vbL1 = smem + 32768 + fr * 128 + ((((gs ^ 4) ^ (fr & 7)) & 7) << 4);

  f32x4 acc[2][8] = {};
  f32x4 accl[2] = {};
  float mr[2] = {-3e38f, -3e38f};

  short8 ones;
#pragma unroll
  for (int i = 0; i < 8; ++i) ones[i] = (short)0x3F80;

  // prologue: stage K(0) only (V(0) staged inside iter 0)
#pragma unroll
  for (int i = 0; i < 4; ++i) gll16(kptr + i * 2048, &Kl[0][wid][i * 16][0]);

  int cur = 0;
  for (int kt = 0; kt < nt; ++kt) {
    asm volatile("s_waitcnt vmcnt(0)" ::: "memory");   // K(kt) staged; Vl free (PV(kt-1) done pre-barrier)
    __builtin_amdgcn_sched_barrier(0);
    __builtin_amdgcn_s_barrier();
    __builtin_amdgcn_sched_barrier(0);
    // issue V(kt) FIRST (oldest -> gated by vmcnt(4)), then K(kt+1)
#pragma unroll
    for (int i = 0; i < 4; ++i)
      gll16(vptr + (long)kt * 64 + (long)i * 8 * Tk, &Vl[32 * wid + 8 * i][0]);
    if (kt + 1 < nt) {
#pragma unroll
      for (int i = 0; i < 4; ++i)
        gll16(kptr + (long)(kt + 1) * 8192 + i * 2048, &Kl[cur ^ 1][wid][i * 16][0]);
    }
    const char* kc = kbL + cur * 16384;
    // ---- QK^T (swapped) ----
    f32x4 sa[2][4] = {};
    __builtin_amdgcn_s_setprio(1);
#pragma unroll
    for (int kk = 0; kk < 4; ++kk) {
      short8 bk[4];
#pragma unroll
      for (int jm = 0; jm < 4; ++jm)
        bk[jm] = *(const short8*)(kc + kk * 4096 + jm * 1024);
#pragma unroll
      for (int m = 0; m < 2; ++m)
#pragma unroll
        for (int jm = 0; jm < 4; ++jm)
          sa[m][jm] = __builtin_amdgcn_mfma_f32_16x16x32_bf16(bk[jm], aq[m][kk], sa[m][jm], 0, 0, 0);
    }
    __builtin_amdgcn_s_setprio(0);
    // ---- softmax (exp2 domain, defer-rescale) ----
    float tmx[2];
#pragma unroll
    for (int m = 0; m < 2; ++m) {
      float v0 = fmaxf(fmaxf(sa[m][0][0], sa[m][0][1]), fmaxf(sa[m][0][2], sa[m][0][3]));
      float v1 = fmaxf(fmaxf(sa[m][1][0], sa[m][1][1]), fmaxf(sa[m][1][2], sa[m][1][3]));
      float v2 = fmaxf(fmaxf(sa[m][2][0], sa[m][2][1]), fmaxf(sa[m][2][2], sa[m][2][3]));
      float v3 = fmaxf(fmaxf(sa[m][3][0], sa[m][3][1]), fmaxf(sa[m][3][2], sa[m][3][3]));
      float v = fmaxf(fmaxf(v0, v1), fmaxf(v2, v3));
      v = fmaxf(v, __shfl_xor(v, 16));
      v = fmaxf(v, __shfl_xor(v, 32));
      tmx[m] = v;
    }
    const bool need = (tmx[0] > mr[0] + 8.f) | (tmx[1] > mr[1] + 8.f);
    if (__any((int)need)) {
#pragma unroll
      for (int m = 0; m < 2; ++m) {
        const float mn = fmaxf(mr[m], tmx[m]);
        const float av = __builtin_amdgcn_exp2f(mr[m] - mn);
        mr[m] = mn;
#pragma unroll
        for (int jd = 0; jd < 8; ++jd)
#pragma unroll
          for (int r = 0; r < 4; ++r) acc[m][jd][r] *= av;
#pragma unroll
        for (int r = 0; r < 4; ++r) accl[m][r] *= av;
      }
    }
#pragma unroll
    for (int m = 0; m < 2; ++m)
#pragma unroll
      for (int jm = 0; jm < 4; ++jm)
#pragma unroll
        for (int r = 0; r < 4; ++r)
          sa[m][jm][r] = __builtin_amdgcn_exp2f(sa[m][jm][r] - mr[m]);
    // ---- pack P^T pairs in-register ----
    unsigned pk[2][4][2];
#pragma unroll
    for (int m = 0; m < 2; ++m)
#pragma unroll
      for (int jm = 0; jm < 4; ++jm) {
        asm("v_cvt_pk_bf16_f32 %0, %1, %2" : "=v"(pk[m][jm][0]) : "v"(sa[m][jm][0]), "v"(sa[m][jm][1]));
        asm("v_cvt_pk_bf16_f32 %0, %1, %2" : "=v"(pk[m][jm][1]) : "v"(sa[m][jm][2]), "v"(sa[m][jm][3]));
      }
    // ---- wait V(kt) (K(kt+1) stays in flight), barrier, PV ----
    if (kt + 1 < nt) { asm volatile("s_waitcnt vmcnt(4)" ::: "memory"); }
    else             { asm volatile("s_waitcnt vmcnt(0)" ::: "memory"); }
    __builtin_amdgcn_sched_barrier(0);
    __builtin_amdgcn_s_barrier();
    __builtin_amdgcn_sched_barrier(0);
    __builtin_amdgcn_s_setprio(1);
#pragma unroll
    for (int kk = 0; kk < 2; ++kk) {
      short8 pt[2];
#pragma unroll
      for (int m = 0; m < 2; ++m) {
        union { unsigned u[4]; short8 s; } pp;
        pp.u[0] = pk[m][kk][0];     pp.u[1] = pk[m][kk][1];
        pp.u[2] = pk[m][kk + 2][0]; pp.u[3] = pk[m][kk + 2][1];
        pt[m] = pp.s;
      }
      const char* vc = kk ? vbL1 : vbL0;
#pragma unroll
      for (int jd = 0; jd < 8; ++jd) {
        short8 bb = *(const short8*)(vc + jd * 2048);
#pragma unroll
        for (int m = 0; m < 2; ++m)
          acc[m][jd] = __builtin_amdgcn_mfma_f32_16x16x32_bf16(bb, pt[m], acc[m][jd], 0, 0, 0);
      }
#pragma unroll
      for (int m = 0; m < 2; ++m)
        accl[m] = __builtin_amdgcn_mfma_f32_16x16x32_bf16(ones, pt[m], accl[m], 0, 0, 0);
    }
    __builtin_amdgcn_s_setprio(0);
    cur ^= 1;
  }
  // ---- epilogue: normalize, transpose O^T -> O through LDS, coalesced store ----
  __syncthreads();
  float* Ot = (float*)smem;             // [4 waves][16 q][132 d] = 33.8 KB (fits 48KB)
  float* ot = Ot + wid * 16 * 132;
#pragma unroll
  for (int m = 0; m < 2; ++m) {
    const float inv = 1.f / accl[m][0];
#pragma unroll
    for (int jd = 0; jd < 8; ++jd) {
      f32x4 v;
#pragma unroll
      for (int r = 0; r < 4; ++r) v[r] = acc[m][jd][r] * inv;
      *(f32x4*)&ot[fr * 132 + jd * 16 + gs * 4] = v;
    }
    asm volatile("s_waitcnt lgkmcnt(0)" ::: "memory");
    __builtin_amdgcn_sched_barrier(0);
    const int q = qtm + wid * 32 + m * 16 + (lane >> 2);
    float* od = O + ((long)(b * 4096 + q) * 8 + h) * 128 + (lane & 3) * 32;
#pragma unroll
    for (int j = 0; j < 8; ++j) {
      f32x4 v = *(const f32x4*)&ot[(lane >> 2) * 132 + (lane & 3) * 32 + j * 4];
      *(f32x4*)&od[j * 4] = v;
    }
    asm volatile("s_waitcnt lgkmcnt(0)" ::: "memory");
    __builtin_amdgcn_sched_barrier(0);
  }
}

// ---------- fused router MLP tail + contra-flow + head mixing ----------
__global__ __launch_bounds__(256) void router_mix(const float* __restrict__ hid,
    const float* __restrict__ rb1, const float* __restrict__ rW2, const float* __restrict__ rb2,
    const float* __restrict__ al, const float* __restrict__ O, u16* __restrict__ mixed) {
  const int tok = blockIdx.x;
  const int b = tok >> 12, t = tok & 4095;
  const int tid = threadIdx.x;
  __shared__ float lred[4][8];
  __shared__ float wgt[8];
  __shared__ float ta[8];
  const float hv = fmaxf(hid[(long)tok * 256 + tid] + rb1[tid], 0.f);
  const float4* w4 = (const float4*)(rW2 + tid * 8);
  const float4 wa = w4[0], wb = w4[1];
  float part[8] = {hv * wa.x, hv * wa.y, hv * wa.z, hv * wa.w,
                   hv * wb.x, hv * wb.y, hv * wb.z, hv * wb.w};
#pragma unroll
  for (int h = 0; h < 8; ++h) {
    float v = part[h];
#pragma unroll
    for (int o = 1; o < 64; o <<= 1) v += __shfl_xor(v, o);
    if ((tid & 63) == 0) lred[tid >> 6][h] = v;
  }
  __syncthreads();
  if (tid < 8) ta[tid] = tanhf(al[tid]);
  if (tid == 0) {
    float lg[8], m = -1e30f;
#pragma unroll
    for (int h = 0; h < 8; ++h) {
      lg[h] = lred[0][h] + lred[1][h] + lred[2][h] + lred[3][h] + rb2[h];
      m = fmaxf(m, lg[h]);
    }
    float s = 0.f;
#pragma unroll
    for (int h = 0; h < 8; ++h) { lg[h] = __expf(lg[h] - m); s += lg[h]; }
    const float inv = 1.f / s;
#pragma unroll
    for (int h = 0; h < 8; ++h) wgt[h] = lg[h] * inv;
  }
  __syncthreads();
  if (tid < 128) {
    const long base = (long)tok * 1024 + tid;
    const long rbase = ((long)b * 4096 + (4095 - t)) * 1024 + tid;
    float acc = 0.f;
#pragma unroll
    for (int h = 0; h < 8; ++h)
      acc += wgt[h] * (O[base + h * 128] + ta[h] * O[rbase + h * 128]);
    mixed[(long)tok * 128 + tid] = f2bf(acc);
  }
}

extern "C" void kernel_launch(void* const* d_in, const int* in_sizes, int n_in,
                              void* d_out, int out_size, void* d_ws, size_t ws_size,
                              hipStream_t stream) {
  const float* x    = (const float*)d_in[0];
  const float* Wq   = (const float*)d_in[1];
  const float* Wk   = (const float*)d_in[2];
  const float* Wv   = (const float*)d_in[3];
  const float* bg   = (const float*)d_in[4];
  const float* al   = (const float*)d_in[5];
  const float* rW1  = (const float*)d_in[6];
  const float* rb1  = (const float*)d_in[7];
  const float* rW2  = (const float*)d_in[8];
  const float* rb2  = (const float*)d_in[9];
  const float* Wout = (const float*)d_in[10];
  float* out = (float*)d_out;

  // ---- arena (lifetime overlays, ~95.5 MB) ----
  const size_t MB = 1u << 20;
  char* w = (char*)d_ws;
  u16*   xbf   = (u16*)(w + 0);            // 16 MB [P0-P1]
  float* O     = (float*)(w + 0);          // 32 MB [P4-P5] overlays dead pools
  u16*   Qb    = (u16*)(w + 32 * MB);      // 16 MB [P1-P4]
  u16*   KV    = (u16*)(w + 48 * MB);      // 15 MB [P1-P2]
  u16*   Kp    = (u16*)(w + 48 * MB);      // 7.5MB [P3-P4] overlays dead KV
  u16*   KT    = (u16*)(w + 63 * MB);      // 7.5MB [P2-P3]
  u16*   VT    = (u16*)(w + 70 * MB + 512 * 1024); // 7.5MB [P2-P4]
  float* hid   = (float*)(w + 78 * MB);    //  8 MB [P1-P5]
  u16*   wqT   = (u16*)(w + 86 * MB);      //  2 MB
  u16*   kvT   = (u16*)(w + 88 * MB);      //  4 MB
  u16*   rw1T  = (u16*)(w + 92 * MB);      // 512 KB
  u16*   woutT = (u16*)(w + 92 * MB + 512 * 1024);   // 256 KB
  u16*   crep  = (u16*)(w + 92 * MB + 768 * 1024);   // 257 KB
  u16*   mixed = (u16*)(w + 93 * MB + 512 * 1024);   //  2 MB
  u16*   xp2   = (u16*)(w + 16 * MB);
  u16*   xp4   = (u16*)(w + 24 * MB);
  u16*   xp8   = (u16*)(w + 28 * MB);

  // P0: pooling + weight prep + irfft (one launch)
  prep_all<<<dim3(14976), dim3(256), 0, stream>>>(x, Wq, Wk, Wv, rW1, Wout, bg,
      xbf, xp2, xp4, xp8, wqT, kvT, rw1T, woutT, crep);

  // P1: all projections + router hidden (XCD-swizzled job order)
  gemm_p1<<<dim3(1120), dim3(256), 0, stream>>>(xbf, wqT, kvT, rw1T, Qb, KV, hid);

  // P2: K/V transposes (V keys PV-permuted)
  tpose_all<<<dim3(240, 4, 8), dim3(256), 0, stream>>>(KV, KT, VT);

  // P3: circulant conv (BK=128)
  conv_k<<<dim3(32, 1, 16), dim3(256), 0, stream>>>(crep, KT, Kp);

  // P4: flash v6 (single-V, 3 blocks/CU)
  flash<<<dim3(512), dim3(256), 0, stream>>>(Qb, Kp, VT, O);

  // P5: router + mix, then output projection
  router_mix<<<dim3(8192), dim3(256), 0, stream>>>(hid, rb1, rW2, rb2, al, O, mixed);
  gemm_bt<false><<<dim3(64, 8), dim3(256), 0, stream>>>(mixed, woutT, out,
      128, 128, 128, 1024, 0, 0, 0, 1.f);
}

// Round 14
// 329.994 us; speedup vs baseline: 1.1581x; 1.1581x over previous
//
#include <hip/hip_runtime.h>
#include <hip/hip_bf16.h>

typedef __attribute__((ext_vector_type(8))) short short8;
typedef __attribute__((ext_vector_type(4))) short short4v;
typedef __attribute__((ext_vector_type(4))) float f32x4;
typedef unsigned short u16;

#define T_ 4096
#define D_ 1024
#define ISSL2E (0.08838834764831845f * 1.4426950408889634f)   // 1/sqrt(128) * log2(e)

__device__ __forceinline__ u16 f2bf(float f) {
  union { float f; unsigned u; } v; v.f = f;
  unsigned r = v.u + 0x7FFFu + ((v.u >> 16) & 1u);
  return (u16)(r >> 16);
}

// ---------- fused prep: pooling + weight transposes + irfft, ONE launch ----------
__global__ __launch_bounds__(256) void prep_all(const float* __restrict__ x,
    const float* __restrict__ Wq, const float* __restrict__ Wk, const float* __restrict__ Wv,
    const float* __restrict__ rW1, const float* __restrict__ Wout, const float* __restrict__ bg,
    u16* __restrict__ p1, u16* __restrict__ p2, u16* __restrict__ p4, u16* __restrict__ p8,
    u16* __restrict__ wqT, u16* __restrict__ kvT, u16* __restrict__ rw1T, u16* __restrict__ woutT,
    u16* __restrict__ crep) {
  const int blk = blockIdx.x;
  const int tid = threadIdx.x;
  if (blk < 1024) {                          // ---- pooling ----
    const int b = blk >> 9, t0 = (blk & 511) << 3;
    const float* src = x + ((long)b * T_ + t0) * D_;
#pragma unroll
    for (int j = 0; j < 4; ++j) {
      const int c = tid + j * 256;
      float v[8];
#pragma unroll
      for (int r = 0; r < 8; ++r) v[r] = src[r * D_ + c];
#pragma unroll
      for (int r = 0; r < 8; ++r) p1[((long)b * 4096 + t0 + r) * D_ + c] = f2bf(v[r]);
#pragma unroll
      for (int r = 0; r < 4; ++r)
        p2[((long)b * 2048 + (t0 >> 1) + r) * D_ + c] = f2bf((v[2*r] + v[2*r+1]) * 0.5f);
#pragma unroll
      for (int r = 0; r < 2; ++r)
        p4[((long)b * 1024 + (t0 >> 2) + r) * D_ + c] =
            f2bf((v[4*r] + v[4*r+1] + v[4*r+2] + v[4*r+3]) * 0.25f);
      p8[((long)b * 512 + (t0 >> 3)) * D_ + c] =
          f2bf((v[0]+v[1]+v[2]+v[3]+v[4]+v[5]+v[6]+v[7]) * 0.125f);
    }
    return;
  }
  if (blk < 14848) {                         // ---- weight transposes ----
    const int idx = (blk - 1024) * 256 + tid;
    if (idx < 1048576) {
      const int h = idx >> 17, wi = idx & 131071;
      const int c = wi >> 10, k = wi & 1023;
      wqT[idx] = f2bf(Wq[(long)h * 131072 + k * 128 + c]);
    } else if (idx < 3145728) {
      const int lid = idx - 1048576;
      const int g = lid >> 19, wi = lid & 524287;
      const int n = wi >> 10, k = wi & 1023;
      const int kv = n >> 8, hh = (n >> 7) & 1, c = n & 127;
      const float* W = kv ? Wv : Wk;
      kvT[lid] = f2bf(W[(long)(2 * g + hh) * 131072 + k * 128 + c]);
    } else if (idx < 3407872) {
      const int lid = idx - 3145728;
      const int n = lid >> 10, k = lid & 1023;
      rw1T[lid] = f2bf(rW1[(long)k * 256 + n]);
    } else if (idx < 3538944) {
      const int lid = idx - 3407872;
      const int n = lid >> 7, k = lid & 127;
      woutT[lid] = f2bf(Wout[(long)k * 1024 + n]);
    }
    return;
  }
  // ---- irfft: conv kernel c per head, 4 phase-shifted replicas ----
  const int rel = blk - 14848;
  const int h = rel >> 4, xi = rel & 15;
  const int Tk = 4096 >> (h >> 1);
  const int mask = Tk - 1;
  if (xi * 256 >= Tk) return;
  const int nb = (Tk >> 1) + 1;
  __shared__ float ct[4096];
  __shared__ float wm[2049];
  const float w0 = 6.283185307179586f / (float)Tk;
  for (int j = tid; j < Tk; j += 256) ct[j] = cosf(w0 * (float)j);
  for (int m = tid; m < nb; m += 256) {
    int band = (m * 8) / nb; if (band > 7) band = 7;
    const float g = 1.f / (1.f + expf(-bg[h * 8 + band]));
    const float sc = (m == 0 || m == nb - 1) ? 1.f : 2.f;
    wm[m] = g * sc / (float)Tk;
  }
  __syncthreads();
  const int n = xi * 256 + tid;
  float acc = 0.f;
  int idx = 0;
  for (int m = 0; m < nb; ++m) {
    acc += wm[m] * ct[idx];
    idx += n;
    if (idx >= Tk) idx -= Tk;
  }
  const u16 bf = f2bf(acc);
  u16* hb = crep + (long)h * 16416;
#pragma unroll
  for (int p = 0; p < 4; ++p) {
    const int q = (n - p) & mask;
    hb[p * 4104 + q] = bf;
    if (q < 8) hb[p * 4104 + q + Tk] = bf;
  }
}

// ---------- bf16 tiled transpose for K,V slices (V keys PV-permuted) ----------
__global__ __launch_bounds__(256) void tpose_all(const u16* __restrict__ KV,
                                                 u16* __restrict__ KT, u16* __restrict__ VT) {
  const int xt = blockIdx.x;
  int g, lx;
  if (xt < 128)      { g = 0; lx = xt; }
  else if (xt < 192) { g = 1; lx = xt - 128; }
  else if (xt < 224) { g = 2; lx = xt - 192; }
  else               { g = 3; lx = xt - 224; }
  const int Tk = 4096 >> g;
  const long kvrow[4] = {0, 8192, 12288, 14336};
  const long ktoff[4] = {0, 2097152, 3145728, 3670016};
  __shared__ u16 tile[32][33];
  const int z = blockIdx.z;
  const int b = z & 1, hh = (z >> 1) & 1, kv = z >> 2;
  const u16* src = KV + kvrow[g] * 512 + (long)b * Tk * 512 + kv * 256 + hh * 128;
  u16* dst = (kv ? VT : KT) + ktoff[g] + (long)(hh * 2 + b) * 128 * Tk;
  const int r0 = lx * 32, c0 = blockIdx.y * 32;
  const int ci = threadIdx.x & 31, ri = threadIdx.x >> 5;
#pragma unroll
  for (int j = 0; j < 4; ++j)
    tile[ri + 8 * j][ci] = src[(long)(r0 + ri + 8 * j) * 512 + c0 + ci];
  __syncthreads();
  const int key = r0 + ci;
  const int col = kv ? ((key & ~63) | (((key >> 4) & 1) << 5) | (((key >> 2) & 3) << 3)
                                    | (((key >> 5) & 1) << 2) | (key & 3))
                     : key;
#pragma unroll
  for (int j = 0; j < 4; ++j)
    dst[(long)(c0 + ri + 8 * j) * Tk + col] = tile[ci][ri + 8 * j];
}

// ---------- async global->LDS ----------
__device__ __forceinline__ void gll16(const void* g, void* l) {
  __builtin_amdgcn_global_load_lds((const __attribute__((address_space(1))) void*)g,
                                   (__attribute__((address_space(3))) void*)l, 16, 0, 0);
}

// ---------- shared bf16 MFMA GEMM core (XOR-swizzled LDS) ----------
__device__ __forceinline__ void gemm_core(const u16* __restrict__ A, const u16* __restrict__ Bt,
    void* __restrict__ Cv, int K, int lda, int ldb, int ldc, int tm, int tn, float alpha,
    bool obf, u16 (*lds)[2][128][32]) {
  const int tid = threadIdx.x, lane = tid & 63, wid = tid >> 6;
  const int wr = wid >> 1, wc = wid & 1;
  const int srow = lane >> 2;
  const int scol = ((lane & 3) ^ ((lane >> 3) & 3)) * 8;
  const u16* ga0 = A + (long)(tm + 32 * wid + srow) * lda + scol;
  const u16* ga1 = ga0 + (long)16 * lda;
  const u16* gb0 = Bt + (long)(tn + 32 * wid + srow) * ldb + scol;
  const u16* gb1 = gb0 + (long)16 * ldb;
  f32x4 acc[4][4] = {};
  const int nk = K >> 5;
  gll16(ga0, &lds[0][0][32 * wid][0]);
  gll16(ga1, &lds[0][0][32 * wid + 16][0]);
  gll16(gb0, &lds[0][1][32 * wid][0]);
  gll16(gb1, &lds[0][1][32 * wid + 16][0]);
  int buf = 0;
  const int fr = lane & 15;
  const int fo2 = (((lane >> 4) & 3) ^ ((lane >> 1) & 3)) * 8;
  for (int kt = 0; kt < nk; ++kt) {
    __syncthreads();
    if (kt + 1 < nk) {
      const long ko = (long)(kt + 1) * 32;
      gll16(ga0 + ko, &lds[buf ^ 1][0][32 * wid][0]);
      gll16(ga1 + ko, &lds[buf ^ 1][0][32 * wid + 16][0]);
      gll16(gb0 + ko, &lds[buf ^ 1][1][32 * wid][0]);
      gll16(gb1 + ko, &lds[buf ^ 1][1][32 * wid + 16][0]);
    }
    short8 af[4], bfr[4];
#pragma unroll
    for (int i = 0; i < 4; ++i) {
      af[i]  = *(const short8*)&lds[buf][0][wr * 64 + i * 16 + fr][fo2];
      bfr[i] = *(const short8*)&lds[buf][1][wc * 64 + i * 16 + fr][fo2];
    }
#pragma unroll
    for (int i = 0; i < 4; ++i)
#pragma unroll
      for (int j = 0; j < 4; ++j)
        acc[i][j] = __builtin_amdgcn_mfma_f32_16x16x32_bf16(af[i], bfr[j], acc[i][j], 0, 0, 0);
    buf ^= 1;
  }
  const int er = (lane >> 4) * 4, ec = lane & 15;
  if (obf) {
    u16* C = (u16*)Cv;
#pragma unroll
    for (int i = 0; i < 4; ++i)
#pragma unroll
      for (int j = 0; j < 4; ++j)
#pragma unroll
        for (int r = 0; r < 4; ++r)
          C[(long)(tm + wr * 64 + i * 16 + er + r) * ldc + (tn + wc * 64 + j * 16 + ec)] =
              f2bf(acc[i][j][r] * alpha);
  } else {
    float* C = (float*)Cv;
#pragma unroll
    for (int i = 0; i < 4; ++i)
#pragma unroll
      for (int j = 0; j < 4; ++j)
#pragma unroll
        for (int r = 0; r < 4; ++r)
          C[(long)(tm + wr * 64 + i * 16 + er + r) * ldc + (tn + wc * 64 + j * 16 + ec)] =
              acc[i][j][r] * alpha;
  }
}

template <bool OBF>
__global__ __launch_bounds__(256) void gemm_bt(const u16* __restrict__ A, const u16* __restrict__ Bt,
                                               void* __restrict__ Cv, int K, int lda, int ldb, int ldc,
                                               long abs_, long bbs, long cbs, float alpha) {
  __shared__ u16 lds[2][2][128][32];
  const u16* Az = A + (long)blockIdx.z * abs_;
  const u16* Bz = Bt + (long)blockIdx.z * bbs;
  void* Cz = OBF ? (void*)((u16*)Cv + (long)blockIdx.z * cbs)
                 : (void*)((float*)Cv + (long)blockIdx.z * cbs);
  gemm_core(Az, Bz, Cz, K, lda, ldb, ldc, blockIdx.x * 128, blockIdx.y * 128, alpha, OBF, lds);
}

// ---------- mega-GEMM: Q + KV + router hidden (XCD-swizzled job order) ----------
__global__ __launch_bounds__(256) void gemm_p1(const u16* __restrict__ xbf,
    const u16* __restrict__ wqT, const u16* __restrict__ kvT, const u16* __restrict__ rw1T,
    u16* __restrict__ Qb, u16* __restrict__ KV, float* __restrict__ hid) {
  __shared__ u16 lds[2][2][128][32];
  const int bid = blockIdx.x;
  const int id = (bid & 7) * 140 + (bid >> 3);   // bijective: 1120 = 8 XCDs x 140 jobs
  if (id < 512) {
    gemm_core(xbf, wqT, Qb, 1024, 1024, 1024, 1024,
              (id >> 3) * 128, (id & 7) * 128, 1.f, true, lds);
  } else if (id < 992) {
    const int lid = id - 512;
    const int rt = lid >> 2, y = lid & 3;
    int g, lr;
    if (rt < 64)       { g = 0; lr = rt; }
    else if (rt < 96)  { g = 1; lr = rt - 64; }
    else if (rt < 112) { g = 2; lr = rt - 96; }
    else               { g = 3; lr = rt - 112; }
    const long xofs[4] = {0, 8388608, 12582912, 14680064};
    const long kvrow[4] = {0, 8192, 12288, 14336};
    gemm_core(xbf + xofs[g], kvT + (long)g * 524288, KV + kvrow[g] * 512,
              1024, 1024, 1024, 512, lr * 128, y * 128, 1.f, true, lds);
  } else {
    const int lid = id - 992;
    gemm_core(xbf, rw1T, hid, 1024, 1024, 1024, 256,
              (lid >> 1) * 128, (lid & 1) * 128, 1.f, false, lds);
  }
}

// ---------- circulant conv GEMM, BK=64 (64.1 KB LDS -> 2 blocks/CU) ----------
__global__ __launch_bounds__(256) void conv_k(const u16* __restrict__ crep,
    const u16* __restrict__ KT, u16* __restrict__ Kp) {
  const int z = blockIdx.z, h = z >> 1, b = z & 1, g = h >> 1;
  const int Tk = 4096 >> g, mask = Tk - 1;
  const int tm = blockIdx.x << 7;
  if (tm >= Tk) return;
  __shared__ u16 clds[16416];
  __shared__ u16 blds[2][2][128][32];   // dbuf x 2 K-chunks of 32
  const int tid = threadIdx.x, lane = tid & 63, wid = tid >> 6;
  const int wr = wid >> 1, wc = wid & 1;
  const int srow = lane >> 2;
  const int scol = ((lane & 3) ^ ((lane >> 3) & 3)) * 8;
  const int fr = lane & 15, fo = (lane >> 4) * 8;
  const int fo2 = (((lane >> 4) & 3) ^ ((lane >> 1) & 3)) * 8;
  {
    const short8* src = (const short8*)(crep + (long)h * 16416);
    short8* dst = (short8*)clds;
    for (int j = tid; j < 2052; j += 256) dst[j] = src[j];
  }
  const long ktofs = 4194304 - (4194304 >> g);
  const u16* Bt = KT + ktofs + (long)((h & 1) * 2 + b) * 128 * Tk;
  u16* out = Kp + ktofs + ((long)(h & 1) << 8) * Tk + ((long)b << 7) * Tk;
  const u16* gb0 = Bt + (long)(32 * wid + srow) * Tk + scol;
  const u16* gb1 = gb0 + (long)16 * Tk;
  f32x4 acc[4][4] = {};
  int base[4];
#pragma unroll
  for (int i = 0; i < 4; ++i) base[i] = (fo - (tm + wr * 64 + i * 16 + fr)) & mask;
  const int p = base[0] & 3;
  const u16* crow = clds + p * 4104;
  const int nk = Tk >> 6;
#pragma unroll
  for (int c = 0; c < 2; ++c) {
    gll16(gb0 + c * 32, &blds[0][c][32 * wid][0]);
    gll16(gb1 + c * 32, &blds[0][c][32 * wid + 16][0]);
  }
  int buf = 0;
  for (int kt = 0; kt < nk; ++kt) {
    __syncthreads();
    if (kt + 1 < nk) {
      const long ko = (long)(kt + 1) * 64;
#pragma unroll
      for (int c = 0; c < 2; ++c) {
        gll16(gb0 + ko + c * 32, &blds[buf ^ 1][c][32 * wid][0]);
        gll16(gb1 + ko + c * 32, &blds[buf ^ 1][c][32 * wid + 16][0]);
      }
    }
#pragma unroll
    for (int c = 0; c < 2; ++c) {
      short8 af[4], bfr[4];
#pragma unroll
      for (int i = 0; i < 4; ++i) {
        const int a0 = base[i] ^ p;
        short4v lo = *(const short4v*)(crow + a0);
        short4v hi = *(const short4v*)(crow + a0 + 4);
        af[i][0] = lo[0]; af[i][1] = lo[1]; af[i][2] = lo[2]; af[i][3] = lo[3];
        af[i][4] = hi[0]; af[i][5] = hi[1]; af[i][6] = hi[2]; af[i][7] = hi[3];
        base[i] = (base[i] + 32) & mask;
        bfr[i] = *(const short8*)&blds[buf][c][wc * 64 + i * 16 + fr][fo2];
      }
#pragma unroll
      for (int i = 0; i < 4; ++i)
#pragma unroll
        for (int j = 0; j < 4; ++j)
          acc[i][j] = __builtin_amdgcn_mfma_f32_16x16x32_bf16(af[i], bfr[j], acc[i][j], 0, 0, 0);
    }
    buf ^= 1;
  }
  const int er = (lane >> 4) * 4, ec = lane & 15;
#pragma unroll
  for (int i = 0; i < 4; ++i)
#pragma unroll
    for (int j = 0; j < 4; ++j)
#pragma unroll
      for (int r = 0; r < 4; ++r)
        out[(long)(tm + wr * 64 + i * 16 + er + r) * 128 + (wc * 64 + j * 16 + ec)] =
            f2bf(acc[i][j][r] * ISSL2E);
}

// ---------- flash attention v4 (known-good r10/r12 version) ----------
__global__ __launch_bounds__(256, 2) void flash(const u16* __restrict__ Qb,
    const u16* __restrict__ Kp, const u16* __restrict__ VT, float* __restrict__ O) {
  const int wg = blockIdx.x;
  const int x = wg & 7, s = wg >> 3;
  const int t4 = s >> 4;
  const int lvl = t4 ^ (t4 >> 1);
  const int hh = x >> 2, b = (x >> 1) & 1;
  const int h = lvl * 2 + hh;
  const int qtm = (((x & 1) << 4) + (s & 15)) << 7;
  const int Tk = 4096 >> lvl;
  const int nt = Tk >> 6;

  __shared__ __align__(16) char smem[65536];
  u16 (*Kl)[4][64][32] = (u16(*)[4][64][32])smem;
  u16 (*Vl)[128][64]   = (u16(*)[128][64])(smem + 32768);

  const int tid = threadIdx.x, lane = tid & 63, wid = tid >> 6;
  const int fr = lane & 15, gs = lane >> 4;
  const int fo = gs * 8;
  const int fo2 = ((gs & 3) ^ ((lane >> 1) & 3)) * 8;

  const long ktofs = 4194304 - (4194304 >> lvl);
  const u16* kbase = Kp + ktofs + (long)(hh * 2 + b) * 128 * Tk;
  const u16* vbase = VT + ktofs + (long)(hh * 2 + b) * 128 * Tk;

  short8 aq[2][4];
#pragma unroll
  for (int m = 0; m < 2; ++m)
#pragma unroll
    for (int kk = 0; kk < 4; ++kk)
      aq[m][kk] = *(const short8*)(Qb +
          ((long)(b * 4096 + qtm + wid * 32 + m * 16 + fr)) * 1024 + h * 128 + kk * 32 + fo);

  const u16* kptr = kbase + (long)(lane >> 2) * 128 + wid * 32 +
                    (((lane & 3) ^ ((lane >> 3) & 3)) << 3);
  const u16* vptr = vbase + (long)(32 * wid + (lane >> 3)) * Tk +
                    (((lane & 7) ^ ((lane >> 3) & 7)) << 3);

  const char* kbL  = smem + fr * 64 + fo2 * 2;
  const char* vbL0 = smem + 32768 + fr * 128 + ((((gs    ) ^ (fr & 7)) & 7) << 4);
  const char* vbL1 = smem + 32768 + fr * 128 + ((((gs ^ 4) ^ (fr & 7)) & 7) << 4);

  f32x4 acc[2][8] = {};
  f32x4 accl[2] = {};
  float mr[2] = {-3e38f, -3e38f};

  short8 ones;
#pragma unroll
  for (int i = 0; i < 8; ++i) ones[i] = (short)0x3F80;

#pragma unroll
  for (int i = 0; i < 4; ++i) {
    gll16(kptr + i * 2048, &Kl[0][wid][i * 16][0]);
    gll16(vptr + (long)i * 8 * Tk, &Vl[0][32 * wid + 8 * i][0]);
  }

  int cur = 0;
  for (int kt = 0; kt < nt; ++kt) {
    asm volatile("s_waitcnt vmcnt(0)" ::: "memory");
    __builtin_amdgcn_sched_barrier(0);
    __builtin_amdgcn_s_barrier();
    __builtin_amdgcn_sched_barrier(0);
    if (kt + 1 < nt) {
      const int ktn = kt + 1;
#pragma unroll
      for (int i = 0; i < 4; ++i) {
        gll16(kptr + (long)ktn * 8192 + i * 2048, &Kl[cur ^ 1][wid][i * 16][0]);
        gll16(vptr + (long)ktn * 64 + (long)i * 8 * Tk, &Vl[cur ^ 1][32 * wid + 8 * i][0]);
      }
    }
    const char* kc = kbL + cur * 16384;
    f32x4 sa[2][4] = {};
    __builtin_amdgcn_s_setprio(1);
#pragma unroll
    for (int kk = 0; kk < 4; ++kk) {
      short8 bk[4];
#pragma unroll
      for (int jm = 0; jm < 4; ++jm)
        bk[jm] = *(const short8*)(kc + kk * 4096 + jm * 1024);
#pragma unroll
      for (int m = 0; m < 2; ++m)
#pragma unroll
        for (int jm = 0; jm < 4; ++jm)
          sa[m][jm] = __builtin_amdgcn_mfma_f32_16x16x32_bf16(bk[jm], aq[m][kk], sa[m][jm], 0, 0, 0);
    }
    __builtin_amdgcn_s_setprio(0);
    float tmx[2];
#pragma unroll
    for (int m = 0; m < 2; ++m) {
      float v0 = fmaxf(fmaxf(sa[m][0][0], sa[m][0][1]), fmaxf(sa[m][0][2], sa[m][0][3]));
      float v1 = fmaxf(fmaxf(sa[m][1][0], sa[m][1][1]), fmaxf(sa[m][1][2], sa[m][1][3]));
      float v2 = fmaxf(fmaxf(sa[m][2][0], sa[m][2][1]), fmaxf(sa[m][2][2], sa[m][2][3]));
      float v3 = fmaxf(fmaxf(sa[m][3][0], sa[m][3][1]), fmaxf(sa[m][3][2], sa[m][3][3]));
      float v = fmaxf(fmaxf(v0, v1), fmaxf(v2, v3));
      v = fmaxf(v, __shfl_xor(v, 16));
      v = fmaxf(v, __shfl_xor(v, 32));
      tmx[m] = v;
    }
    const bool need = (tmx[0] > mr[0] + 8.f) | (tmx[1] > mr[1] + 8.f);
    if (__any((int)need)) {
#pragma unroll
      for (int m = 0; m < 2; ++m) {
        const float mn = fmaxf(mr[m], tmx[m]);
        const float av = __builtin_amdgcn_exp2f(mr[m] - mn);
        mr[m] = mn;
#pragma unroll
        for (int jd = 0; jd < 8; ++jd)
#pragma unroll
          for (int r = 0; r < 4; ++r) acc[m][jd][r] *= av;
#pragma unroll
        for (int r = 0; r < 4; ++r) accl[m][r] *= av;
      }
    }
#pragma unroll
    for (int m = 0; m < 2; ++m)
#pragma unroll
      for (int jm = 0; jm < 4; ++jm)
#pragma unroll
        for (int r = 0; r < 4; ++r)
          sa[m][jm][r] = __builtin_amdgcn_exp2f(sa[m][jm][r] - mr[m]);
    unsigned pk[2][4][2];
#pragma unroll
    for (int m = 0; m < 2; ++m)
#pragma unroll
      for (int jm = 0; jm < 4; ++jm) {
        asm("v_cvt_pk_bf16_f32 %0, %1, %2" : "=v"(pk[m][jm][0]) : "v"(sa[m][jm][0]), "v"(sa[m][jm][1]));
        asm("v_cvt_pk_bf16_f32 %0, %1, %2" : "=v"(pk[m][jm][1]) : "v"(sa[m][jm][2]), "v"(sa[m][jm][3]));
      }
    const char* vc0 = vbL0 + cur * 16384;
    const char* vc1 = vbL1 + cur * 16384;
    __builtin_amdgcn_s_setprio(1);
#pragma unroll
    for (int kk = 0; kk < 2; ++kk) {
      short8 pt[2];
#pragma unroll
      for (int m = 0; m < 2; ++m) {
        union { unsigned u[4]; short8 s; } pp;
        pp.u[0] = pk[m][kk][0];     pp.u[1] = pk[m][kk][1];
        pp.u[2] = pk[m][kk + 2][0]; pp.u[3] = pk[m][kk + 2][1];
        pt[m] = pp.s;
      }
      const char* vc = kk ? vc1 : vc0;
#pragma unroll
      for (int jd = 0; jd < 8; ++jd) {
        short8 bb = *(const short8*)(vc + jd * 2048);
#pragma unroll
        for (int m = 0; m < 2; ++m)
          acc[m][jd] = __builtin_amdgcn_mfma_f32_16x16x32_bf16(bb, pt[m], acc[m][jd], 0, 0, 0);
      }
#pragma unroll
      for (int m = 0; m < 2; ++m)
        accl[m] = __builtin_amdgcn_mfma_f32_16x16x32_bf16(ones, pt[m], accl[m], 0, 0, 0);
    }
    __builtin_amdgcn_s_setprio(0);
    cur ^= 1;
  }
  __syncthreads();
  float* Ot = (float*)smem;
  float* ot = Ot + wid * 16 * 132;
#pragma unroll
  for (int m = 0; m < 2; ++m) {
    const float inv = 1.f / accl[m][0];
#pragma unroll
    for (int jd = 0; jd < 8; ++jd) {
      f32x4 v;
#pragma unroll
      for (int r = 0; r < 4; ++r) v[r] = acc[m][jd][r] * inv;
      *(f32x4*)&ot[fr * 132 + jd * 16 + gs * 4] = v;
    }
    asm volatile("s_waitcnt lgkmcnt(0)" ::: "memory");
    __builtin_amdgcn_sched_barrier(0);
    const int q = qtm + wid * 32 + m * 16 + (lane >> 2);
    float* od = O + ((long)(b * 4096 + q) * 8 + h) * 128 + (lane & 3) * 32;
#pragma unroll
    for (int j = 0; j < 8; ++j) {
      f32x4 v = *(const f32x4*)&ot[(lane >> 2) * 132 + (lane & 3) * 32 + j * 4];
      *(f32x4*)&od[j * 4] = v;
    }
    asm volatile("s_waitcnt lgkmcnt(0)" ::: "memory");
    __builtin_amdgcn_sched_barrier(0);
  }
}

// ---------- fused router MLP tail + contra-flow + head mixing ----------
__global__ __launch_bounds__(256) void router_mix(const float* __restrict__ hid,
    const float* __restrict__ rb1, const float* __restrict__ rW2, const float* __restrict__ rb2,
    const float* __restrict__ al, const float* __restrict__ O, u16* __restrict__ mixed) {
  const int tok = blockIdx.x;
  const int b = tok >> 12, t = tok & 4095;
  const int tid = threadIdx.x;
  __shared__ float lred[4][8];
  __shared__ float wgt[8];
  __shared__ float ta[8];
  const float hv = fmaxf(hid[(long)tok * 256 + tid] + rb1[tid], 0.f);
  const float4* w4 = (const float4*)(rW2 + tid * 8);
  const float4 wa = w4[0], wb = w4[1];
  float part[8] = {hv * wa.x, hv * wa.y, hv * wa.z, hv * wa.w,
                   hv * wb.x, hv * wb.y, hv * wb.z, hv * wb.w};
#pragma unroll
  for (int h = 0; h < 8; ++h) {
    float v = part[h];
#pragma unroll
    for (int o = 1; o < 64; o <<= 1) v += __shfl_xor(v, o);
    if ((tid & 63) == 0) lred[tid >> 6][h] = v;
  }
  __syncthreads();
  if (tid < 8) ta[tid] = tanhf(al[tid]);
  if (tid == 0) {
    float lg[8], m = -1e30f;
#pragma unroll
    for (int h = 0; h < 8; ++h) {
      lg[h] = lred[0][h] + lred[1][h] + lred[2][h] + lred[3][h] + rb2[h];
      m = fmaxf(m, lg[h]);
    }
    float s = 0.f;
#pragma unroll
    for (int h = 0; h < 8; ++h) { lg[h] = __expf(lg[h] - m); s += lg[h]; }
    const float inv = 1.f / s;
#pragma unroll
    for (int h = 0; h < 8; ++h) wgt[h] = lg[h] * inv;
  }
  __syncthreads();
  if (tid < 128) {
    const long base = (long)tok * 1024 + tid;
    const long rbase = ((long)b * 4096 + (4095 - t)) * 1024 + tid;
    float acc = 0.f;
#pragma unroll
    for (int h = 0; h < 8; ++h)
      acc += wgt[h] * (O[base + h * 128] + ta[h] * O[rbase + h * 128]);
    mixed[(long)tok * 128 + tid] = f2bf(acc);
  }
}

extern "C" void kernel_launch(void* const* d_in, const int* in_sizes, int n_in,
                              void* d_out, int out_size, void* d_ws, size_t ws_size,
                              hipStream_t stream) {
  const float* x    = (const float*)d_in[0];
  const float* Wq   = (const float*)d_in[1];
  const float* Wk   = (const float*)d_in[2];
  const float* Wv   = (const float*)d_in[3];
  const float* bg   = (const float*)d_in[4];
  const float* al   = (const float*)d_in[5];
  const float* rW1  = (const float*)d_in[6];
  const float* rb1  = (const float*)d_in[7];
  const float* rW2  = (const float*)d_in[8];
  const float* rb2  = (const float*)d_in[9];
  const float* Wout = (const float*)d_in[10];
  float* out = (float*)d_out;

  // ---- arena (lifetime overlays, ~95.5 MB) ----
  const size_t MB = 1u << 20;
  char* w = (char*)d_ws;
  u16*   xbf   = (u16*)(w + 0);            // 16 MB [P0-P1]
  float* O     = (float*)(w + 0);          // 32 MB [P4-P5] overlays dead pools
  u16*   Qb    = (u16*)(w + 32 * MB);      // 16 MB [P1-P4]
  u16*   KV    = (u16*)(w + 48 * MB);      // 15 MB [P1-P2]
  u16*   Kp    = (u16*)(w + 48 * MB);      // 7.5MB [P3-P4] overlays dead KV
  u16*   KT    = (u16*)(w + 63 * MB);      // 7.5MB [P2-P3]
  u16*   VT    = (u16*)(w + 70 * MB + 512 * 1024); // 7.5MB [P2-P4]
  float* hid   = (float*)(w + 78 * MB);    //  8 MB [P1-P5]
  u16*   wqT   = (u16*)(w + 86 * MB);      //  2 MB
  u16*   kvT   = (u16*)(w + 88 * MB);      //  4 MB
  u16*   rw1T  = (u16*)(w + 92 * MB);      // 512 KB
  u16*   woutT = (u16*)(w + 92 * MB + 512 * 1024);   // 256 KB
  u16*   crep  = (u16*)(w + 92 * MB + 768 * 1024);   // 257 KB
  u16*   mixed = (u16*)(w + 93 * MB + 512 * 1024);   //  2 MB
  u16*   xp2   = (u16*)(w + 16 * MB);
  u16*   xp4   = (u16*)(w + 24 * MB);
  u16*   xp8   = (u16*)(w + 28 * MB);

  // P0: pooling + weight prep + irfft (one launch)
  prep_all<<<dim3(14976), dim3(256), 0, stream>>>(x, Wq, Wk, Wv, rW1, Wout, bg,
      xbf, xp2, xp4, xp8, wqT, kvT, rw1T, woutT, crep);

  // P1: all projections + router hidden (XCD-swizzled job order)
  gemm_p1<<<dim3(1120), dim3(256), 0, stream>>>(xbf, wqT, kvT, rw1T, Qb, KV, hid);

  // P2: K/V transposes (V keys PV-permuted)
  tpose_all<<<dim3(240, 4, 8), dim3(256), 0, stream>>>(KV, KT, VT);

  // P3: circulant conv (BK=64, 2 blocks/CU)
  conv_k<<<dim3(32, 1, 16), dim3(256), 0, stream>>>(crep, KT, Kp);

  // P4: flash v4
  flash<<<dim3(512), dim3(256), 0, stream>>>(Qb, Kp, VT, O);

  // P5: router + mix, then output projection
  router_mix<<<dim3(8192), dim3(256), 0, stream>>>(hid, rb1, rW2, rb2, al, O, mixed);
  gemm_bt<false><<<dim3(64, 8), dim3(256), 0, stream>>>(mixed, woutT, out,
      128, 128, 128, 1024, 0, 0, 0, 1.f);
}

// Round 15
// 319.917 us; speedup vs baseline: 1.1945x; 1.0315x over previous
//
#include <hip/hip_runtime.h>
#include <hip/hip_bf16.h>

typedef __attribute__((ext_vector_type(8))) short short8;
typedef __attribute__((ext_vector_type(4))) short short4v;
typedef __attribute__((ext_vector_type(4))) float f32x4;
typedef unsigned short u16;

#define T_ 4096
#define D_ 1024
#define ISSL2E (0.08838834764831845f * 1.4426950408889634f)   // 1/sqrt(128) * log2(e)

__device__ __forceinline__ u16 f2bf(float f) {
  union { float f; unsigned u; } v; v.f = f;
  unsigned r = v.u + 0x7FFFu + ((v.u >> 16) & 1u);
  return (u16)(r >> 16);
}

// ---------- fused prep: pooling + weight transposes + irfft, ONE launch ----------
__global__ __launch_bounds__(256) void prep_all(const float* __restrict__ x,
    const float* __restrict__ Wq, const float* __restrict__ Wk, const float* __restrict__ Wv,
    const float* __restrict__ rW1, const float* __restrict__ Wout, const float* __restrict__ bg,
    u16* __restrict__ p1, u16* __restrict__ p2, u16* __restrict__ p4, u16* __restrict__ p8,
    u16* __restrict__ wqT, u16* __restrict__ kvT, u16* __restrict__ rw1T, u16* __restrict__ woutT,
    u16* __restrict__ crep) {
  const int blk = blockIdx.x;
  const int tid = threadIdx.x;
  if (blk < 1024) {                          // ---- pooling ----
    const int b = blk >> 9, t0 = (blk & 511) << 3;
    const float* src = x + ((long)b * T_ + t0) * D_;
#pragma unroll
    for (int j = 0; j < 4; ++j) {
      const int c = tid + j * 256;
      float v[8];
#pragma unroll
      for (int r = 0; r < 8; ++r) v[r] = src[r * D_ + c];
#pragma unroll
      for (int r = 0; r < 8; ++r) p1[((long)b * 4096 + t0 + r) * D_ + c] = f2bf(v[r]);
#pragma unroll
      for (int r = 0; r < 4; ++r)
        p2[((long)b * 2048 + (t0 >> 1) + r) * D_ + c] = f2bf((v[2*r] + v[2*r+1]) * 0.5f);
#pragma unroll
      for (int r = 0; r < 2; ++r)
        p4[((long)b * 1024 + (t0 >> 2) + r) * D_ + c] =
            f2bf((v[4*r] + v[4*r+1] + v[4*r+2] + v[4*r+3]) * 0.25f);
      p8[((long)b * 512 + (t0 >> 3)) * D_ + c] =
          f2bf((v[0]+v[1]+v[2]+v[3]+v[4]+v[5]+v[6]+v[7]) * 0.125f);
    }
    return;
  }
  if (blk < 14848) {                         // ---- weight transposes ----
    const int idx = (blk - 1024) * 256 + tid;
    if (idx < 1048576) {
      const int h = idx >> 17, wi = idx & 131071;
      const int c = wi >> 10, k = wi & 1023;
      wqT[idx] = f2bf(Wq[(long)h * 131072 + k * 128 + c]);
    } else if (idx < 3145728) {
      const int lid = idx - 1048576;
      const int g = lid >> 19, wi = lid & 524287;
      const int n = wi >> 10, k = wi & 1023;
      const int kv = n >> 8, hh = (n >> 7) & 1, c = n & 127;
      const float* W = kv ? Wv : Wk;
      kvT[lid] = f2bf(W[(long)(2 * g + hh) * 131072 + k * 128 + c]);
    } else if (idx < 3407872) {
      const int lid = idx - 3145728;
      const int n = lid >> 10, k = lid & 1023;
      rw1T[lid] = f2bf(rW1[(long)k * 256 + n]);
    } else if (idx < 3538944) {
      const int lid = idx - 3407872;
      const int n = lid >> 7, k = lid & 127;
      woutT[lid] = f2bf(Wout[(long)k * 1024 + n]);
    }
    return;
  }
  // ---- irfft: conv kernel c per head, 4 phase-shifted replicas ----
  const int rel = blk - 14848;
  const int h = rel >> 4, xi = rel & 15;
  const int Tk = 4096 >> (h >> 1);
  const int mask = Tk - 1;
  if (xi * 256 >= Tk) return;
  const int nb = (Tk >> 1) + 1;
  __shared__ float ct[4096];
  __shared__ float wm[2049];
  const float w0 = 6.283185307179586f / (float)Tk;
  for (int j = tid; j < Tk; j += 256) ct[j] = cosf(w0 * (float)j);
  for (int m = tid; m < nb; m += 256) {
    int band = (m * 8) / nb; if (band > 7) band = 7;
    const float g = 1.f / (1.f + expf(-bg[h * 8 + band]));
    const float sc = (m == 0 || m == nb - 1) ? 1.f : 2.f;
    wm[m] = g * sc / (float)Tk;
  }
  __syncthreads();
  const int n = xi * 256 + tid;
  float acc = 0.f;
  int idx = 0;
  for (int m = 0; m < nb; ++m) {
    acc += wm[m] * ct[idx];
    idx += n;
    if (idx >= Tk) idx -= Tk;
  }
  const u16 bf = f2bf(acc);
  u16* hb = crep + (long)h * 16416;
#pragma unroll
  for (int p = 0; p < 4; ++p) {
    const int q = (n - p) & mask;
    hb[p * 4104 + q] = bf;
    if (q < 8) hb[p * 4104 + q + Tk] = bf;
  }
}

// ---------- bf16 tiled transpose for K,V slices (V keys PV-permuted) ----------
__global__ __launch_bounds__(256) void tpose_all(const u16* __restrict__ KV,
                                                 u16* __restrict__ KT, u16* __restrict__ VT) {
  const int xt = blockIdx.x;
  int g, lx;
  if (xt < 128)      { g = 0; lx = xt; }
  else if (xt < 192) { g = 1; lx = xt - 128; }
  else if (xt < 224) { g = 2; lx = xt - 192; }
  else               { g = 3; lx = xt - 224; }
  const int Tk = 4096 >> g;
  const long kvrow[4] = {0, 8192, 12288, 14336};
  const long ktoff[4] = {0, 2097152, 3145728, 3670016};
  __shared__ u16 tile[32][33];
  const int z = blockIdx.z;
  const int b = z & 1, hh = (z >> 1) & 1, kv = z >> 2;
  const u16* src = KV + kvrow[g] * 512 + (long)b * Tk * 512 + kv * 256 + hh * 128;
  u16* dst = (kv ? VT : KT) + ktoff[g] + (long)(hh * 2 + b) * 128 * Tk;
  const int r0 = lx * 32, c0 = blockIdx.y * 32;
  const int ci = threadIdx.x & 31, ri = threadIdx.x >> 5;
#pragma unroll
  for (int j = 0; j < 4; ++j)
    tile[ri + 8 * j][ci] = src[(long)(r0 + ri + 8 * j) * 512 + c0 + ci];
  __syncthreads();
  const int key = r0 + ci;
  const int col = kv ? ((key & ~63) | (((key >> 4) & 1) << 5) | (((key >> 2) & 3) << 3)
                                    | (((key >> 5) & 1) << 2) | (key & 3))
                     : key;
#pragma unroll
  for (int j = 0; j < 4; ++j)
    dst[(long)(c0 + ri + 8 * j) * Tk + col] = tile[ci][ri + 8 * j];
}

// ---------- async global->LDS ----------
__device__ __forceinline__ void gll16(const void* g, void* l) {
  __builtin_amdgcn_global_load_lds((const __attribute__((address_space(1))) void*)g,
                                   (__attribute__((address_space(3))) void*)l, 16, 0, 0);
}

// ---------- shared bf16 MFMA GEMM core (XOR-swizzled LDS) ----------
__device__ __forceinline__ void gemm_core(const u16* __restrict__ A, const u16* __restrict__ Bt,
    void* __restrict__ Cv, int K, int lda, int ldb, int ldc, int tm, int tn, float alpha,
    bool obf, u16 (*lds)[2][128][32]) {
  const int tid = threadIdx.x, lane = tid & 63, wid = tid >> 6;
  const int wr = wid >> 1, wc = wid & 1;
  const int srow = lane >> 2;
  const int scol = ((lane & 3) ^ ((lane >> 3) & 3)) * 8;
  const u16* ga0 = A + (long)(tm + 32 * wid + srow) * lda + scol;
  const u16* ga1 = ga0 + (long)16 * lda;
  const u16* gb0 = Bt + (long)(tn + 32 * wid + srow) * ldb + scol;
  const u16* gb1 = gb0 + (long)16 * ldb;
  f32x4 acc[4][4] = {};
  const int nk = K >> 5;
  gll16(ga0, &lds[0][0][32 * wid][0]);
  gll16(ga1, &lds[0][0][32 * wid + 16][0]);
  gll16(gb0, &lds[0][1][32 * wid][0]);
  gll16(gb1, &lds[0][1][32 * wid + 16][0]);
  int buf = 0;
  const int fr = lane & 15;
  const int fo2 = (((lane >> 4) & 3) ^ ((lane >> 1) & 3)) * 8;
  for (int kt = 0; kt < nk; ++kt) {
    __syncthreads();
    if (kt + 1 < nk) {
      const long ko = (long)(kt + 1) * 32;
      gll16(ga0 + ko, &lds[buf ^ 1][0][32 * wid][0]);
      gll16(ga1 + ko, &lds[buf ^ 1][0][32 * wid + 16][0]);
      gll16(gb0 + ko, &lds[buf ^ 1][1][32 * wid][0]);
      gll16(gb1 + ko, &lds[buf ^ 1][1][32 * wid + 16][0]);
    }
    short8 af[4], bfr[4];
#pragma unroll
    for (int i = 0; i < 4; ++i) {
      af[i]  = *(const short8*)&lds[buf][0][wr * 64 + i * 16 + fr][fo2];
      bfr[i] = *(const short8*)&lds[buf][1][wc * 64 + i * 16 + fr][fo2];
    }
#pragma unroll
    for (int i = 0; i < 4; ++i)
#pragma unroll
      for (int j = 0; j < 4; ++j)
        acc[i][j] = __builtin_amdgcn_mfma_f32_16x16x32_bf16(af[i], bfr[j], acc[i][j], 0, 0, 0);
    buf ^= 1;
  }
  const int er = (lane >> 4) * 4, ec = lane & 15;
  if (obf) {
    u16* C = (u16*)Cv;
#pragma unroll
    for (int i = 0; i < 4; ++i)
#pragma unroll
      for (int j = 0; j < 4; ++j)
#pragma unroll
        for (int r = 0; r < 4; ++r)
          C[(long)(tm + wr * 64 + i * 16 + er + r) * ldc + (tn + wc * 64 + j * 16 + ec)] =
              f2bf(acc[i][j][r] * alpha);
  } else {
    float* C = (float*)Cv;
#pragma unroll
    for (int i = 0; i < 4; ++i)
#pragma unroll
      for (int j = 0; j < 4; ++j)
#pragma unroll
        for (int r = 0; r < 4; ++r)
          C[(long)(tm + wr * 64 + i * 16 + er + r) * ldc + (tn + wc * 64 + j * 16 + ec)] =
              acc[i][j][r] * alpha;
  }
}

template <bool OBF>
__global__ __launch_bounds__(256) void gemm_bt(const u16* __restrict__ A, const u16* __restrict__ Bt,
                                               void* __restrict__ Cv, int K, int lda, int ldb, int ldc,
                                               long abs_, long bbs, long cbs, float alpha) {
  __shared__ u16 lds[2][2][128][32];
  const u16* Az = A + (long)blockIdx.z * abs_;
  const u16* Bz = Bt + (long)blockIdx.z * bbs;
  void* Cz = OBF ? (void*)((u16*)Cv + (long)blockIdx.z * cbs)
                 : (void*)((float*)Cv + (long)blockIdx.z * cbs);
  gemm_core(Az, Bz, Cz, K, lda, ldb, ldc, blockIdx.x * 128, blockIdx.y * 128, alpha, OBF, lds);
}

// ---------- mega-GEMM: Q + KV + router hidden (XCD-swizzled job order) ----------
__global__ __launch_bounds__(256) void gemm_p1(const u16* __restrict__ xbf,
    const u16* __restrict__ wqT, const u16* __restrict__ kvT, const u16* __restrict__ rw1T,
    u16* __restrict__ Qb, u16* __restrict__ KV, float* __restrict__ hid) {
  __shared__ u16 lds[2][2][128][32];
  const int bid = blockIdx.x;
  const int id = (bid & 7) * 140 + (bid >> 3);   // bijective: 1120 = 8 XCDs x 140 jobs
  if (id < 512) {
    gemm_core(xbf, wqT, Qb, 1024, 1024, 1024, 1024,
              (id >> 3) * 128, (id & 7) * 128, 1.f, true, lds);
  } else if (id < 992) {
    const int lid = id - 512;
    const int rt = lid >> 2, y = lid & 3;
    int g, lr;
    if (rt < 64)       { g = 0; lr = rt; }
    else if (rt < 96)  { g = 1; lr = rt - 64; }
    else if (rt < 112) { g = 2; lr = rt - 96; }
    else               { g = 3; lr = rt - 112; }
    const long xofs[4] = {0, 8388608, 12582912, 14680064};
    const long kvrow[4] = {0, 8192, 12288, 14336};
    gemm_core(xbf + xofs[g], kvT + (long)g * 524288, KV + kvrow[g] * 512,
              1024, 1024, 1024, 512, lr * 128, y * 128, 1.f, true, lds);
  } else {
    const int lid = id - 992;
    gemm_core(xbf, rw1T, hid, 1024, 1024, 1024, 256,
              (lid >> 1) * 128, (lid & 1) * 128, 1.f, false, lds);
  }
}

// ---------- circulant conv GEMM, BK=128, compact XCD-chunked grid (240 blocks) ----------
__global__ __launch_bounds__(256) void conv_k(const u16* __restrict__ crep,
    const u16* __restrict__ KT, u16* __restrict__ Kp) {
  const int bid = blockIdx.x;
  const int j = (bid & 7) * 30 + (bid >> 3);     // bijective: 240 = 8 XCDs x 30 jobs
  int z, lx;
  if (j < 128)      { z = j >> 5;             lx = j & 31; }
  else if (j < 192) { z = 4 + ((j - 128) >> 4); lx = (j - 128) & 15; }
  else if (j < 224) { z = 8 + ((j - 192) >> 3); lx = (j - 192) & 7; }
  else              { z = 12 + ((j - 224) >> 2); lx = (j - 224) & 3; }
  const int h = z >> 1, b = z & 1, g = h >> 1;
  const int Tk = 4096 >> g, mask = Tk - 1;
  const int tm = lx << 7;
  __shared__ u16 clds[16416];
  __shared__ u16 blds[2][4][128][32];   // dbuf x 4 K-chunks of 32
  const int tid = threadIdx.x, lane = tid & 63, wid = tid >> 6;
  const int wr = wid >> 1, wc = wid & 1;
  const int srow = lane >> 2;
  const int scol = ((lane & 3) ^ ((lane >> 3) & 3)) * 8;
  const int fr = lane & 15, fo = (lane >> 4) * 8;
  const int fo2 = (((lane >> 4) & 3) ^ ((lane >> 1) & 3)) * 8;
  {
    const short8* src = (const short8*)(crep + (long)h * 16416);
    short8* dst = (short8*)clds;
    for (int jj = tid; jj < 2052; jj += 256) dst[jj] = src[jj];
  }
  const long ktofs = 4194304 - (4194304 >> g);
  const u16* Bt = KT + ktofs + (long)((h & 1) * 2 + b) * 128 * Tk;
  u16* out = Kp + ktofs + ((long)(h & 1) << 8) * Tk + ((long)b << 7) * Tk;
  const u16* gb0 = Bt + (long)(32 * wid + srow) * Tk + scol;
  const u16* gb1 = gb0 + (long)16 * Tk;
  f32x4 acc[4][4] = {};
  int base[4];
#pragma unroll
  for (int i = 0; i < 4; ++i) base[i] = (fo - (tm + wr * 64 + i * 16 + fr)) & mask;
  const int p = base[0] & 3;
  const u16* crow = clds + p * 4104;
  const int nk = Tk >> 7;
#pragma unroll
  for (int c = 0; c < 4; ++c) {
    gll16(gb0 + c * 32, &blds[0][c][32 * wid][0]);
    gll16(gb1 + c * 32, &blds[0][c][32 * wid + 16][0]);
  }
  int buf = 0;
  for (int kt = 0; kt < nk; ++kt) {
    __syncthreads();
    if (kt + 1 < nk) {
      const long ko = (long)(kt + 1) * 128;
#pragma unroll
      for (int c = 0; c < 4; ++c) {
        gll16(gb0 + ko + c * 32, &blds[buf ^ 1][c][32 * wid][0]);
        gll16(gb1 + ko + c * 32, &blds[buf ^ 1][c][32 * wid + 16][0]);
      }
    }
#pragma unroll
    for (int c = 0; c < 4; ++c) {
      short8 af[4], bfr[4];
#pragma unroll
      for (int i = 0; i < 4; ++i) {
        const int a0 = base[i] ^ p;
        short4v lo = *(const short4v*)(crow + a0);
        short4v hi = *(const short4v*)(crow + a0 + 4);
        af[i][0] = lo[0]; af[i][1] = lo[1]; af[i][2] = lo[2]; af[i][3] = lo[3];
        af[i][4] = hi[0]; af[i][5] = hi[1]; af[i][6] = hi[2]; af[i][7] = hi[3];
        base[i] = (base[i] + 32) & mask;
        bfr[i] = *(const short8*)&blds[buf][c][wc * 64 + i * 16 + fr][fo2];
      }
#pragma unroll
      for (int i = 0; i < 4; ++i)
#pragma unroll
        for (int jj = 0; jj < 4; ++jj)
          acc[i][jj] = __builtin_amdgcn_mfma_f32_16x16x32_bf16(af[i], bfr[jj], acc[i][jj], 0, 0, 0);
    }
    buf ^= 1;
  }
  const int er = (lane >> 4) * 4, ec = lane & 15;
#pragma unroll
  for (int i = 0; i < 4; ++i)
#pragma unroll
    for (int jj = 0; jj < 4; ++jj)
#pragma unroll
      for (int r = 0; r < 4; ++r)
        out[(long)(tm + wr * 64 + i * 16 + er + r) * 128 + (wc * 64 + jj * 16 + ec)] =
            f2bf(acc[i][jj][r] * ISSL2E);
}

// ---------- flash attention v4 (known-good) ----------
__global__ __launch_bounds__(256, 2) void flash(const u16* __restrict__ Qb,
    const u16* __restrict__ Kp, const u16* __restrict__ VT, float* __restrict__ O) {
  const int wg = blockIdx.x;
  const int x = wg & 7, s = wg >> 3;
  const int t4 = s >> 4;
  const int lvl = t4 ^ (t4 >> 1);
  const int hh = x >> 2, b = (x >> 1) & 1;
  const int h = lvl * 2 + hh;
  const int qtm = (((x & 1) << 4) + (s & 15)) << 7;
  const int Tk = 4096 >> lvl;
  const int nt = Tk >> 6;

  __shared__ __align__(16) char smem[65536];
  u16 (*Kl)[4][64][32] = (u16(*)[4][64][32])smem;
  u16 (*Vl)[128][64]   = (u16(*)[128][64])(smem + 32768);

  const int tid = threadIdx.x, lane = tid & 63, wid = tid >> 6;
  const int fr = lane & 15, gs = lane >> 4;
  const int fo = gs * 8;
  const int fo2 = ((gs & 3) ^ ((lane >> 1) & 3)) * 8;

  const long ktofs = 4194304 - (4194304 >> lvl);
  const u16* kbase = Kp + ktofs + (long)(hh * 2 + b) * 128 * Tk;
  const u16* vbase = VT + ktofs + (long)(hh * 2 + b) * 128 * Tk;

  short8 aq[2][4];
#pragma unroll
  for (int m = 0; m < 2; ++m)
#pragma unroll
    for (int kk = 0; kk < 4; ++kk)
      aq[m][kk] = *(const short8*)(Qb +
          ((long)(b * 4096 + qtm + wid * 32 + m * 16 + fr)) * 1024 + h * 128 + kk * 32 + fo);

  const u16* kptr = kbase + (long)(lane >> 2) * 128 + wid * 32 +
                    (((lane & 3) ^ ((lane >> 3) & 3)) << 3);
  const u16* vptr = vbase + (long)(32 * wid + (lane >> 3)) * Tk +
                    (((lane & 7) ^ ((lane >> 3) & 7)) << 3);

  const char* kbL  = smem + fr * 64 + fo2 * 2;
  const char* vbL0 = smem + 32768 + fr * 128 + ((((gs    ) ^ (fr & 7)) & 7) << 4);
  const char* vbL1 = smem + 32768 + fr * 128 + ((((gs ^ 4) ^ (fr & 7)) & 7) << 4);

  f32x4 acc[2][8] = {};
  f32x4 accl[2] = {};
  float mr[2] = {-3e38f, -3e38f};

  short8 ones;
#pragma unroll
  for (int i = 0; i < 8; ++i) ones[i] = (short)0x3F80;

#pragma unroll
  for (int i = 0; i < 4; ++i) {
    gll16(kptr + i * 2048, &Kl[0][wid][i * 16][0]);
    gll16(vptr + (long)i * 8 * Tk, &Vl[0][32 * wid + 8 * i][0]);
  }

  int cur = 0;
  for (int kt = 0; kt < nt; ++kt) {
    asm volatile("s_waitcnt vmcnt(0)" ::: "memory");
    __builtin_amdgcn_sched_barrier(0);
    __builtin_amdgcn_s_barrier();
    __builtin_amdgcn_sched_barrier(0);
    if (kt + 1 < nt) {
      const int ktn = kt + 1;
#pragma unroll
      for (int i = 0; i < 4; ++i) {
        gll16(kptr + (long)ktn * 8192 + i * 2048, &Kl[cur ^ 1][wid][i * 16][0]);
        gll16(vptr + (long)ktn * 64 + (long)i * 8 * Tk, &Vl[cur ^ 1][32 * wid + 8 * i][0]);
      }
    }
    const char* kc = kbL + cur * 16384;
    f32x4 sa[2][4] = {};
    __builtin_amdgcn_s_setprio(1);
#pragma unroll
    for (int kk = 0; kk < 4; ++kk) {
      short8 bk[4];
#pragma unroll
      for (int jm = 0; jm < 4; ++jm)
        bk[jm] = *(const short8*)(kc + kk * 4096 + jm * 1024);
#pragma unroll
      for (int m = 0; m < 2; ++m)
#pragma unroll
        for (int jm = 0; jm < 4; ++jm)
          sa[m][jm] = __builtin_amdgcn_mfma_f32_16x16x32_bf16(bk[jm], aq[m][kk], sa[m][jm], 0, 0, 0);
    }
    __builtin_amdgcn_s_setprio(0);
    float tmx[2];
#pragma unroll
    for (int m = 0; m < 2; ++m) {
      float v0 = fmaxf(fmaxf(sa[m][0][0], sa[m][0][1]), fmaxf(sa[m][0][2], sa[m][0][3]));
      float v1 = fmaxf(fmaxf(sa[m][1][0], sa[m][1][1]), fmaxf(sa[m][1][2], sa[m][1][3]));
      float v2 = fmaxf(fmaxf(sa[m][2][0], sa[m][2][1]), fmaxf(sa[m][2][2], sa[m][2][3]));
      float v3 = fmaxf(fmaxf(sa[m][3][0], sa[m][3][1]), fmaxf(sa[m][3][2], sa[m][3][3]));
      float v = fmaxf(fmaxf(v0, v1), fmaxf(v2, v3));
      v = fmaxf(v, __shfl_xor(v, 16));
      v = fmaxf(v, __shfl_xor(v, 32));
      tmx[m] = v;
    }
    const bool need = (tmx[0] > mr[0] + 8.f) | (tmx[1] > mr[1] + 8.f);
    if (__any((int)need)) {
#pragma unroll
      for (int m = 0; m < 2; ++m) {
        const float mn = fmaxf(mr[m], tmx[m]);
        const float av = __builtin_amdgcn_exp2f(mr[m] - mn);
        mr[m] = mn;
#pragma unroll
        for (int jd = 0; jd < 8; ++jd)
#pragma unroll
          for (int r = 0; r < 4; ++r) acc[m][jd][r] *= av;
#pragma unroll
        for (int r = 0; r < 4; ++r) accl[m][r] *= av;
      }
    }
#pragma unroll
    for (int m = 0; m < 2; ++m)
#pragma unroll
      for (int jm = 0; jm < 4; ++jm)
#pragma unroll
        for (int r = 0; r < 4; ++r)
          sa[m][jm][r] = __builtin_amdgcn_exp2f(sa[m][jm][r] - mr[m]);
    unsigned pk[2][4][2];
#pragma unroll
    for (int m = 0; m < 2; ++m)
#pragma unroll
      for (int jm = 0; jm < 4; ++jm) {
        asm("v_cvt_pk_bf16_f32 %0, %1, %2" : "=v"(pk[m][jm][0]) : "v"(sa[m][jm][0]), "v"(sa[m][jm][1]));
        asm("v_cvt_pk_bf16_f32 %0, %1, %2" : "=v"(pk[m][jm][1]) : "v"(sa[m][jm][2]), "v"(sa[m][jm][3]));
      }
    const char* vc0 = vbL0 + cur * 16384;
    const char* vc1 = vbL1 + cur * 16384;
    __builtin_amdgcn_s_setprio(1);
#pragma unroll
    for (int kk = 0; kk < 2; ++kk) {
      short8 pt[2];
#pragma unroll
      for (int m = 0; m < 2; ++m) {
        union { unsigned u[4]; short8 s; } pp;
        pp.u[0] = pk[m][kk][0];     pp.u[1] = pk[m][kk][1];
        pp.u[2] = pk[m][kk + 2][0]; pp.u[3] = pk[m][kk + 2][1];
        pt[m] = pp.s;
      }
      const char* vc = kk ? vc1 : vc0;
#pragma unroll
      for (int jd = 0; jd < 8; ++jd) {
        short8 bb = *(const short8*)(vc + jd * 2048);
#pragma unroll
        for (int m = 0; m < 2; ++m)
          acc[m][jd] = __builtin_amdgcn_mfma_f32_16x16x32_bf16(bb, pt[m], acc[m][jd], 0, 0, 0);
      }
#pragma unroll
      for (int m = 0; m < 2; ++m)
        accl[m] = __builtin_amdgcn_mfma_f32_16x16x32_bf16(ones, pt[m], accl[m], 0, 0, 0);
    }
    __builtin_amdgcn_s_setprio(0);
    cur ^= 1;
  }
  __syncthreads();
  float* Ot = (float*)smem;
  float* ot = Ot + wid * 16 * 132;
#pragma unroll
  for (int m = 0; m < 2; ++m) {
    const float inv = 1.f / accl[m][0];
#pragma unroll
    for (int jd = 0; jd < 8; ++jd) {
      f32x4 v;
#pragma unroll
      for (int r = 0; r < 4; ++r) v[r] = acc[m][jd][r] * inv;
      *(f32x4*)&ot[fr * 132 + jd * 16 + gs * 4] = v;
    }
    asm volatile("s_waitcnt lgkmcnt(0)" ::: "memory");
    __builtin_amdgcn_sched_barrier(0);
    const int q = qtm + wid * 32 + m * 16 + (lane >> 2);
    float* od = O + ((long)(b * 4096 + q) * 8 + h) * 128 + (lane & 3) * 32;
#pragma unroll
    for (int j = 0; j < 8; ++j) {
      f32x4 v = *(const f32x4*)&ot[(lane >> 2) * 132 + (lane & 3) * 32 + j * 4];
      *(f32x4*)&od[j * 4] = v;
    }
    asm volatile("s_waitcnt lgkmcnt(0)" ::: "memory");
    __builtin_amdgcn_sched_barrier(0);
  }
}

// ---------- fused router MLP tail + contra-flow + head mixing ----------
__global__ __launch_bounds__(256) void router_mix(const float* __restrict__ hid,
    const float* __restrict__ rb1, const float* __restrict__ rW2, const float* __restrict__ rb2,
    const float* __restrict__ al, const float* __restrict__ O, u16* __restrict__ mixed) {
  const int tok = blockIdx.x;
  const int b = tok >> 12, t = tok & 4095;
  const int tid = threadIdx.x;
  __shared__ float lred[4][8];
  __shared__ float wgt[8];
  __shared__ float ta[8];
  const float hv = fmaxf(hid[(long)tok * 256 + tid] + rb1[tid], 0.f);
  const float4* w4 = (const float4*)(rW2 + tid * 8);
  const float4 wa = w4[0], wb = w4[1];
  float part[8] = {hv * wa.x, hv * wa.y, hv * wa.z, hv * wa.w,
                   hv * wb.x, hv * wb.y, hv * wb.z, hv * wb.w};
#pragma unroll
  for (int h = 0; h < 8; ++h) {
    float v = part[h];
#pragma unroll
    for (int o = 1; o < 64; o <<= 1) v += __shfl_xor(v, o);
    if ((tid & 63) == 0) lred[tid >> 6][h] = v;
  }
  __syncthreads();
  if (tid < 8) ta[tid] = tanhf(al[tid]);
  if (tid == 0) {
    float lg[8], m = -1e30f;
#pragma unroll
    for (int h = 0; h < 8; ++h) {
      lg[h] = lred[0][h] + lred[1][h] + lred[2][h] + lred[3][h] + rb2[h];
      m = fmaxf(m, lg[h]);
    }
    float s = 0.f;
#pragma unroll
    for (int h = 0; h < 8; ++h) { lg[h] = __expf(lg[h] - m); s += lg[h]; }
    const float inv = 1.f / s;
#pragma unroll
    for (int h = 0; h < 8; ++h) wgt[h] = lg[h] * inv;
  }
  __syncthreads();
  if (tid < 128) {
    const long base = (long)tok * 1024 + tid;
    const long rbase = ((long)b * 4096 + (4095 - t)) * 1024 + tid;
    float acc = 0.f;
#pragma unroll
    for (int h = 0; h < 8; ++h)
      acc += wgt[h] * (O[base + h * 128] + ta[h] * O[rbase + h * 128]);
    mixed[(long)tok * 128 + tid] = f2bf(acc);
  }
}

extern "C" void kernel_launch(void* const* d_in, const int* in_sizes, int n_in,
                              void* d_out, int out_size, void* d_ws, size_t ws_size,
                              hipStream_t stream) {
  const float* x    = (const float*)d_in[0];
  const float* Wq   = (const float*)d_in[1];
  const float* Wk   = (const float*)d_in[2];
  const float* Wv   = (const float*)d_in[3];
  const float* bg   = (const float*)d_in[4];
  const float* al   = (const float*)d_in[5];
  const float* rW1  = (const float*)d_in[6];
  const float* rb1  = (const float*)d_in[7];
  const float* rW2  = (const float*)d_in[8];
  const float* rb2  = (const float*)d_in[9];
  const float* Wout = (const float*)d_in[10];
  float* out = (float*)d_out;

  // ---- arena (lifetime overlays, ~95.5 MB) ----
  const size_t MB = 1u << 20;
  char* w = (char*)d_ws;
  u16*   xbf   = (u16*)(w + 0);            // 16 MB [P0-P1]
  float* O     = (float*)(w + 0);          // 32 MB [P4-P5] overlays dead pools
  u16*   Qb    = (u16*)(w + 32 * MB);      // 16 MB [P1-P4]
  u16*   KV    = (u16*)(w + 48 * MB);      // 15 MB [P1-P2]
  u16*   Kp    = (u16*)(w + 48 * MB);      // 7.5MB [P3-P4] overlays dead KV
  u16*   KT    = (u16*)(w + 63 * MB);      // 7.5MB [P2-P3]
  u16*   VT    = (u16*)(w + 70 * MB + 512 * 1024); // 7.5MB [P2-P4]
  float* hid   = (float*)(w + 78 * MB);    //  8 MB [P1-P5]
  u16*   wqT   = (u16*)(w + 86 * MB);      //  2 MB
  u16*   kvT   = (u16*)(w + 88 * MB);      //  4 MB
  u16*   rw1T  = (u16*)(w + 92 * MB);      // 512 KB
  u16*   woutT = (u16*)(w + 92 * MB + 512 * 1024);   // 256 KB
  u16*   crep  = (u16*)(w + 92 * MB + 768 * 1024);   // 257 KB
  u16*   mixed = (u16*)(w + 93 * MB + 512 * 1024);   //  2 MB
  u16*   xp2   = (u16*)(w + 16 * MB);
  u16*   xp4   = (u16*)(w + 24 * MB);
  u16*   xp8   = (u16*)(w + 28 * MB);

  // P0: pooling + weight prep + irfft (one launch)
  prep_all<<<dim3(14976), dim3(256), 0, stream>>>(x, Wq, Wk, Wv, rW1, Wout, bg,
      xbf, xp2, xp4, xp8, wqT, kvT, rw1T, woutT, crep);

  // P1: all projections + router hidden (XCD-swizzled job order)
  gemm_p1<<<dim3(1120), dim3(256), 0, stream>>>(xbf, wqT, kvT, rw1T, Qb, KV, hid);

  // P2: K/V transposes (V keys PV-permuted)
  tpose_all<<<dim3(240, 4, 8), dim3(256), 0, stream>>>(KV, KT, VT);

  // P3: circulant conv (BK=128, compact XCD-chunked 240-block grid)
  conv_k<<<dim3(240), dim3(256), 0, stream>>>(crep, KT, Kp);

  // P4: flash v4
  flash<<<dim3(512), dim3(256), 0, stream>>>(Qb, Kp, VT, O);

  // P5: router + mix, then output projection
  router_mix<<<dim3(8192), dim3(256), 0, stream>>>(hid, rb1, rW2, rb2, al, O, mixed);
  gemm_bt<false><<<dim3(64, 8), dim3(256), 0, stream>>>(mixed, woutT, out,
      128, 128, 128, 1024, 0, 0, 0, 1.f);
}

// Round 16
// 314.531 us; speedup vs baseline: 1.2150x; 1.0171x over previous
//
#include <hip/hip_runtime.h>
#include <hip/hip_bf16.h>

typedef __attribute__((ext_vector_type(8))) short short8;
typedef __attribute__((ext_vector_type(4))) short short4v;
typedef __attribute__((ext_vector_type(4))) float f32x4;
typedef unsigned short u16;

#define T_ 4096
#define D_ 1024
#define ISSL2E (0.08838834764831845f * 1.4426950408889634f)   // 1/sqrt(128) * log2(e)

__device__ __forceinline__ u16 f2bf(float f) {
  union { float f; unsigned u; } v; v.f = f;
  unsigned r = v.u + 0x7FFFu + ((v.u >> 16) & 1u);
  return (u16)(r >> 16);
}

// ---------- fused prep: pooling + weight transposes + irfft, ONE launch ----------
__global__ __launch_bounds__(256) void prep_all(const float* __restrict__ x,
    const float* __restrict__ Wq, const float* __restrict__ Wk, const float* __restrict__ Wv,
    const float* __restrict__ rW1, const float* __restrict__ Wout, const float* __restrict__ bg,
    u16* __restrict__ p1, u16* __restrict__ p2, u16* __restrict__ p4, u16* __restrict__ p8,
    u16* __restrict__ wqT, u16* __restrict__ kvT, u16* __restrict__ rw1T, u16* __restrict__ woutT,
    u16* __restrict__ crep) {
  const int blk = blockIdx.x;
  const int tid = threadIdx.x;
  if (blk < 1024) {                          // ---- pooling ----
    const int b = blk >> 9, t0 = (blk & 511) << 3;
    const float* src = x + ((long)b * T_ + t0) * D_;
#pragma unroll
    for (int j = 0; j < 4; ++j) {
      const int c = tid + j * 256;
      float v[8];
#pragma unroll
      for (int r = 0; r < 8; ++r) v[r] = src[r * D_ + c];
#pragma unroll
      for (int r = 0; r < 8; ++r) p1[((long)b * 4096 + t0 + r) * D_ + c] = f2bf(v[r]);
#pragma unroll
      for (int r = 0; r < 4; ++r)
        p2[((long)b * 2048 + (t0 >> 1) + r) * D_ + c] = f2bf((v[2*r] + v[2*r+1]) * 0.5f);
#pragma unroll
      for (int r = 0; r < 2; ++r)
        p4[((long)b * 1024 + (t0 >> 2) + r) * D_ + c] =
            f2bf((v[4*r] + v[4*r+1] + v[4*r+2] + v[4*r+3]) * 0.25f);
      p8[((long)b * 512 + (t0 >> 3)) * D_ + c] =
          f2bf((v[0]+v[1]+v[2]+v[3]+v[4]+v[5]+v[6]+v[7]) * 0.125f);
    }
    return;
  }
  if (blk < 14848) {                         // ---- weight transposes ----
    const int idx = (blk - 1024) * 256 + tid;
    if (idx < 1048576) {
      const int h = idx >> 17, wi = idx & 131071;
      const int c = wi >> 10, k = wi & 1023;
      wqT[idx] = f2bf(Wq[(long)h * 131072 + k * 128 + c]);
    } else if (idx < 3145728) {
      const int lid = idx - 1048576;
      const int g = lid >> 19, wi = lid & 524287;
      const int n = wi >> 10, k = wi & 1023;
      const int kv = n >> 8, hh = (n >> 7) & 1, c = n & 127;
      const float* W = kv ? Wv : Wk;
      kvT[lid] = f2bf(W[(long)(2 * g + hh) * 131072 + k * 128 + c]);
    } else if (idx < 3407872) {
      const int lid = idx - 3145728;
      const int n = lid >> 10, k = lid & 1023;
      rw1T[lid] = f2bf(rW1[(long)k * 256 + n]);
    } else if (idx < 3538944) {
      const int lid = idx - 3407872;
      const int n = lid >> 7, k = lid & 127;
      woutT[lid] = f2bf(Wout[(long)k * 1024 + n]);
    }
    return;
  }
  // ---- irfft: conv kernel c per head, 4 phase-shifted replicas ----
  const int rel = blk - 14848;
  const int h = rel >> 4, xi = rel & 15;
  const int Tk = 4096 >> (h >> 1);
  const int mask = Tk - 1;
  if (xi * 256 >= Tk) return;
  const int nb = (Tk >> 1) + 1;
  __shared__ float ct[4096];
  __shared__ float wm[2049];
  const float w0 = 6.283185307179586f / (float)Tk;
  for (int j = tid; j < Tk; j += 256) ct[j] = cosf(w0 * (float)j);
  for (int m = tid; m < nb; m += 256) {
    int band = (m * 8) / nb; if (band > 7) band = 7;
    const float g = 1.f / (1.f + expf(-bg[h * 8 + band]));
    const float sc = (m == 0 || m == nb - 1) ? 1.f : 2.f;
    wm[m] = g * sc / (float)Tk;
  }
  __syncthreads();
  const int n = xi * 256 + tid;
  float acc = 0.f;
  int idx = 0;
  for (int m = 0; m < nb; ++m) {
    acc += wm[m] * ct[idx];
    idx += n;
    if (idx >= Tk) idx -= Tk;
  }
  const u16 bf = f2bf(acc);
  u16* hb = crep + (long)h * 16416;
#pragma unroll
  for (int p = 0; p < 4; ++p) {
    const int q = (n - p) & mask;
    hb[p * 4104 + q] = bf;
    if (q < 8) hb[p * 4104 + q + Tk] = bf;
  }
}

// ---------- async global->LDS ----------
__device__ __forceinline__ void gll16(const void* g, void* l) {
  __builtin_amdgcn_global_load_lds((const __attribute__((address_space(1))) void*)g,
                                   (__attribute__((address_space(3))) void*)l, 16, 0, 0);
}

// ---------- shared bf16 MFMA GEMM core (XOR-swizzled LDS) ----------
// mode: 0 = fp32 C, 1 = bf16 C, 2 = fused K/V transpose write (KTp/VTp/Tkv/bsel used)
__device__ __forceinline__ void gemm_core(const u16* __restrict__ A, const u16* __restrict__ Bt,
    void* __restrict__ Cv, int K, int lda, int ldb, int ldc, int tm, int tn, float alpha,
    int mode, u16 (*lds)[2][128][32],
    u16* KTp = nullptr, u16* VTp = nullptr, int Tkv = 0, int bsel = 0) {
  const int tid = threadIdx.x, lane = tid & 63, wid = tid >> 6;
  const int wr = wid >> 1, wc = wid & 1;
  const int srow = lane >> 2;
  const int scol = ((lane & 3) ^ ((lane >> 3) & 3)) * 8;
  const u16* ga0 = A + (long)(tm + 32 * wid + srow) * lda + scol;
  const u16* ga1 = ga0 + (long)16 * lda;
  const u16* gb0 = Bt + (long)(tn + 32 * wid + srow) * ldb + scol;
  const u16* gb1 = gb0 + (long)16 * ldb;
  f32x4 acc[4][4] = {};
  const int nk = K >> 5;
  gll16(ga0, &lds[0][0][32 * wid][0]);
  gll16(ga1, &lds[0][0][32 * wid + 16][0]);
  gll16(gb0, &lds[0][1][32 * wid][0]);
  gll16(gb1, &lds[0][1][32 * wid + 16][0]);
  int buf = 0;
  const int fr = lane & 15;
  const int fo2 = (((lane >> 4) & 3) ^ ((lane >> 1) & 3)) * 8;
  for (int kt = 0; kt < nk; ++kt) {
    __syncthreads();
    if (kt + 1 < nk) {
      const long ko = (long)(kt + 1) * 32;
      gll16(ga0 + ko, &lds[buf ^ 1][0][32 * wid][0]);
      gll16(ga1 + ko, &lds[buf ^ 1][0][32 * wid + 16][0]);
      gll16(gb0 + ko, &lds[buf ^ 1][1][32 * wid][0]);
      gll16(gb1 + ko, &lds[buf ^ 1][1][32 * wid + 16][0]);
    }
    short8 af[4], bfr[4];
#pragma unroll
    for (int i = 0; i < 4; ++i) {
      af[i]  = *(const short8*)&lds[buf][0][wr * 64 + i * 16 + fr][fo2];
      bfr[i] = *(const short8*)&lds[buf][1][wc * 64 + i * 16 + fr][fo2];
    }
#pragma unroll
    for (int i = 0; i < 4; ++i)
#pragma unroll
      for (int j = 0; j < 4; ++j)
        acc[i][j] = __builtin_amdgcn_mfma_f32_16x16x32_bf16(af[i], bfr[j], acc[i][j], 0, 0, 0);
    buf ^= 1;
  }
  const int er = (lane >> 4) * 4, ec = lane & 15;
  if (mode == 2) {
    // fused transpose: write K/V slices directly (bit-identical to old KV->tpose path)
    const int tb = tm - bsel * Tkv + wr * 64;
#pragma unroll
    for (int i = 0; i < 4; ++i) {
      const int t0 = tb + i * 16 + er;          // 4-aligned key base
      const int kperm = (t0 & ~63) | (((t0 >> 4) & 1) << 5) | (((t0 >> 2) & 3) << 3)
                      | (((t0 >> 5) & 1) << 2); // V key permutation (low2 bits = 0)
#pragma unroll
      for (int j = 0; j < 4; ++j) {
        const int col = tn + wc * 64 + j * 16 + ec;
        const int kv = col >> 8, hh = (col >> 7) & 1, c = col & 127;
        u16* dstb = (kv ? VTp : KTp) + ((long)(hh * 2 + bsel) * 128 + c) * Tkv;
        short4v v;
#pragma unroll
        for (int r = 0; r < 4; ++r) v[r] = (short)f2bf(acc[i][j][r]);
        *(short4v*)(dstb + (kv ? kperm : t0)) = v;
      }
    }
  } else if (mode == 1) {
    u16* C = (u16*)Cv;
#pragma unroll
    for (int i = 0; i < 4; ++i)
#pragma unroll
      for (int j = 0; j < 4; ++j)
#pragma unroll
        for (int r = 0; r < 4; ++r)
          C[(long)(tm + wr * 64 + i * 16 + er + r) * ldc + (tn + wc * 64 + j * 16 + ec)] =
              f2bf(acc[i][j][r] * alpha);
  } else {
    float* C = (float*)Cv;
#pragma unroll
    for (int i = 0; i < 4; ++i)
#pragma unroll
      for (int j = 0; j < 4; ++j)
#pragma unroll
        for (int r = 0; r < 4; ++r)
          C[(long)(tm + wr * 64 + i * 16 + er + r) * ldc + (tn + wc * 64 + j * 16 + ec)] =
              acc[i][j][r] * alpha;
  }
}

template <bool OBF>
__global__ __launch_bounds__(256) void gemm_bt(const u16* __restrict__ A, const u16* __restrict__ Bt,
                                               void* __restrict__ Cv, int K, int lda, int ldb, int ldc,
                                               long abs_, long bbs, long cbs, float alpha) {
  __shared__ u16 lds[2][2][128][32];
  const u16* Az = A + (long)blockIdx.z * abs_;
  const u16* Bz = Bt + (long)blockIdx.z * bbs;
  void* Cz = OBF ? (void*)((u16*)Cv + (long)blockIdx.z * cbs)
                 : (void*)((float*)Cv + (long)blockIdx.z * cbs);
  gemm_core(Az, Bz, Cz, K, lda, ldb, ldc, blockIdx.x * 128, blockIdx.y * 128, alpha,
            OBF ? 1 : 0, lds);
}

// ---------- mega-GEMM: Q + KV(direct-transposed) + router hidden ----------
__global__ __launch_bounds__(256) void gemm_p1(const u16* __restrict__ xbf,
    const u16* __restrict__ wqT, const u16* __restrict__ kvT, const u16* __restrict__ rw1T,
    u16* __restrict__ Qb, u16* __restrict__ KT, u16* __restrict__ VT, float* __restrict__ hid) {
  __shared__ u16 lds[2][2][128][32];
  const int bid = blockIdx.x;
  const int id = (bid & 7) * 140 + (bid >> 3);   // bijective: 1120 = 8 XCDs x 140 jobs
  if (id < 512) {
    gemm_core(xbf, wqT, Qb, 1024, 1024, 1024, 1024,
              (id >> 3) * 128, (id & 7) * 128, 1.f, 1, lds);
  } else if (id < 992) {
    const int lid = id - 512;
    const int rt = lid >> 2, y = lid & 3;
    int g, lr;
    if (rt < 64)       { g = 0; lr = rt; }
    else if (rt < 96)  { g = 1; lr = rt - 64; }
    else if (rt < 112) { g = 2; lr = rt - 96; }
    else               { g = 3; lr = rt - 112; }
    const long xofs[4] = {0, 8388608, 12582912, 14680064};
    const long ktoff[4] = {0, 2097152, 3145728, 3670016};
    const int Tk = 4096 >> g;
    const int tm = lr * 128;
    const int bsel = (tm >= Tk) ? 1 : 0;
    gemm_core(xbf + xofs[g], kvT + (long)g * 524288, nullptr,
              1024, 1024, 1024, 0, tm, y * 128, 1.f, 2, lds,
              KT + ktoff[g], VT + ktoff[g], Tk, bsel);
  } else {
    const int lid = id - 992;
    gemm_core(xbf, rw1T, hid, 1024, 1024, 1024, 256,
              (lid >> 1) * 128, (lid & 1) * 128, 1.f, 0, lds);
  }
}

// ---------- circulant conv GEMM, BK=128, compact XCD-chunked grid (240 blocks) ----------
__global__ __launch_bounds__(256) void conv_k(const u16* __restrict__ crep,
    const u16* __restrict__ KT, u16* __restrict__ Kp) {
  const int bid = blockIdx.x;
  const int j = (bid & 7) * 30 + (bid >> 3);     // bijective: 240 = 8 XCDs x 30 jobs
  int z, lx;
  if (j < 128)      { z = j >> 5;             lx = j & 31; }
  else if (j < 192) { z = 4 + ((j - 128) >> 4); lx = (j - 128) & 15; }
  else if (j < 224) { z = 8 + ((j - 192) >> 3); lx = (j - 192) & 7; }
  else              { z = 12 + ((j - 224) >> 2); lx = (j - 224) & 3; }
  const int h = z >> 1, b = z & 1, g = h >> 1;
  const int Tk = 4096 >> g, mask = Tk - 1;
  const int tm = lx << 7;
  __shared__ u16 clds[16416];
  __shared__ u16 blds[2][4][128][32];
  const int tid = threadIdx.x, lane = tid & 63, wid = tid >> 6;
  const int wr = wid >> 1, wc = wid & 1;
  const int srow = lane >> 2;
  const int scol = ((lane & 3) ^ ((lane >> 3) & 3)) * 8;
  const int fr = lane & 15, fo = (lane >> 4) * 8;
  const int fo2 = (((lane >> 4) & 3) ^ ((lane >> 1) & 3)) * 8;
  {
    const short8* src = (const short8*)(crep + (long)h * 16416);
    short8* dst = (short8*)clds;
    for (int jj = tid; jj < 2052; jj += 256) dst[jj] = src[jj];
  }
  const long ktofs = 4194304 - (4194304 >> g);
  const u16* Bt = KT + ktofs + (long)((h & 1) * 2 + b) * 128 * Tk;
  u16* out = Kp + ktofs + ((long)(h & 1) << 8) * Tk + ((long)b << 7) * Tk;
  const u16* gb0 = Bt + (long)(32 * wid + srow) * Tk + scol;
  const u16* gb1 = gb0 + (long)16 * Tk;
  f32x4 acc[4][4] = {};
  int base[4];
#pragma unroll
  for (int i = 0; i < 4; ++i) base[i] = (fo - (tm + wr * 64 + i * 16 + fr)) & mask;
  const int p = base[0] & 3;
  const u16* crow = clds + p * 4104;
  const int nk = Tk >> 7;
#pragma unroll
  for (int c = 0; c < 4; ++c) {
    gll16(gb0 + c * 32, &blds[0][c][32 * wid][0]);
    gll16(gb1 + c * 32, &blds[0][c][32 * wid + 16][0]);
  }
  int buf = 0;
  for (int kt = 0; kt < nk; ++kt) {
    __syncthreads();
    if (kt + 1 < nk) {
      const long ko = (long)(kt + 1) * 128;
#pragma unroll
      for (int c = 0; c < 4; ++c) {
        gll16(gb0 + ko + c * 32, &blds[buf ^ 1][c][32 * wid][0]);
        gll16(gb1 + ko + c * 32, &blds[buf ^ 1][c][32 * wid + 16][0]);
      }
    }
#pragma unroll
    for (int c = 0; c < 4; ++c) {
      short8 af[4], bfr[4];
#pragma unroll
      for (int i = 0; i < 4; ++i) {
        const int a0 = base[i] ^ p;
        short4v lo = *(const short4v*)(crow + a0);
        short4v hi = *(const short4v*)(crow + a0 + 4);
        af[i][0] = lo[0]; af[i][1] = lo[1]; af[i][2] = lo[2]; af[i][3] = lo[3];
        af[i][4] = hi[0]; af[i][5] = hi[1]; af[i][6] = hi[2]; af[i][7] = hi[3];
        base[i] = (base[i] + 32) & mask;
        bfr[i] = *(const short8*)&blds[buf][c][wc * 64 + i * 16 + fr][fo2];
      }
#pragma unroll
      for (int i = 0; i < 4; ++i)
#pragma unroll
        for (int jj = 0; jj < 4; ++jj)
          acc[i][jj] = __builtin_amdgcn_mfma_f32_16x16x32_bf16(af[i], bfr[jj], acc[i][jj], 0, 0, 0);
    }
    buf ^= 1;
  }
  const int er = (lane >> 4) * 4, ec = lane & 15;
#pragma unroll
  for (int i = 0; i < 4; ++i)
#pragma unroll
    for (int jj = 0; jj < 4; ++jj)
#pragma unroll
      for (int r = 0; r < 4; ++r)
        out[(long)(tm + wr * 64 + i * 16 + er + r) * 128 + (wc * 64 + jj * 16 + ec)] =
            f2bf(acc[i][jj][r] * ISSL2E);
}

// ---------- flash attention v4 (known-good) ----------
__global__ __launch_bounds__(256, 2) void flash(const u16* __restrict__ Qb,
    const u16* __restrict__ Kp, const u16* __restrict__ VT, float* __restrict__ O) {
  const int wg = blockIdx.x;
  const int x = wg & 7, s = wg >> 3;
  const int t4 = s >> 4;
  const int lvl = t4 ^ (t4 >> 1);
  const int hh = x >> 2, b = (x >> 1) & 1;
  const int h = lvl * 2 + hh;
  const int qtm = (((x & 1) << 4) + (s & 15)) << 7;
  const int Tk = 4096 >> lvl;
  const int nt = Tk >> 6;

  __shared__ __align__(16) char smem[65536];
  u16 (*Kl)[4][64][32] = (u16(*)[4][64][32])smem;
  u16 (*Vl)[128][64]   = (u16(*)[128][64])(smem + 32768);

  const int tid = threadIdx.x, lane = tid & 63, wid = tid >> 6;
  const int fr = lane & 15, gs = lane >> 4;
  const int fo = gs * 8;
  const int fo2 = ((gs & 3) ^ ((lane >> 1) & 3)) * 8;

  const long ktofs = 4194304 - (4194304 >> lvl);
  const u16* kbase = Kp + ktofs + (long)(hh * 2 + b) * 128 * Tk;
  const u16* vbase = VT + ktofs + (long)(hh * 2 + b) * 128 * Tk;

  short8 aq[2][4];
#pragma unroll
  for (int m = 0; m < 2; ++m)
#pragma unroll
    for (int kk = 0; kk < 4; ++kk)
      aq[m][kk] = *(const short8*)(Qb +
          ((long)(b * 4096 + qtm + wid * 32 + m * 16 + fr)) * 1024 + h * 128 + kk * 32 + fo);

  const u16* kptr = kbase + (long)(lane >> 2) * 128 + wid * 32 +
                    (((lane & 3) ^ ((lane >> 3) & 3)) << 3);
  const u16* vptr = vbase + (long)(32 * wid + (lane >> 3)) * Tk +
                    (((lane & 7) ^ ((lane >> 3) & 7)) << 3);

  const char* kbL  = smem + fr * 64 + fo2 * 2;
  const char* vbL0 = smem + 32768 + fr * 128 + ((((gs    ) ^ (fr & 7)) & 7) << 4);
  const char* vbL1 = smem + 32768 + fr * 128 + ((((gs ^ 4) ^ (fr & 7)) & 7) << 4);

  f32x4 acc[2][8] = {};
  f32x4 accl[2] = {};
  float mr[2] = {-3e38f, -3e38f};

  short8 ones;
#pragma unroll
  for (int i = 0; i < 8; ++i) ones[i] = (short)0x3F80;

#pragma unroll
  for (int i = 0; i < 4; ++i) {
    gll16(kptr + i * 2048, &Kl[0][wid][i * 16][0]);
    gll16(vptr + (long)i * 8 * Tk, &Vl[0][32 * wid + 8 * i][0]);
  }

  int cur = 0;
  for (int kt = 0; kt < nt; ++kt) {
    asm volatile("s_waitcnt vmcnt(0)" ::: "memory");
    __builtin_amdgcn_sched_barrier(0);
    __builtin_amdgcn_s_barrier();
    __builtin_amdgcn_sched_barrier(0);
    if (kt + 1 < nt) {
      const int ktn = kt + 1;
#pragma unroll
      for (int i = 0; i < 4; ++i) {
        gll16(kptr + (long)ktn * 8192 + i * 2048, &Kl[cur ^ 1][wid][i * 16][0]);
        gll16(vptr + (long)ktn * 64 + (long)i * 8 * Tk, &Vl[cur ^ 1][32 * wid + 8 * i][0]);
      }
    }
    const char* kc = kbL + cur * 16384;
    f32x4 sa[2][4] = {};
    __builtin_amdgcn_s_setprio(1);
#pragma unroll
    for (int kk = 0; kk < 4; ++kk) {
      short8 bk[4];
#pragma unroll
      for (int jm = 0; jm < 4; ++jm)
        bk[jm] = *(const short8*)(kc + kk * 4096 + jm * 1024);
#pragma unroll
      for (int m = 0; m < 2; ++m)
#pragma unroll
        for (int jm = 0; jm < 4; ++jm)
          sa[m][jm] = __builtin_amdgcn_mfma_f32_16x16x32_bf16(bk[jm], aq[m][kk], sa[m][jm], 0, 0, 0);
    }
    __builtin_amdgcn_s_setprio(0);
    float tmx[2];
#pragma unroll
    for (int m = 0; m < 2; ++m) {
      float v0 = fmaxf(fmaxf(sa[m][0][0], sa[m][0][1]), fmaxf(sa[m][0][2], sa[m][0][3]));
      float v1 = fmaxf(fmaxf(sa[m][1][0], sa[m][1][1]), fmaxf(sa[m][1][2], sa[m][1][3]));
      float v2 = fmaxf(fmaxf(sa[m][2][0], sa[m][2][1]), fmaxf(sa[m][2][2], sa[m][2][3]));
      float v3 = fmaxf(fmaxf(sa[m][3][0], sa[m][3][1]), fmaxf(sa[m][3][2], sa[m][3][3]));
      float v = fmaxf(fmaxf(v0, v1), fmaxf(v2, v3));
      v = fmaxf(v, __shfl_xor(v, 16));
      v = fmaxf(v, __shfl_xor(v, 32));
      tmx[m] = v;
    }
    const bool need = (tmx[0] > mr[0] + 8.f) | (tmx[1] > mr[1] + 8.f);
    if (__any((int)need)) {
#pragma unroll
      for (int m = 0; m < 2; ++m) {
        const float mn = fmaxf(mr[m], tmx[m]);
        const float av = __builtin_amdgcn_exp2f(mr[m] - mn);
        mr[m] = mn;
#pragma unroll
        for (int jd = 0; jd < 8; ++jd)
#pragma unroll
          for (int r = 0; r < 4; ++r) acc[m][jd][r] *= av;
#pragma unroll
        for (int r = 0; r < 4; ++r) accl[m][r] *= av;
      }
    }
#pragma unroll
    for (int m = 0; m < 2; ++m)
#pragma unroll
      for (int jm = 0; jm < 4; ++jm)
#pragma unroll
        for (int r = 0; r < 4; ++r)
          sa[m][jm][r] = __builtin_amdgcn_exp2f(sa[m][jm][r] - mr[m]);
    unsigned pk[2][4][2];
#pragma unroll
    for (int m = 0; m < 2; ++m)
#pragma unroll
      for (int jm = 0; jm < 4; ++jm) {
        asm("v_cvt_pk_bf16_f32 %0, %1, %2" : "=v"(pk[m][jm][0]) : "v"(sa[m][jm][0]), "v"(sa[m][jm][1]));
        asm("v_cvt_pk_bf16_f32 %0, %1, %2" : "=v"(pk[m][jm][1]) : "v"(sa[m][jm][2]), "v"(sa[m][jm][3]));
      }
    const char* vc0 = vbL0 + cur * 16384;
    const char* vc1 = vbL1 + cur * 16384;
    __builtin_amdgcn_s_setprio(1);
#pragma unroll
    for (int kk = 0; kk < 2; ++kk) {
      short8 pt[2];
#pragma unroll
      for (int m = 0; m < 2; ++m) {
        union { unsigned u[4]; short8 s; } pp;
        pp.u[0] = pk[m][kk][0];     pp.u[1] = pk[m][kk][1];
        pp.u[2] = pk[m][kk + 2][0]; pp.u[3] = pk[m][kk + 2][1];
        pt[m] = pp.s;
      }
      const char* vc = kk ? vc1 : vc0;
#pragma unroll
      for (int jd = 0; jd < 8; ++jd) {
        short8 bb = *(const short8*)(vc + jd * 2048);
#pragma unroll
        for (int m = 0; m < 2; ++m)
          acc[m][jd] = __builtin_amdgcn_mfma_f32_16x16x32_bf16(bb, pt[m], acc[m][jd], 0, 0, 0);
      }
#pragma unroll
      for (int m = 0; m < 2; ++m)
        accl[m] = __builtin_amdgcn_mfma_f32_16x16x32_bf16(ones, pt[m], accl[m], 0, 0, 0);
    }
    __builtin_amdgcn_s_setprio(0);
    cur ^= 1;
  }
  __syncthreads();
  float* Ot = (float*)smem;
  float* ot = Ot + wid * 16 * 132;
#pragma unroll
  for (int m = 0; m < 2; ++m) {
    const float inv = 1.f / accl[m][0];
#pragma unroll
    for (int jd = 0; jd < 8; ++jd) {
      f32x4 v;
#pragma unroll
      for (int r = 0; r < 4; ++r) v[r] = acc[m][jd][r] * inv;
      *(f32x4*)&ot[fr * 132 + jd * 16 + gs * 4] = v;
    }
    asm volatile("s_waitcnt lgkmcnt(0)" ::: "memory");
    __builtin_amdgcn_sched_barrier(0);
    const int q = qtm + wid * 32 + m * 16 + (lane >> 2);
    float* od = O + ((long)(b * 4096 + q) * 8 + h) * 128 + (lane & 3) * 32;
#pragma unroll
    for (int j = 0; j < 8; ++j) {
      f32x4 v = *(const f32x4*)&ot[(lane >> 2) * 132 + (lane & 3) * 32 + j * 4];
      *(f32x4*)&od[j * 4] = v;
    }
    asm volatile("s_waitcnt lgkmcnt(0)" ::: "memory");
    __builtin_amdgcn_sched_barrier(0);
  }
}

// ---------- fused router MLP tail + contra-flow + head mixing ----------
__global__ __launch_bounds__(256) void router_mix(const float* __restrict__ hid,
    const float* __restrict__ rb1, const float* __restrict__ rW2, const float* __restrict__ rb2,
    const float* __restrict__ al, const float* __restrict__ O, u16* __restrict__ mixed) {
  const int tok = blockIdx.x;
  const int b = tok >> 12, t = tok & 4095;
  const int tid = threadIdx.x;
  __shared__ float lred[4][8];
  __shared__ float wgt[8];
  __shared__ float ta[8];
  const float hv = fmaxf(hid[(long)tok * 256 + tid] + rb1[tid], 0.f);
  const float4* w4 = (const float4*)(rW2 + tid * 8);
  const float4 wa = w4[0], wb = w4[1];
  float part[8] = {hv * wa.x, hv * wa.y, hv * wa.z, hv * wa.w,
                   hv * wb.x, hv * wb.y, hv * wb.z, hv * wb.w};
#pragma unroll
  for (int h = 0; h < 8; ++h) {
    float v = part[h];
#pragma unroll
    for (int o = 1; o < 64; o <<= 1) v += __shfl_xor(v, o);
    if ((tid & 63) == 0) lred[tid >> 6][h] = v;
  }
  __syncthreads();
  if (tid < 8) ta[tid] = tanhf(al[tid]);
  if (tid == 0) {
    float lg[8], m = -1e30f;
#pragma unroll
    for (int h = 0; h < 8; ++h) {
      lg[h] = lred[0][h] + lred[1][h] + lred[2][h] + lred[3][h] + rb2[h];
      m = fmaxf(m, lg[h]);
    }
    float s = 0.f;
#pragma unroll
    for (int h = 0; h < 8; ++h) { lg[h] = __expf(lg[h] - m); s += lg[h]; }
    const float inv = 1.f / s;
#pragma unroll
    for (int h = 0; h < 8; ++h) wgt[h] = lg[h] * inv;
  }
  __syncthreads();
  if (tid < 128) {
    const long base = (long)tok * 1024 + tid;
    const long rbase = ((long)b * 4096 + (4095 - t)) * 1024 + tid;
    float acc = 0.f;
#pragma unroll
    for (int h = 0; h < 8; ++h)
      acc += wgt[h] * (O[base + h * 128] + ta[h] * O[rbase + h * 128]);
    mixed[(long)tok * 128 + tid] = f2bf(acc);
  }
}

extern "C" void kernel_launch(void* const* d_in, const int* in_sizes, int n_in,
                              void* d_out, int out_size, void* d_ws, size_t ws_size,
                              hipStream_t stream) {
  const float* x    = (const float*)d_in[0];
  const float* Wq   = (const float*)d_in[1];
  const float* Wk   = (const float*)d_in[2];
  const float* Wv   = (const float*)d_in[3];
  const float* bg   = (const float*)d_in[4];
  const float* al   = (const float*)d_in[5];
  const float* rW1  = (const float*)d_in[6];
  const float* rb1  = (const float*)d_in[7];
  const float* rW2  = (const float*)d_in[8];
  const float* rb2  = (const float*)d_in[9];
  const float* Wout = (const float*)d_in[10];
  float* out = (float*)d_out;

  // ---- arena (lifetime overlays, ~95.5 MB) ----
  const size_t MB = 1u << 20;
  char* w = (char*)d_ws;
  u16*   xbf   = (u16*)(w + 0);            // 16 MB [P0-P1]
  float* O     = (float*)(w + 0);          // 32 MB [P4-P5] overlays dead pools
  u16*   Qb    = (u16*)(w + 32 * MB);      // 16 MB [P1-P4]
  u16*   Kp    = (u16*)(w + 48 * MB);      // 7.5MB [P3-P4]
  u16*   KT    = (u16*)(w + 63 * MB);      // 7.5MB [P1-P3]
  u16*   VT    = (u16*)(w + 70 * MB + 512 * 1024); // 7.5MB [P1-P4]
  float* hid   = (float*)(w + 78 * MB);    //  8 MB [P1-P5]
  u16*   wqT   = (u16*)(w + 86 * MB);      //  2 MB
  u16*   kvT   = (u16*)(w + 88 * MB);      //  4 MB
  u16*   rw1T  = (u16*)(w + 92 * MB);      // 512 KB
  u16*   woutT = (u16*)(w + 92 * MB + 512 * 1024);   // 256 KB
  u16*   crep  = (u16*)(w + 92 * MB + 768 * 1024);   // 257 KB
  u16*   mixed = (u16*)(w + 93 * MB + 512 * 1024);   //  2 MB
  u16*   xp2   = (u16*)(w + 16 * MB);
  u16*   xp4   = (u16*)(w + 24 * MB);
  u16*   xp8   = (u16*)(w + 28 * MB);

  // P0: pooling + weight prep + irfft (one launch)
  prep_all<<<dim3(14976), dim3(256), 0, stream>>>(x, Wq, Wk, Wv, rW1, Wout, bg,
      xbf, xp2, xp4, xp8, wqT, kvT, rw1T, woutT, crep);

  // P1: Q + KV (direct-transposed KT/VT) + router hidden, one launch
  gemm_p1<<<dim3(1120), dim3(256), 0, stream>>>(xbf, wqT, kvT, rw1T, Qb, KT, VT, hid);

  // P3: circulant conv (BK=128, compact XCD-chunked 240-block grid)
  conv_k<<<dim3(240), dim3(256), 0, stream>>>(crep, KT, Kp);

  // P4: flash v4
  flash<<<dim3(512), dim3(256), 0, stream>>>(Qb, Kp, VT, O);

  // P5: router + mix, then output projection
  router_mix<<<dim3(8192), dim3(256), 0, stream>>>(hid, rb1, rW2, rb2, al, O, mixed);
  gemm_bt<false><<<dim3(64, 8), dim3(256), 0, stream>>>(mixed, woutT, out,
      128, 128, 128, 1024, 0, 0, 0, 1.f);
}

// Round 17
// 312.227 us; speedup vs baseline: 1.2240x; 1.0074x over previous
//
#include <hip/hip_runtime.h>
#include <hip/hip_bf16.h>

typedef __attribute__((ext_vector_type(8))) short short8;
typedef __attribute__((ext_vector_type(4))) short short4v;
typedef __attribute__((ext_vector_type(4))) float f32x4;
typedef unsigned short u16;

#define T_ 4096
#define D_ 1024
#define ISSL2E (0.08838834764831845f * 1.4426950408889634f)   // 1/sqrt(128) * log2(e)

__device__ __forceinline__ u16 f2bf(float f) {
  union { float f; unsigned u; } v; v.f = f;
  unsigned r = v.u + 0x7FFFu + ((v.u >> 16) & 1u);
  return (u16)(r >> 16);
}
__device__ __forceinline__ float bf2f(u16 u) {
  union { unsigned u; float f; } v; v.u = ((unsigned)u) << 16; return v.f;
}

// ---------- fused prep: pooling + weight transposes + irfft, ONE launch ----------
__global__ __launch_bounds__(256) void prep_all(const float* __restrict__ x,
    const float* __restrict__ Wq, const float* __restrict__ Wk, const float* __restrict__ Wv,
    const float* __restrict__ rW1, const float* __restrict__ Wout, const float* __restrict__ bg,
    u16* __restrict__ p1, u16* __restrict__ p2, u16* __restrict__ p4, u16* __restrict__ p8,
    u16* __restrict__ wqT, u16* __restrict__ kvT, u16* __restrict__ rw1T, u16* __restrict__ woutT,
    u16* __restrict__ crep) {
  const int blk = blockIdx.x;
  const int tid = threadIdx.x;
  if (blk < 1024) {                          // ---- pooling ----
    const int b = blk >> 9, t0 = (blk & 511) << 3;
    const float* src = x + ((long)b * T_ + t0) * D_;
#pragma unroll
    for (int j = 0; j < 4; ++j) {
      const int c = tid + j * 256;
      float v[8];
#pragma unroll
      for (int r = 0; r < 8; ++r) v[r] = src[r * D_ + c];
#pragma unroll
      for (int r = 0; r < 8; ++r) p1[((long)b * 4096 + t0 + r) * D_ + c] = f2bf(v[r]);
#pragma unroll
      for (int r = 0; r < 4; ++r)
        p2[((long)b * 2048 + (t0 >> 1) + r) * D_ + c] = f2bf((v[2*r] + v[2*r+1]) * 0.5f);
#pragma unroll
      for (int r = 0; r < 2; ++r)
        p4[((long)b * 1024 + (t0 >> 2) + r) * D_ + c] =
            f2bf((v[4*r] + v[4*r+1] + v[4*r+2] + v[4*r+3]) * 0.25f);
      p8[((long)b * 512 + (t0 >> 3)) * D_ + c] =
          f2bf((v[0]+v[1]+v[2]+v[3]+v[4]+v[5]+v[6]+v[7]) * 0.125f);
    }
    return;
  }
  if (blk < 14848) {                         // ---- weight transposes ----
    const int idx = (blk - 1024) * 256 + tid;
    if (idx < 1048576) {
      const int h = idx >> 17, wi = idx & 131071;
      const int c = wi >> 10, k = wi & 1023;
      wqT[idx] = f2bf(Wq[(long)h * 131072 + k * 128 + c]);
    } else if (idx < 3145728) {
      const int lid = idx - 1048576;
      const int g = lid >> 19, wi = lid & 524287;
      const int n = wi >> 10, k = wi & 1023;
      const int kv = n >> 8, hh = (n >> 7) & 1, c = n & 127;
      const float* W = kv ? Wv : Wk;
      kvT[lid] = f2bf(W[(long)(2 * g + hh) * 131072 + k * 128 + c]);
    } else if (idx < 3407872) {
      const int lid = idx - 3145728;
      const int n = lid >> 10, k = lid & 1023;
      rw1T[lid] = f2bf(rW1[(long)k * 256 + n]);
    } else if (idx < 3538944) {
      const int lid = idx - 3407872;
      const int n = lid >> 7, k = lid & 127;
      woutT[lid] = f2bf(Wout[(long)k * 1024 + n]);
    }
    return;
  }
  // ---- irfft: conv kernel c per head, 4 phase-shifted replicas ----
  const int rel = blk - 14848;
  const int h = rel >> 4, xi = rel & 15;
  const int Tk = 4096 >> (h >> 1);
  const int mask = Tk - 1;
  if (xi * 256 >= Tk) return;
  const int nb = (Tk >> 1) + 1;
  __shared__ float ct[4096];
  __shared__ float wm[2049];
  const float w0 = 6.283185307179586f / (float)Tk;
  for (int j = tid; j < Tk; j += 256) ct[j] = cosf(w0 * (float)j);
  for (int m = tid; m < nb; m += 256) {
    int band = (m * 8) / nb; if (band > 7) band = 7;
    const float g = 1.f / (1.f + expf(-bg[h * 8 + band]));
    const float sc = (m == 0 || m == nb - 1) ? 1.f : 2.f;
    wm[m] = g * sc / (float)Tk;
  }
  __syncthreads();
  const int n = xi * 256 + tid;
  float acc = 0.f;
  int idx = 0;
  for (int m = 0; m < nb; ++m) {
    acc += wm[m] * ct[idx];
    idx += n;
    if (idx >= Tk) idx -= Tk;
  }
  const u16 bf = f2bf(acc);
  u16* hb = crep + (long)h * 16416;
#pragma unroll
  for (int p = 0; p < 4; ++p) {
    const int q = (n - p) & mask;
    hb[p * 4104 + q] = bf;
    if (q < 8) hb[p * 4104 + q + Tk] = bf;
  }
}

// ---------- async global->LDS ----------
__device__ __forceinline__ void gll16(const void* g, void* l) {
  __builtin_amdgcn_global_load_lds((const __attribute__((address_space(1))) void*)g,
                                   (__attribute__((address_space(3))) void*)l, 16, 0, 0);
}

// ---------- shared bf16 MFMA GEMM core (XOR-swizzled LDS) ----------
// mode: 0 = fp32 C, 1 = bf16 C, 2 = fused K/V transpose write (KTp/VTp/Tkv/bsel used)
__device__ __forceinline__ void gemm_core(const u16* __restrict__ A, const u16* __restrict__ Bt,
    void* __restrict__ Cv, int K, int lda, int ldb, int ldc, int tm, int tn, float alpha,
    int mode, u16 (*lds)[2][128][32],
    u16* KTp = nullptr, u16* VTp = nullptr, int Tkv = 0, int bsel = 0) {
  const int tid = threadIdx.x, lane = tid & 63, wid = tid >> 6;
  const int wr = wid >> 1, wc = wid & 1;
  const int srow = lane >> 2;
  const int scol = ((lane & 3) ^ ((lane >> 3) & 3)) * 8;
  const u16* ga0 = A + (long)(tm + 32 * wid + srow) * lda + scol;
  const u16* ga1 = ga0 + (long)16 * lda;
  const u16* gb0 = Bt + (long)(tn + 32 * wid + srow) * ldb + scol;
  const u16* gb1 = gb0 + (long)16 * ldb;
  f32x4 acc[4][4] = {};
  const int nk = K >> 5;
  gll16(ga0, &lds[0][0][32 * wid][0]);
  gll16(ga1, &lds[0][0][32 * wid + 16][0]);
  gll16(gb0, &lds[0][1][32 * wid][0]);
  gll16(gb1, &lds[0][1][32 * wid + 16][0]);
  int buf = 0;
  const int fr = lane & 15;
  const int fo2 = (((lane >> 4) & 3) ^ ((lane >> 1) & 3)) * 8;
  for (int kt = 0; kt < nk; ++kt) {
    __syncthreads();
    if (kt + 1 < nk) {
      const long ko = (long)(kt + 1) * 32;
      gll16(ga0 + ko, &lds[buf ^ 1][0][32 * wid][0]);
      gll16(ga1 + ko, &lds[buf ^ 1][0][32 * wid + 16][0]);
      gll16(gb0 + ko, &lds[buf ^ 1][1][32 * wid][0]);
      gll16(gb1 + ko, &lds[buf ^ 1][1][32 * wid + 16][0]);
    }
    short8 af[4], bfr[4];
#pragma unroll
    for (int i = 0; i < 4; ++i) {
      af[i]  = *(const short8*)&lds[buf][0][wr * 64 + i * 16 + fr][fo2];
      bfr[i] = *(const short8*)&lds[buf][1][wc * 64 + i * 16 + fr][fo2];
    }
#pragma unroll
    for (int i = 0; i < 4; ++i)
#pragma unroll
      for (int j = 0; j < 4; ++j)
        acc[i][j] = __builtin_amdgcn_mfma_f32_16x16x32_bf16(af[i], bfr[j], acc[i][j], 0, 0, 0);
    buf ^= 1;
  }
  const int er = (lane >> 4) * 4, ec = lane & 15;
  if (mode == 2) {
    const int tb = tm - bsel * Tkv + wr * 64;
#pragma unroll
    for (int i = 0; i < 4; ++i) {
      const int t0 = tb + i * 16 + er;
      const int kperm = (t0 & ~63) | (((t0 >> 4) & 1) << 5) | (((t0 >> 2) & 3) << 3)
                      | (((t0 >> 5) & 1) << 2);
#pragma unroll
      for (int j = 0; j < 4; ++j) {
        const int col = tn + wc * 64 + j * 16 + ec;
        const int kv = col >> 8, hh = (col >> 7) & 1, c = col & 127;
        u16* dstb = (kv ? VTp : KTp) + ((long)(hh * 2 + bsel) * 128 + c) * Tkv;
        short4v v;
#pragma unroll
        for (int r = 0; r < 4; ++r) v[r] = (short)f2bf(acc[i][j][r]);
        *(short4v*)(dstb + (kv ? kperm : t0)) = v;
      }
    }
  } else if (mode == 1) {
    u16* C = (u16*)Cv;
#pragma unroll
    for (int i = 0; i < 4; ++i)
#pragma unroll
      for (int j = 0; j < 4; ++j)
#pragma unroll
        for (int r = 0; r < 4; ++r)
          C[(long)(tm + wr * 64 + i * 16 + er + r) * ldc + (tn + wc * 64 + j * 16 + ec)] =
              f2bf(acc[i][j][r] * alpha);
  } else {
    float* C = (float*)Cv;
#pragma unroll
    for (int i = 0; i < 4; ++i)
#pragma unroll
      for (int j = 0; j < 4; ++j)
#pragma unroll
        for (int r = 0; r < 4; ++r)
          C[(long)(tm + wr * 64 + i * 16 + er + r) * ldc + (tn + wc * 64 + j * 16 + ec)] =
              acc[i][j][r] * alpha;
  }
}

template <bool OBF>
__global__ __launch_bounds__(256) void gemm_bt(const u16* __restrict__ A, const u16* __restrict__ Bt,
                                               void* __restrict__ Cv, int K, int lda, int ldb, int ldc,
                                               long abs_, long bbs, long cbs, float alpha) {
  __shared__ u16 lds[2][2][128][32];
  const u16* Az = A + (long)blockIdx.z * abs_;
  const u16* Bz = Bt + (long)blockIdx.z * bbs;
  void* Cz = OBF ? (void*)((u16*)Cv + (long)blockIdx.z * cbs)
                 : (void*)((float*)Cv + (long)blockIdx.z * cbs);
  gemm_core(Az, Bz, Cz, K, lda, ldb, ldc, blockIdx.x * 128, blockIdx.y * 128, alpha,
            OBF ? 1 : 0, lds);
}

// ---------- mega-GEMM: Q + KV(direct-transposed) + router hidden ----------
__global__ __launch_bounds__(256) void gemm_p1(const u16* __restrict__ xbf,
    const u16* __restrict__ wqT, const u16* __restrict__ kvT, const u16* __restrict__ rw1T,
    u16* __restrict__ Qb, u16* __restrict__ KT, u16* __restrict__ VT, float* __restrict__ hid) {
  __shared__ u16 lds[2][2][128][32];
  const int bid = blockIdx.x;
  const int id = (bid & 7) * 140 + (bid >> 3);   // bijective: 1120 = 8 XCDs x 140 jobs
  if (id < 512) {
    gemm_core(xbf, wqT, Qb, 1024, 1024, 1024, 1024,
              (id >> 3) * 128, (id & 7) * 128, 1.f, 1, lds);
  } else if (id < 992) {
    const int lid = id - 512;
    const int rt = lid >> 2, y = lid & 3;
    int g, lr;
    if (rt < 64)       { g = 0; lr = rt; }
    else if (rt < 96)  { g = 1; lr = rt - 64; }
    else if (rt < 112) { g = 2; lr = rt - 96; }
    else               { g = 3; lr = rt - 112; }
    const long xofs[4] = {0, 8388608, 12582912, 14680064};
    const long ktoff[4] = {0, 2097152, 3145728, 3670016};
    const int Tk = 4096 >> g;
    const int tm = lr * 128;
    const int bsel = (tm >= Tk) ? 1 : 0;
    gemm_core(xbf + xofs[g], kvT + (long)g * 524288, nullptr,
              1024, 1024, 1024, 0, tm, y * 128, 1.f, 2, lds,
              KT + ktoff[g], VT + ktoff[g], Tk, bsel);
  } else {
    const int lid = id - 992;
    gemm_core(xbf, rw1T, hid, 1024, 1024, 1024, 256,
              (lid >> 1) * 128, (lid & 1) * 128, 1.f, 0, lds);
  }
}

// ---------- circulant conv GEMM, BK=128, compact XCD-chunked grid (240 blocks) ----------
__global__ __launch_bounds__(256) void conv_k(const u16* __restrict__ crep,
    const u16* __restrict__ KT, u16* __restrict__ Kp) {
  const int bid = blockIdx.x;
  const int j = (bid & 7) * 30 + (bid >> 3);     // bijective: 240 = 8 XCDs x 30 jobs
  int z, lx;
  if (j < 128)      { z = j >> 5;             lx = j & 31; }
  else if (j < 192) { z = 4 + ((j - 128) >> 4); lx = (j - 128) & 15; }
  else if (j < 224) { z = 8 + ((j - 192) >> 3); lx = (j - 192) & 7; }
  else              { z = 12 + ((j - 224) >> 2); lx = (j - 224) & 3; }
  const int h = z >> 1, b = z & 1, g = h >> 1;
  const int Tk = 4096 >> g, mask = Tk - 1;
  const int tm = lx << 7;
  __shared__ u16 clds[16416];
  __shared__ u16 blds[2][4][128][32];
  const int tid = threadIdx.x, lane = tid & 63, wid = tid >> 6;
  const int wr = wid >> 1, wc = wid & 1;
  const int srow = lane >> 2;
  const int scol = ((lane & 3) ^ ((lane >> 3) & 3)) * 8;
  const int fr = lane & 15, fo = (lane >> 4) * 8;
  const int fo2 = (((lane >> 4) & 3) ^ ((lane >> 1) & 3)) * 8;
  {
    const short8* src = (const short8*)(crep + (long)h * 16416);
    short8* dst = (short8*)clds;
    for (int jj = tid; jj < 2052; jj += 256) dst[jj] = src[jj];
  }
  const long ktofs = 4194304 - (4194304 >> g);
  const u16* Bt = KT + ktofs + (long)((h & 1) * 2 + b) * 128 * Tk;
  u16* out = Kp + ktofs + ((long)(h & 1) << 8) * Tk + ((long)b << 7) * Tk;
  const u16* gb0 = Bt + (long)(32 * wid + srow) * Tk + scol;
  const u16* gb1 = gb0 + (long)16 * Tk;
  f32x4 acc[4][4] = {};
  int base[4];
#pragma unroll
  for (int i = 0; i < 4; ++i) base[i] = (fo - (tm + wr * 64 + i * 16 + fr)) & mask;
  const int p = base[0] & 3;
  const u16* crow = clds + p * 4104;
  const int nk = Tk >> 7;
#pragma unroll
  for (int c = 0; c < 4; ++c) {
    gll16(gb0 + c * 32, &blds[0][c][32 * wid][0]);
    gll16(gb1 + c * 32, &blds[0][c][32 * wid + 16][0]);
  }
  int buf = 0;
  for (int kt = 0; kt < nk; ++kt) {
    __syncthreads();
    if (kt + 1 < nk) {
      const long ko = (long)(kt + 1) * 128;
#pragma unroll
      for (int c = 0; c < 4; ++c) {
        gll16(gb0 + ko + c * 32, &blds[buf ^ 1][c][32 * wid][0]);
        gll16(gb1 + ko + c * 32, &blds[buf ^ 1][c][32 * wid + 16][0]);
      }
    }
#pragma unroll
    for (int c = 0; c < 4; ++c) {
      short8 af[4], bfr[4];
#pragma unroll
      for (int i = 0; i < 4; ++i) {
        const int a0 = base[i] ^ p;
        short4v lo = *(const short4v*)(crow + a0);
        short4v hi = *(const short4v*)(crow + a0 + 4);
        af[i][0] = lo[0]; af[i][1] = lo[1]; af[i][2] = lo[2]; af[i][3] = lo[3];
        af[i][4] = hi[0]; af[i][5] = hi[1]; af[i][6] = hi[2]; af[i][7] = hi[3];
        base[i] = (base[i] + 32) & mask;
        bfr[i] = *(const short8*)&blds[buf][c][wc * 64 + i * 16 + fr][fo2];
      }
#pragma unroll
      for (int i = 0; i < 4; ++i)
#pragma unroll
        for (int jj = 0; jj < 4; ++jj)
          acc[i][jj] = __builtin_amdgcn_mfma_f32_16x16x32_bf16(af[i], bfr[jj], acc[i][jj], 0, 0, 0);
    }
    buf ^= 1;
  }
  const int er = (lane >> 4) * 4, ec = lane & 15;
#pragma unroll
  for (int i = 0; i < 4; ++i)
#pragma unroll
    for (int jj = 0; jj < 4; ++jj)
#pragma unroll
      for (int r = 0; r < 4; ++r)
        out[(long)(tm + wr * 64 + i * 16 + er + r) * 128 + (wc * 64 + jj * 16 + ec)] =
            f2bf(acc[i][jj][r] * ISSL2E);
}

// ---------- flash attention v4, bf16 O output ----------
__global__ __launch_bounds__(256, 2) void flash(const u16* __restrict__ Qb,
    const u16* __restrict__ Kp, const u16* __restrict__ VT, u16* __restrict__ O) {
  const int wg = blockIdx.x;
  const int x = wg & 7, s = wg >> 3;
  const int t4 = s >> 4;
  const int lvl = t4 ^ (t4 >> 1);
  const int hh = x >> 2, b = (x >> 1) & 1;
  const int h = lvl * 2 + hh;
  const int qtm = (((x & 1) << 4) + (s & 15)) << 7;
  const int Tk = 4096 >> lvl;
  const int nt = Tk >> 6;

  __shared__ __align__(16) char smem[65536];
  u16 (*Kl)[4][64][32] = (u16(*)[4][64][32])smem;
  u16 (*Vl)[128][64]   = (u16(*)[128][64])(smem + 32768);

  const int tid = threadIdx.x, lane = tid & 63, wid = tid >> 6;
  const int fr = lane & 15, gs = lane >> 4;
  const int fo = gs * 8;
  const int fo2 = ((gs & 3) ^ ((lane >> 1) & 3)) * 8;

  const long ktofs = 4194304 - (4194304 >> lvl);
  const u16* kbase = Kp + ktofs + (long)(hh * 2 + b) * 128 * Tk;
  const u16* vbase = VT + ktofs + (long)(hh * 2 + b) * 128 * Tk;

  short8 aq[2][4];
#pragma unroll
  for (int m = 0; m < 2; ++m)
#pragma unroll
    for (int kk = 0; kk < 4; ++kk)
      aq[m][kk] = *(const short8*)(Qb +
          ((long)(b * 4096 + qtm + wid * 32 + m * 16 + fr)) * 1024 + h * 128 + kk * 32 + fo);

  const u16* kptr = kbase + (long)(lane >> 2) * 128 + wid * 32 +
                    (((lane & 3) ^ ((lane >> 3) & 3)) << 3);
  const u16* vptr = vbase + (long)(32 * wid + (lane >> 3)) * Tk +
                    (((lane & 7) ^ ((lane >> 3) & 7)) << 3);

  const char* kbL  = smem + fr * 64 + fo2 * 2;
  const char* vbL0 = smem + 32768 + fr * 128 + ((((gs    ) ^ (fr & 7)) & 7) << 4);
  const char* vbL1 = smem + 32768 + fr * 128 + ((((gs ^ 4) ^ (fr & 7)) & 7) << 4);

  f32x4 acc[2][8] = {};
  f32x4 accl[2] = {};
  float mr[2] = {-3e38f, -3e38f};

  short8 ones;
#pragma unroll
  for (int i = 0; i < 8; ++i) ones[i] = (short)0x3F80;

#pragma unroll
  for (int i = 0; i < 4; ++i) {
    gll16(kptr + i * 2048, &Kl[0][wid][i * 16][0]);
    gll16(vptr + (long)i * 8 * Tk, &Vl[0][32 * wid + 8 * i][0]);
  }

  int cur = 0;
  for (int kt = 0; kt < nt; ++kt) {
    asm volatile("s_waitcnt vmcnt(0)" ::: "memory");
    __builtin_amdgcn_sched_barrier(0);
    __builtin_amdgcn_s_barrier();
    __builtin_amdgcn_sched_barrier(0);
    if (kt + 1 < nt) {
      const int ktn = kt + 1;
#pragma unroll
      for (int i = 0; i < 4; ++i) {
        gll16(kptr + (long)ktn * 8192 + i * 2048, &Kl[cur ^ 1][wid][i * 16][0]);
        gll16(vptr + (long)ktn * 64 + (long)i * 8 * Tk, &Vl[cur ^ 1][32 * wid + 8 * i][0]);
      }
    }
    const char* kc = kbL + cur * 16384;
    f32x4 sa[2][4] = {};
    __builtin_amdgcn_s_setprio(1);
#pragma unroll
    for (int kk = 0; kk < 4; ++kk) {
      short8 bk[4];
#pragma unroll
      for (int jm = 0; jm < 4; ++jm)
        bk[jm] = *(const short8*)(kc + kk * 4096 + jm * 1024);
#pragma unroll
      for (int m = 0; m < 2; ++m)
#pragma unroll
        for (int jm = 0; jm < 4; ++jm)
          sa[m][jm] = __builtin_amdgcn_mfma_f32_16x16x32_bf16(bk[jm], aq[m][kk], sa[m][jm], 0, 0, 0);
    }
    __builtin_amdgcn_s_setprio(0);
    float tmx[2];
#pragma unroll
    for (int m = 0; m < 2; ++m) {
      float v0 = fmaxf(fmaxf(sa[m][0][0], sa[m][0][1]), fmaxf(sa[m][0][2], sa[m][0][3]));
      float v1 = fmaxf(fmaxf(sa[m][1][0], sa[m][1][1]), fmaxf(sa[m][1][2], sa[m][1][3]));
      float v2 = fmaxf(fmaxf(sa[m][2][0], sa[m][2][1]), fmaxf(sa[m][2][2], sa[m][2][3]));
      float v3 = fmaxf(fmaxf(sa[m][3][0], sa[m][3][1]), fmaxf(sa[m][3][2], sa[m][3][3]));
      float v = fmaxf(fmaxf(v0, v1), fmaxf(v2, v3));
      v = fmaxf(v, __shfl_xor(v, 16));
      v = fmaxf(v, __shfl_xor(v, 32));
      tmx[m] = v;
    }
    const bool need = (tmx[0] > mr[0] + 8.f) | (tmx[1] > mr[1] + 8.f);
    if (__any((int)need)) {
#pragma unroll
      for (int m = 0; m < 2; ++m) {
        const float mn = fmaxf(mr[m], tmx[m]);
        const float av = __builtin_amdgcn_exp2f(mr[m] - mn);
        mr[m] = mn;
#pragma unroll
        for (int jd = 0; jd < 8; ++jd)
#pragma unroll
          for (int r = 0; r < 4; ++r) acc[m][jd][r] *= av;
#pragma unroll
        for (int r = 0; r < 4; ++r) accl[m][r] *= av;
      }
    }
#pragma unroll
    for (int m = 0; m < 2; ++m)
#pragma unroll
      for (int jm = 0; jm < 4; ++jm)
#pragma unroll
        for (int r = 0; r < 4; ++r)
          sa[m][jm][r] = __builtin_amdgcn_exp2f(sa[m][jm][r] - mr[m]);
    unsigned pk[2][4][2];
#pragma unroll
    for (int m = 0; m < 2; ++m)
#pragma unroll
      for (int jm = 0; jm < 4; ++jm) {
        asm("v_cvt_pk_bf16_f32 %0, %1, %2" : "=v"(pk[m][jm][0]) : "v"(sa[m][jm][0]), "v"(sa[m][jm][1]));
        asm("v_cvt_pk_bf16_f32 %0, %1, %2" : "=v"(pk[m][jm][1]) : "v"(sa[m][jm][2]), "v"(sa[m][jm][3]));
      }
    const char* vc0 = vbL0 + cur * 16384;
    const char* vc1 = vbL1 + cur * 16384;
    __builtin_amdgcn_s_setprio(1);
#pragma unroll
    for (int kk = 0; kk < 2; ++kk) {
      short8 pt[2];
#pragma unroll
      for (int m = 0; m < 2; ++m) {
        union { unsigned u[4]; short8 s; } pp;
        pp.u[0] = pk[m][kk][0];     pp.u[1] = pk[m][kk][1];
        pp.u[2] = pk[m][kk + 2][0]; pp.u[3] = pk[m][kk + 2][1];
        pt[m] = pp.s;
      }
      const char* vc = kk ? vc1 : vc0;
#pragma unroll
      for (int jd = 0; jd < 8; ++jd) {
        short8 bb = *(const short8*)(vc + jd * 2048);
#pragma unroll
        for (int m = 0; m < 2; ++m)
          acc[m][jd] = __builtin_amdgcn_mfma_f32_16x16x32_bf16(bb, pt[m], acc[m][jd], 0, 0, 0);
      }
#pragma unroll
      for (int m = 0; m < 2; ++m)
        accl[m] = __builtin_amdgcn_mfma_f32_16x16x32_bf16(ones, pt[m], accl[m], 0, 0, 0);
    }
    __builtin_amdgcn_s_setprio(0);
    cur ^= 1;
  }
  // ---- epilogue: normalize, transpose O^T -> O through LDS, bf16 coalesced store ----
  __syncthreads();
  float* Ot = (float*)smem;
  float* ot = Ot + wid * 16 * 132;
#pragma unroll
  for (int m = 0; m < 2; ++m) {
    const float inv = 1.f / accl[m][0];
#pragma unroll
    for (int jd = 0; jd < 8; ++jd) {
      f32x4 v;
#pragma unroll
      for (int r = 0; r < 4; ++r) v[r] = acc[m][jd][r] * inv;
      *(f32x4*)&ot[fr * 132 + jd * 16 + gs * 4] = v;
    }
    asm volatile("s_waitcnt lgkmcnt(0)" ::: "memory");
    __builtin_amdgcn_sched_barrier(0);
    const int q = qtm + wid * 32 + m * 16 + (lane >> 2);
    u16* od = O + ((long)(b * 4096 + q) * 8 + h) * 128 + (lane & 3) * 32;
#pragma unroll
    for (int j = 0; j < 8; ++j) {
      f32x4 v = *(const f32x4*)&ot[(lane >> 2) * 132 + (lane & 3) * 32 + j * 4];
      short4v s;
#pragma unroll
      for (int r = 0; r < 4; ++r) s[r] = (short)f2bf(v[r]);
      *(short4v*)(od + j * 4) = s;
    }
    asm volatile("s_waitcnt lgkmcnt(0)" ::: "memory");
    __builtin_amdgcn_sched_barrier(0);
  }
}

// ---------- fused router MLP tail + contra-flow + head mixing (bf16 O input) ----------
__global__ __launch_bounds__(256) void router_mix(const float* __restrict__ hid,
    const float* __restrict__ rb1, const float* __restrict__ rW2, const float* __restrict__ rb2,
    const float* __restrict__ al, const u16* __restrict__ O, u16* __restrict__ mixed) {
  const int tok = blockIdx.x;
  const int b = tok >> 12, t = tok & 4095;
  const int tid = threadIdx.x;
  __shared__ float lred[4][8];
  __shared__ float wgt[8];
  __shared__ float ta[8];
  const float hv = fmaxf(hid[(long)tok * 256 + tid] + rb1[tid], 0.f);
  const float4* w4 = (const float4*)(rW2 + tid * 8);
  const float4 wa = w4[0], wb = w4[1];
  float part[8] = {hv * wa.x, hv * wa.y, hv * wa.z, hv * wa.w,
                   hv * wb.x, hv * wb.y, hv * wb.z, hv * wb.w};
#pragma unroll
  for (int h = 0; h < 8; ++h) {
    float v = part[h];
#pragma unroll
    for (int o = 1; o < 64; o <<= 1) v += __shfl_xor(v, o);
    if ((tid & 63) == 0) lred[tid >> 6][h] = v;
  }
  __syncthreads();
  if (tid < 8) ta[tid] = tanhf(al[tid]);
  if (tid == 0) {
    float lg[8], m = -1e30f;
#pragma unroll
    for (int h = 0; h < 8; ++h) {
      lg[h] = lred[0][h] + lred[1][h] + lred[2][h] + lred[3][h] + rb2[h];
      m = fmaxf(m, lg[h]);
    }
    float s = 0.f;
#pragma unroll
    for (int h = 0; h < 8; ++h) { lg[h] = __expf(lg[h] - m); s += lg[h]; }
    const float inv = 1.f / s;
#pragma unroll
    for (int h = 0; h < 8; ++h) wgt[h] = lg[h] * inv;
  }
  __syncthreads();
  if (tid < 128) {
    const long base = (long)tok * 1024 + tid;
    const long rbase = ((long)b * 4096 + (4095 - t)) * 1024 + tid;
    float acc = 0.f;
#pragma unroll
    for (int h = 0; h < 8; ++h)
      acc += wgt[h] * (bf2f(O[base + h * 128]) + ta[h] * bf2f(O[rbase + h * 128]));
    mixed[(long)tok * 128 + tid] = f2bf(acc);
  }
}

extern "C" void kernel_launch(void* const* d_in, const int* in_sizes, int n_in,
                              void* d_out, int out_size, void* d_ws, size_t ws_size,
                              hipStream_t stream) {
  const float* x    = (const float*)d_in[0];
  const float* Wq   = (const float*)d_in[1];
  const float* Wk   = (const float*)d_in[2];
  const float* Wv   = (const float*)d_in[3];
  const float* bg   = (const float*)d_in[4];
  const float* al   = (const float*)d_in[5];
  const float* rW1  = (const float*)d_in[6];
  const float* rb1  = (const float*)d_in[7];
  const float* rW2  = (const float*)d_in[8];
  const float* rb2  = (const float*)d_in[9];
  const float* Wout = (const float*)d_in[10];
  float* out = (float*)d_out;

  // ---- arena (lifetime overlays, ~95.5 MB) ----
  const size_t MB = 1u << 20;
  char* w = (char*)d_ws;
  u16*   xbf   = (u16*)(w + 0);            // 16 MB [P0-P1]
  u16*   O     = (u16*)(w + 0);            // 16 MB bf16 [P4-P5] overlays dead pools
  u16*   Qb    = (u16*)(w + 32 * MB);      // 16 MB [P1-P4]
  u16*   Kp    = (u16*)(w + 48 * MB);      // 7.5MB [P3-P4]
  u16*   KT    = (u16*)(w + 63 * MB);      // 7.5MB [P1-P3]
  u16*   VT    = (u16*)(w + 70 * MB + 512 * 1024); // 7.5MB [P1-P4]
  float* hid   = (float*)(w + 78 * MB);    //  8 MB [P1-P5]
  u16*   wqT   = (u16*)(w + 86 * MB);      //  2 MB
  u16*   kvT   = (u16*)(w + 88 * MB);      //  4 MB
  u16*   rw1T  = (u16*)(w + 92 * MB);      // 512 KB
  u16*   woutT = (u16*)(w + 92 * MB + 512 * 1024);   // 256 KB
  u16*   crep  = (u16*)(w + 92 * MB + 768 * 1024);   // 257 KB
  u16*   mixed = (u16*)(w + 93 * MB + 512 * 1024);   //  2 MB
  u16*   xp2   = (u16*)(w + 16 * MB);
  u16*   xp4   = (u16*)(w + 24 * MB);
  u16*   xp8   = (u16*)(w + 28 * MB);

  // P0: pooling + weight prep + irfft (one launch)
  prep_all<<<dim3(14976), dim3(256), 0, stream>>>(x, Wq, Wk, Wv, rW1, Wout, bg,
      xbf, xp2, xp4, xp8, wqT, kvT, rw1T, woutT, crep);

  // P1: Q + KV (direct-transposed KT/VT) + router hidden, one launch
  gemm_p1<<<dim3(1120), dim3(256), 0, stream>>>(xbf, wqT, kvT, rw1T, Qb, KT, VT, hid);

  // P3: circulant conv (BK=128, compact XCD-chunked 240-block grid)
  conv_k<<<dim3(240), dim3(256), 0, stream>>>(crep, KT, Kp);

  // P4: flash v4 (bf16 O)
  flash<<<dim3(512), dim3(256), 0, stream>>>(Qb, Kp, VT, O);

  // P5: router + mix, then output projection
  router_mix<<<dim3(8192), dim3(256), 0, stream>>>(hid, rb1, rW2, rb2, al, O, mixed);
  gemm_bt<false><<<dim3(64, 8), dim3(256), 0, stream>>>(mixed, woutT, out,
      128, 128, 128, 1024, 0, 0, 0, 1.f);
}

// Round 18
// 297.746 us; speedup vs baseline: 1.2835x; 1.0486x over previous
//
#include <hip/hip_runtime.h>
#include <hip/hip_bf16.h>

typedef __attribute__((ext_vector_type(8))) short short8;
typedef __attribute__((ext_vector_type(4))) short short4v;
typedef __attribute__((ext_vector_type(4))) float f32x4;
typedef unsigned short u16;

#define T_ 4096
#define D_ 1024
#define ISSL2E (0.08838834764831845f * 1.4426950408889634f)   // 1/sqrt(128) * log2(e)

__device__ __forceinline__ u16 f2bf(float f) {
  union { float f; unsigned u; } v; v.f = f;
  unsigned r = v.u + 0x7FFFu + ((v.u >> 16) & 1u);
  return (u16)(r >> 16);
}
__device__ __forceinline__ float bf2f(u16 u) {
  union { unsigned u; float f; } v; v.u = ((unsigned)u) << 16; return v.f;
}

// ---------- fused prep: pooling + weight transposes + irfft, ONE launch ----------
__global__ __launch_bounds__(256) void prep_all(const float* __restrict__ x,
    const float* __restrict__ Wq, const float* __restrict__ Wk, const float* __restrict__ Wv,
    const float* __restrict__ rW1, const float* __restrict__ Wout, const float* __restrict__ bg,
    u16* __restrict__ p1, u16* __restrict__ p2, u16* __restrict__ p4, u16* __restrict__ p8,
    u16* __restrict__ wqT, u16* __restrict__ kvT, u16* __restrict__ rw1T, u16* __restrict__ woutT,
    u16* __restrict__ crep) {
  const int blk = blockIdx.x;
  const int tid = threadIdx.x;
  if (blk < 1024) {
    const int b = blk >> 9, t0 = (blk & 511) << 3;
    const float* src = x + ((long)b * T_ + t0) * D_;
#pragma unroll
    for (int j = 0; j < 4; ++j) {
      const int c = tid + j * 256;
      float v[8];
#pragma unroll
      for (int r = 0; r < 8; ++r) v[r] = src[r * D_ + c];
#pragma unroll
      for (int r = 0; r < 8; ++r) p1[((long)b * 4096 + t0 + r) * D_ + c] = f2bf(v[r]);
#pragma unroll
      for (int r = 0; r < 4; ++r)
        p2[((long)b * 2048 + (t0 >> 1) + r) * D_ + c] = f2bf((v[2*r] + v[2*r+1]) * 0.5f);
#pragma unroll
      for (int r = 0; r < 2; ++r)
        p4[((long)b * 1024 + (t0 >> 2) + r) * D_ + c] =
            f2bf((v[4*r] + v[4*r+1] + v[4*r+2] + v[4*r+3]) * 0.25f);
      p8[((long)b * 512 + (t0 >> 3)) * D_ + c] =
          f2bf((v[0]+v[1]+v[2]+v[3]+v[4]+v[5]+v[6]+v[7]) * 0.125f);
    }
    return;
  }
  if (blk < 14848) {
    const int idx = (blk - 1024) * 256 + tid;
    if (idx < 1048576) {
      const int h = idx >> 17, wi = idx & 131071;
      const int c = wi >> 10, k = wi & 1023;
      wqT[idx] = f2bf(Wq[(long)h * 131072 + k * 128 + c]);
    } else if (idx < 3145728) {
      const int lid = idx - 1048576;
      const int g = lid >> 19, wi = lid & 524287;
      const int n = wi >> 10, k = wi & 1023;
      const int kv = n >> 8, hh = (n >> 7) & 1, c = n & 127;
      const float* W = kv ? Wv : Wk;
      kvT[lid] = f2bf(W[(long)(2 * g + hh) * 131072 + k * 128 + c]);
    } else if (idx < 3407872) {
      const int lid = idx - 3145728;
      const int n = lid >> 10, k = lid & 1023;
      rw1T[lid] = f2bf(rW1[(long)k * 256 + n]);
    } else if (idx < 3538944) {
      const int lid = idx - 3407872;
      const int n = lid >> 7, k = lid & 127;
      woutT[lid] = f2bf(Wout[(long)k * 1024 + n]);
    }
    return;
  }
  const int rel = blk - 14848;
  const int h = rel >> 4, xi = rel & 15;
  const int Tk = 4096 >> (h >> 1);
  const int mask = Tk - 1;
  if (xi * 256 >= Tk) return;
  const int nb = (Tk >> 1) + 1;
  __shared__ float ct[4096];
  __shared__ float wm[2049];
  const float w0 = 6.283185307179586f / (float)Tk;
  for (int j = tid; j < Tk; j += 256) ct[j] = cosf(w0 * (float)j);
  for (int m = tid; m < nb; m += 256) {
    int band = (m * 8) / nb; if (band > 7) band = 7;
    const float g = 1.f / (1.f + expf(-bg[h * 8 + band]));
    const float sc = (m == 0 || m == nb - 1) ? 1.f : 2.f;
    wm[m] = g * sc / (float)Tk;
  }
  __syncthreads();
  const int n = xi * 256 + tid;
  float acc = 0.f;
  int idx = 0;
  for (int m = 0; m < nb; ++m) {
    acc += wm[m] * ct[idx];
    idx += n;
    if (idx >= Tk) idx -= Tk;
  }
  const u16 bf = f2bf(acc);
  u16* hb = crep + (long)h * 16416;
#pragma unroll
  for (int p = 0; p < 4; ++p) {
    const int q = (n - p) & mask;
    hb[p * 4104 + q] = bf;
    if (q < 8) hb[p * 4104 + q + Tk] = bf;
  }
}

// ---------- async global->LDS ----------
__device__ __forceinline__ void gll16(const void* g, void* l) {
  __builtin_amdgcn_global_load_lds((const __attribute__((address_space(1))) void*)g,
                                   (__attribute__((address_space(3))) void*)l, 16, 0, 0);
}

// ---------- shared bf16 MFMA GEMM core (XOR-swizzled LDS) ----------
__device__ __forceinline__ void gemm_core(const u16* __restrict__ A, const u16* __restrict__ Bt,
    void* __restrict__ Cv, int K, int lda, int ldb, int ldc, int tm, int tn, float alpha,
    int mode, u16 (*lds)[2][128][32],
    u16* KTp = nullptr, u16* VTp = nullptr, int Tkv = 0, int bsel = 0) {
  const int tid = threadIdx.x, lane = tid & 63, wid = tid >> 6;
  const int wr = wid >> 1, wc = wid & 1;
  const int srow = lane >> 2;
  const int scol = ((lane & 3) ^ ((lane >> 3) & 3)) * 8;
  const u16* ga0 = A + (long)(tm + 32 * wid + srow) * lda + scol;
  const u16* ga1 = ga0 + (long)16 * lda;
  const u16* gb0 = Bt + (long)(tn + 32 * wid + srow) * ldb + scol;
  const u16* gb1 = gb0 + (long)16 * ldb;
  f32x4 acc[4][4] = {};
  const int nk = K >> 5;
  gll16(ga0, &lds[0][0][32 * wid][0]);
  gll16(ga1, &lds[0][0][32 * wid + 16][0]);
  gll16(gb0, &lds[0][1][32 * wid][0]);
  gll16(gb1, &lds[0][1][32 * wid + 16][0]);
  int buf = 0;
  const int fr = lane & 15;
  const int fo2 = (((lane >> 4) & 3) ^ ((lane >> 1) & 3)) * 8;
  for (int kt = 0; kt < nk; ++kt) {
    __syncthreads();
    if (kt + 1 < nk) {
      const long ko = (long)(kt + 1) * 32;
      gll16(ga0 + ko, &lds[buf ^ 1][0][32 * wid][0]);
      gll16(ga1 + ko, &lds[buf ^ 1][0][32 * wid + 16][0]);
      gll16(gb0 + ko, &lds[buf ^ 1][1][32 * wid][0]);
      gll16(gb1 + ko, &lds[buf ^ 1][1][32 * wid + 16][0]);
    }
    short8 af[4], bfr[4];
#pragma unroll
    for (int i = 0; i < 4; ++i) {
      af[i]  = *(const short8*)&lds[buf][0][wr * 64 + i * 16 + fr][fo2];
      bfr[i] = *(const short8*)&lds[buf][1][wc * 64 + i * 16 + fr][fo2];
    }
#pragma unroll
    for (int i = 0; i < 4; ++i)
#pragma unroll
      for (int j = 0; j < 4; ++j)
        acc[i][j] = __builtin_amdgcn_mfma_f32_16x16x32_bf16(af[i], bfr[j], acc[i][j], 0, 0, 0);
    buf ^= 1;
  }
  const int er = (lane >> 4) * 4, ec = lane & 15;
  if (mode == 2) {
    const int tb = tm - bsel * Tkv + wr * 64;
#pragma unroll
    for (int i = 0; i < 4; ++i) {
      const int t0 = tb + i * 16 + er;
      const int kperm = (t0 & ~63) | (((t0 >> 4) & 1) << 5) | (((t0 >> 2) & 3) << 3)
                      | (((t0 >> 5) & 1) << 2);
#pragma unroll
      for (int j = 0; j < 4; ++j) {
        const int col = tn + wc * 64 + j * 16 + ec;
        const int kv = col >> 8, hh = (col >> 7) & 1, c = col & 127;
        u16* dstb = (kv ? VTp : KTp) + ((long)(hh * 2 + bsel) * 128 + c) * Tkv;
        short4v v;
#pragma unroll
        for (int r = 0; r < 4; ++r) v[r] = (short)f2bf(acc[i][j][r]);
        *(short4v*)(dstb + (kv ? kperm : t0)) = v;
      }
    }
  } else if (mode == 1) {
    u16* C = (u16*)Cv;
#pragma unroll
    for (int i = 0; i < 4; ++i)
#pragma unroll
      for (int j = 0; j < 4; ++j)
#pragma unroll
        for (int r = 0; r < 4; ++r)
          C[(long)(tm + wr * 64 + i * 16 + er + r) * ldc + (tn + wc * 64 + j * 16 + ec)] =
              f2bf(acc[i][j][r] * alpha);
  } else {
    float* C = (float*)Cv;
#pragma unroll
    for (int i = 0; i < 4; ++i)
#pragma unroll
      for (int j = 0; j < 4; ++j)
#pragma unroll
        for (int r = 0; r < 4; ++r)
          C[(long)(tm + wr * 64 + i * 16 + er + r) * ldc + (tn + wc * 64 + j * 16 + ec)] =
              acc[i][j][r] * alpha;
  }
}

template <bool OBF>
__global__ __launch_bounds__(256) void gemm_bt(const u16* __restrict__ A, const u16* __restrict__ Bt,
                                               void* __restrict__ Cv, int K, int lda, int ldb, int ldc,
                                               long abs_, long bbs, long cbs, float alpha) {
  __shared__ u16 lds[2][2][128][32];
  const u16* Az = A + (long)blockIdx.z * abs_;
  const u16* Bz = Bt + (long)blockIdx.z * bbs;
  void* Cz = OBF ? (void*)((u16*)Cv + (long)blockIdx.z * cbs)
                 : (void*)((float*)Cv + (long)blockIdx.z * cbs);
  gemm_core(Az, Bz, Cz, K, lda, ldb, ldc, blockIdx.x * 128, blockIdx.y * 128, alpha,
            OBF ? 1 : 0, lds);
}

// ---------- mega-GEMM: Q + KV(direct-transposed) + router hidden ----------
__global__ __launch_bounds__(256) void gemm_p1(const u16* __restrict__ xbf,
    const u16* __restrict__ wqT, const u16* __restrict__ kvT, const u16* __restrict__ rw1T,
    u16* __restrict__ Qb, u16* __restrict__ KT, u16* __restrict__ VT, float* __restrict__ hid) {
  __shared__ u16 lds[2][2][128][32];
  const int bid = blockIdx.x;
  const int id = (bid & 7) * 140 + (bid >> 3);
  if (id < 512) {
    gemm_core(xbf, wqT, Qb, 1024, 1024, 1024, 1024,
              (id >> 3) * 128, (id & 7) * 128, 1.f, 1, lds);
  } else if (id < 992) {
    const int lid = id - 512;
    const int rt = lid >> 2, y = lid & 3;
    int g, lr;
    if (rt < 64)       { g = 0; lr = rt; }
    else if (rt < 96)  { g = 1; lr = rt - 64; }
    else if (rt < 112) { g = 2; lr = rt - 96; }
    else               { g = 3; lr = rt - 112; }
    const long xofs[4] = {0, 8388608, 12582912, 14680064};
    const long ktoff[4] = {0, 2097152, 3145728, 3670016};
    const int Tk = 4096 >> g;
    const int tm = lr * 128;
    const int bsel = (tm >= Tk) ? 1 : 0;
    gemm_core(xbf + xofs[g], kvT + (long)g * 524288, nullptr,
              1024, 1024, 1024, 0, tm, y * 128, 1.f, 2, lds,
              KT + ktoff[g], VT + ktoff[g], Tk, bsel);
  } else {
    const int lid = id - 992;
    gemm_core(xbf, rw1T, hid, 1024, 1024, 1024, 256,
              (lid >> 1) * 128, (lid & 1) * 128, 1.f, 0, lds);
  }
}

// ---------- circulant conv GEMM, BK=128, compact XCD-chunked grid (240 blocks) ----------
__global__ __launch_bounds__(256) void conv_k(const u16* __restrict__ crep,
    const u16* __restrict__ KT, u16* __restrict__ Kp) {
  const int bid = blockIdx.x;
  const int j = (bid & 7) * 30 + (bid >> 3);
  int z, lx;
  if (j < 128)      { z = j >> 5;             lx = j & 31; }
  else if (j < 192) { z = 4 + ((j - 128) >> 4); lx = (j - 128) & 15; }
  else if (j < 224) { z = 8 + ((j - 192) >> 3); lx = (j - 192) & 7; }
  else              { z = 12 + ((j - 224) >> 2); lx = (j - 224) & 3; }
  const int h = z >> 1, b = z & 1, g = h >> 1;
  const int Tk = 4096 >> g, mask = Tk - 1;
  const int tm = lx << 7;
  __shared__ u16 clds[16416];
  __shared__ u16 blds[2][4][128][32];
  const int tid = threadIdx.x, lane = tid & 63, wid = tid >> 6;
  const int wr = wid >> 1, wc = wid & 1;
  const int srow = lane >> 2;
  const int scol = ((lane & 3) ^ ((lane >> 3) & 3)) * 8;
  const int fr = lane & 15, fo = (lane >> 4) * 8;
  const int fo2 = (((lane >> 4) & 3) ^ ((lane >> 1) & 3)) * 8;
  {
    const short8* src = (const short8*)(crep + (long)h * 16416);
    short8* dst = (short8*)clds;
    for (int jj = tid; jj < 2052; jj += 256) dst[jj] = src[jj];
  }
  const long ktofs = 4194304 - (4194304 >> g);
  const u16* Bt = KT + ktofs + (long)((h & 1) * 2 + b) * 128 * Tk;
  u16* out = Kp + ktofs + ((long)(h & 1) << 8) * Tk + ((long)b << 7) * Tk;
  const u16* gb0 = Bt + (long)(32 * wid + srow) * Tk + scol;
  const u16* gb1 = gb0 + (long)16 * Tk;
  f32x4 acc[4][4] = {};
  int base[4];
#pragma unroll
  for (int i = 0; i < 4; ++i) base[i] = (fo - (tm + wr * 64 + i * 16 + fr)) & mask;
  const int p = base[0] & 3;
  const u16* crow = clds + p * 4104;
  const int nk = Tk >> 7;
#pragma unroll
  for (int c = 0; c < 4; ++c) {
    gll16(gb0 + c * 32, &blds[0][c][32 * wid][0]);
    gll16(gb1 + c * 32, &blds[0][c][32 * wid + 16][0]);
  }
  int buf = 0;
  for (int kt = 0; kt < nk; ++kt) {
    __syncthreads();
    if (kt + 1 < nk) {
      const long ko = (long)(kt + 1) * 128;
#pragma unroll
      for (int c = 0; c < 4; ++c) {
        gll16(gb0 + ko + c * 32, &blds[buf ^ 1][c][32 * wid][0]);
        gll16(gb1 + ko + c * 32, &blds[buf ^ 1][c][32 * wid + 16][0]);
      }
    }
#pragma unroll
    for (int c = 0; c < 4; ++c) {
      short8 af[4], bfr[4];
#pragma unroll
      for (int i = 0; i < 4; ++i) {
        const int a0 = base[i] ^ p;
        short4v lo = *(const short4v*)(crow + a0);
        short4v hi = *(const short4v*)(crow + a0 + 4);
        af[i][0] = lo[0]; af[i][1] = lo[1]; af[i][2] = lo[2]; af[i][3] = lo[3];
        af[i][4] = hi[0]; af[i][5] = hi[1]; af[i][6] = hi[2]; af[i][7] = hi[3];
        base[i] = (base[i] + 32) & mask;
        bfr[i] = *(const short8*)&blds[buf][c][wc * 64 + i * 16 + fr][fo2];
      }
#pragma unroll
      for (int i = 0; i < 4; ++i)
#pragma unroll
        for (int jj = 0; jj < 4; ++jj)
          acc[i][jj] = __builtin_amdgcn_mfma_f32_16x16x32_bf16(af[i], bfr[jj], acc[i][jj], 0, 0, 0);
    }
    buf ^= 1;
  }
  const int er = (lane >> 4) * 4, ec = lane & 15;
#pragma unroll
  for (int i = 0; i < 4; ++i)
#pragma unroll
    for (int jj = 0; jj < 4; ++jj)
#pragma unroll
      for (int r = 0; r < 4; ++r)
        out[(long)(tm + wr * 64 + i * 16 + er + r) * 128 + (wc * 64 + jj * 16 + ec)] =
            f2bf(acc[i][jj][r] * ISSL2E);
}

// ---------- flash v7: v4 inner loop, split-K jobs (1024), bf16 partial O + (m,l) ----------
__global__ __launch_bounds__(256, 2) void flash(const u16* __restrict__ Qb,
    const u16* __restrict__ Kp, const u16* __restrict__ VT,
    u16* __restrict__ Op, float* __restrict__ mlb) {
  const int wg = blockIdx.x;
  const int x = wg & 7, s = wg >> 3;          // 8 XCDs x 128 slots
  const int q4 = s >> 5;
  const int lvl = q4 ^ (q4 >> 1);             // 0,1,3,2
  const int hh = x >> 2, b = (x >> 1) & 1, kh = x & 1;
  const int h = lvl * 2 + hh;
  const int qtm = (s & 31) << 7;
  const int Tk = 4096 >> lvl;                 // full key range (strides)
  const int nt = Tk >> 7;                     // iterations over this job's half

  __shared__ __align__(16) char smem[65536];
  u16 (*Kl)[4][64][32] = (u16(*)[4][64][32])smem;
  u16 (*Vl)[128][64]   = (u16(*)[128][64])(smem + 32768);

  const int tid = threadIdx.x, lane = tid & 63, wid = tid >> 6;
  const int fr = lane & 15, gs = lane >> 4;
  const int fo = gs * 8;
  const int fo2 = ((gs & 3) ^ ((lane >> 1) & 3)) * 8;

  const long ktofs = 4194304 - (4194304 >> lvl);
  const u16* kbase = Kp + ktofs + (long)(hh * 2 + b) * 128 * Tk + (long)kh * (Tk >> 1) * 128;
  const u16* vbase = VT + ktofs + (long)(hh * 2 + b) * 128 * Tk;

  short8 aq[2][4];
#pragma unroll
  for (int m = 0; m < 2; ++m)
#pragma unroll
    for (int kk = 0; kk < 4; ++kk)
      aq[m][kk] = *(const short8*)(Qb +
          ((long)(b * 4096 + qtm + wid * 32 + m * 16 + fr)) * 1024 + h * 128 + kk * 32 + fo);

  const u16* kptr = kbase + (long)(lane >> 2) * 128 + wid * 32 +
                    (((lane & 3) ^ ((lane >> 3) & 3)) << 3);
  const u16* vptr = vbase + (long)(32 * wid + (lane >> 3)) * Tk + kh * (Tk >> 1) +
                    (((lane & 7) ^ ((lane >> 3) & 7)) << 3);

  const char* kbL  = smem + fr * 64 + fo2 * 2;
  const char* vbL0 = smem + 32768 + fr * 128 + ((((gs    ) ^ (fr & 7)) & 7) << 4);
  const char* vbL1 = smem + 32768 + fr * 128 + ((((gs ^ 4) ^ (fr & 7)) & 7) << 4);

  f32x4 acc[2][8] = {};
  f32x4 accl[2] = {};
  float mr[2] = {-3e38f, -3e38f};

  short8 ones;
#pragma unroll
  for (int i = 0; i < 8; ++i) ones[i] = (short)0x3F80;

#pragma unroll
  for (int i = 0; i < 4; ++i) {
    gll16(kptr + i * 2048, &Kl[0][wid][i * 16][0]);
    gll16(vptr + (long)i * 8 * Tk, &Vl[0][32 * wid + 8 * i][0]);
  }

  int cur = 0;
  for (int kt = 0; kt < nt; ++kt) {
    asm volatile("s_waitcnt vmcnt(0)" ::: "memory");
    __builtin_amdgcn_sched_barrier(0);
    __builtin_amdgcn_s_barrier();
    __builtin_amdgcn_sched_barrier(0);
    if (kt + 1 < nt) {
      const int ktn = kt + 1;
#pragma unroll
      for (int i = 0; i < 4; ++i) {
        gll16(kptr + (long)ktn * 8192 + i * 2048, &Kl[cur ^ 1][wid][i * 16][0]);
        gll16(vptr + (long)ktn * 64 + (long)i * 8 * Tk, &Vl[cur ^ 1][32 * wid + 8 * i][0]);
      }
    }
    const char* kc = kbL + cur * 16384;
    f32x4 sa[2][4] = {};
    __builtin_amdgcn_s_setprio(1);
#pragma unroll
    for (int kk = 0; kk < 4; ++kk) {
      short8 bk[4];
#pragma unroll
      for (int jm = 0; jm < 4; ++jm)
        bk[jm] = *(const short8*)(kc + kk * 4096 + jm * 1024);
#pragma unroll
      for (int m = 0; m < 2; ++m)
#pragma unroll
        for (int jm = 0; jm < 4; ++jm)
          sa[m][jm] = __builtin_amdgcn_mfma_f32_16x16x32_bf16(bk[jm], aq[m][kk], sa[m][jm], 0, 0, 0);
    }
    __builtin_amdgcn_s_setprio(0);
    float tmx[2];
#pragma unroll
    for (int m = 0; m < 2; ++m) {
      float v0 = fmaxf(fmaxf(sa[m][0][0], sa[m][0][1]), fmaxf(sa[m][0][2], sa[m][0][3]));
      float v1 = fmaxf(fmaxf(sa[m][1][0], sa[m][1][1]), fmaxf(sa[m][1][2], sa[m][1][3]));
      float v2 = fmaxf(fmaxf(sa[m][2][0], sa[m][2][1]), fmaxf(sa[m][2][2], sa[m][2][3]));
      float v3 = fmaxf(fmaxf(sa[m][3][0], sa[m][3][1]), fmaxf(sa[m][3][2], sa[m][3][3]));
      float v = fmaxf(fmaxf(v0, v1), fmaxf(v2, v3));
      v = fmaxf(v, __shfl_xor(v, 16));
      v = fmaxf(v, __shfl_xor(v, 32));
      tmx[m] = v;
    }
    const bool need = (tmx[0] > mr[0] + 8.f) | (tmx[1] > mr[1] + 8.f);
    if (__any((int)need)) {
#pragma unroll
      for (int m = 0; m < 2; ++m) {
        const float mn = fmaxf(mr[m], tmx[m]);
        const float av = __builtin_amdgcn_exp2f(mr[m] - mn);
        mr[m] = mn;
#pragma unroll
        for (int jd = 0; jd < 8; ++jd)
#pragma unroll
          for (int r = 0; r < 4; ++r) acc[m][jd][r] *= av;
#pragma unroll
        for (int r = 0; r < 4; ++r) accl[m][r] *= av;
      }
    }
#pragma unroll
    for (int m = 0; m < 2; ++m)
#pragma unroll
      for (int jm = 0; jm < 4; ++jm)
#pragma unroll
        for (int r = 0; r < 4; ++r)
          sa[m][jm][r] = __builtin_amdgcn_exp2f(sa[m][jm][r] - mr[m]);
    unsigned pk[2][4][2];
#pragma unroll
    for (int m = 0; m < 2; ++m)
#pragma unroll
      for (int jm = 0; jm < 4; ++jm) {
        asm("v_cvt_pk_bf16_f32 %0, %1, %2" : "=v"(pk[m][jm][0]) : "v"(sa[m][jm][0]), "v"(sa[m][jm][1]));
        asm("v_cvt_pk_bf16_f32 %0, %1, %2" : "=v"(pk[m][jm][1]) : "v"(sa[m][jm][2]), "v"(sa[m][jm][3]));
      }
    const char* vc0 = vbL0 + cur * 16384;
    const char* vc1 = vbL1 + cur * 16384;
    __builtin_amdgcn_s_setprio(1);
#pragma unroll
    for (int kk = 0; kk < 2; ++kk) {
      short8 pt[2];
#pragma unroll
      for (int m = 0; m < 2; ++m) {
        union { unsigned u[4]; short8 s; } pp;
        pp.u[0] = pk[m][kk][0];     pp.u[1] = pk[m][kk][1];
        pp.u[2] = pk[m][kk + 2][0]; pp.u[3] = pk[m][kk + 2][1];
        pt[m] = pp.s;
      }
      const char* vc = kk ? vc1 : vc0;
#pragma unroll
      for (int jd = 0; jd < 8; ++jd) {
        short8 bb = *(const short8*)(vc + jd * 2048);
#pragma unroll
        for (int m = 0; m < 2; ++m)
          acc[m][jd] = __builtin_amdgcn_mfma_f32_16x16x32_bf16(bb, pt[m], acc[m][jd], 0, 0, 0);
      }
#pragma unroll
      for (int m = 0; m < 2; ++m)
        accl[m] = __builtin_amdgcn_mfma_f32_16x16x32_bf16(ones, pt[m], accl[m], 0, 0, 0);
    }
    __builtin_amdgcn_s_setprio(0);
    cur ^= 1;
  }
  // ---- epilogue: UNNORMALIZED bf16 partial O (transposed via LDS) + (m,l) ----
  __syncthreads();
  float* Ot = (float*)smem;
  float* ot = Ot + wid * 16 * 132;
  u16* Obase = Op + (long)kh * 8388608;
#pragma unroll
  for (int m = 0; m < 2; ++m) {
#pragma unroll
    for (int jd = 0; jd < 8; ++jd)
      *(f32x4*)&ot[fr * 132 + jd * 16 + gs * 4] = acc[m][jd];
    asm volatile("s_waitcnt lgkmcnt(0)" ::: "memory");
    __builtin_amdgcn_sched_barrier(0);
    const int q = qtm + wid * 32 + m * 16 + (lane >> 2);
    u16* od = Obase + ((long)(b * 4096 + q) * 8 + h) * 128 + (lane & 3) * 32;
#pragma unroll
    for (int j = 0; j < 8; ++j) {
      f32x4 v = *(const f32x4*)&ot[(lane >> 2) * 132 + (lane & 3) * 32 + j * 4];
      short4v sv;
#pragma unroll
      for (int r = 0; r < 4; ++r) sv[r] = (short)f2bf(v[r]);
      *(short4v*)(od + j * 4) = sv;
    }
    asm volatile("s_waitcnt lgkmcnt(0)" ::: "memory");
    __builtin_amdgcn_sched_barrier(0);
    if (gs == 0) {
      const int q2 = qtm + wid * 32 + m * 16 + fr;
      ((float2*)mlb)[(long)kh * 65536 + (long)(b * 4096 + q2) * 8 + h] =
          make_float2(mr[m], accl[m][0]);
    }
  }
}

// ---------- fused router + flash-combine + contra-flow + head mixing ----------
__global__ __launch_bounds__(256) void router_mix(const float* __restrict__ hid,
    const float* __restrict__ rb1, const float* __restrict__ rW2, const float* __restrict__ rb2,
    const float* __restrict__ al, const u16* __restrict__ Op, const float* __restrict__ mlb,
    u16* __restrict__ mixed) {
  const int tok = blockIdx.x;
  const int b = tok >> 12, t = tok & 4095;
  const int rtok = b * 4096 + (4095 - t);
  const int tid = threadIdx.x;
  __shared__ float lred[4][8];
  __shared__ float wgt[8];
  __shared__ float ta[8];
  __shared__ float el[2][8][2];   // [tok/rtok][h][half]
  const float hv = fmaxf(hid[(long)tok * 256 + tid] + rb1[tid], 0.f);
  const float4* w4 = (const float4*)(rW2 + tid * 8);
  const float4 wa = w4[0], wb = w4[1];
  float part[8] = {hv * wa.x, hv * wa.y, hv * wa.z, hv * wa.w,
                   hv * wb.x, hv * wb.y, hv * wb.z, hv * wb.w};
#pragma unroll
  for (int h = 0; h < 8; ++h) {
    float v = part[h];
#pragma unroll
    for (int o = 1; o < 64; o <<= 1) v += __shfl_xor(v, o);
    if ((tid & 63) == 0) lred[tid >> 6][h] = v;
  }
  if (tid >= 64 && tid < 80) {    // wave 1 lanes 0-15: combine weights
    const int j = tid - 64;
    const int h = j & 7, which = j >> 3;
    const long tk = which ? rtok : tok;
    const float2 a = ((const float2*)mlb)[tk * 8 + h];
    const float2 c = ((const float2*)mlb)[65536 + tk * 8 + h];
    const float M = fmaxf(a.x, c.x);
    const float w1 = exp2f(a.x - M), w2 = exp2f(c.x - M);
    const float inv = 1.f / (w1 * a.y + w2 * c.y);
    el[which][h][0] = w1 * inv;
    el[which][h][1] = w2 * inv;
  }
  __syncthreads();
  if (tid < 8) ta[tid] = tanhf(al[tid]);
  if (tid == 0) {
    float lg[8], m = -1e30f;
#pragma unroll
    for (int h = 0; h < 8; ++h) {
      lg[h] = lred[0][h] + lred[1][h] + lred[2][h] + lred[3][h] + rb2[h];
      m = fmaxf(m, lg[h]);
    }
    float s = 0.f;
#pragma unroll
    for (int h = 0; h < 8; ++h) { lg[h] = __expf(lg[h] - m); s += lg[h]; }
    const float inv = 1.f / s;
#pragma unroll
    for (int h = 0; h < 8; ++h) wgt[h] = lg[h] * inv;
  }
  __syncthreads();
  if (tid < 128) {
    const long base = (long)tok * 1024 + tid;
    const long rbase = (long)rtok * 1024 + tid;
    float acc = 0.f;
#pragma unroll
    for (int h = 0; h < 8; ++h) {
      const float o = el[0][h][0] * bf2f(Op[base + h * 128]) +
                      el[0][h][1] * bf2f(Op[8388608 + base + h * 128]);
      const float orv = el[1][h][0] * bf2f(Op[rbase + h * 128]) +
                        el[1][h][1] * bf2f(Op[8388608 + rbase + h * 128]);
      acc += wgt[h] * (o + ta[h] * orv);
    }
    mixed[(long)tok * 128 + tid] = f2bf(acc);
  }
}

extern "C" void kernel_launch(void* const* d_in, const int* in_sizes, int n_in,
                              void* d_out, int out_size, void* d_ws, size_t ws_size,
                              hipStream_t stream) {
  const float* x    = (const float*)d_in[0];
  const float* Wq   = (const float*)d_in[1];
  const float* Wk   = (const float*)d_in[2];
  const float* Wv   = (const float*)d_in[3];
  const float* bg   = (const float*)d_in[4];
  const float* al   = (const float*)d_in[5];
  const float* rW1  = (const float*)d_in[6];
  const float* rb1  = (const float*)d_in[7];
  const float* rW2  = (const float*)d_in[8];
  const float* rb2  = (const float*)d_in[9];
  const float* Wout = (const float*)d_in[10];
  float* out = (float*)d_out;

  // ---- arena (lifetime overlays, ~97 MB) ----
  const size_t MB = 1u << 20;
  char* w = (char*)d_ws;
  u16*   xbf   = (u16*)(w + 0);            // 16 MB [P0-P1]
  u16*   Op    = (u16*)(w + 0);            // 32 MB bf16 [2][...] [P4-P5] overlays dead pools
  u16*   Qb    = (u16*)(w + 32 * MB);      // 16 MB [P1-P4]
  u16*   Kp    = (u16*)(w + 48 * MB);      // 7.5MB [P3-P4]
  u16*   KT    = (u16*)(w + 63 * MB);      // 7.5MB [P1-P3]
  u16*   VT    = (u16*)(w + 70 * MB + 512 * 1024); // 7.5MB [P1-P4]
  float* hid   = (float*)(w + 78 * MB);    //  8 MB [P1-P5]
  u16*   wqT   = (u16*)(w + 86 * MB);      //  2 MB
  u16*   kvT   = (u16*)(w + 88 * MB);      //  4 MB
  u16*   rw1T  = (u16*)(w + 92 * MB);      // 512 KB
  u16*   woutT = (u16*)(w + 92 * MB + 512 * 1024);   // 256 KB
  u16*   crep  = (u16*)(w + 92 * MB + 768 * 1024);   // 257 KB
  u16*   mixed = (u16*)(w + 93 * MB + 512 * 1024);   //  2 MB
  float* mlbuf = (float*)(w + 95 * MB + 512 * 1024); //  1 MB [P4-P5]
  u16*   xp2   = (u16*)(w + 16 * MB);
  u16*   xp4   = (u16*)(w + 24 * MB);
  u16*   xp8   = (u16*)(w + 28 * MB);

  // P0: pooling + weight prep + irfft (one launch)
  prep_all<<<dim3(14976), dim3(256), 0, stream>>>(x, Wq, Wk, Wv, rW1, Wout, bg,
      xbf, xp2, xp4, xp8, wqT, kvT, rw1T, woutT, crep);

  // P1: Q + KV (direct-transposed KT/VT) + router hidden, one launch
  gemm_p1<<<dim3(1120), dim3(256), 0, stream>>>(xbf, wqT, kvT, rw1T, Qb, KT, VT, hid);

  // P3: circulant conv (BK=128, compact XCD-chunked 240-block grid)
  conv_k<<<dim3(240), dim3(256), 0, stream>>>(crep, KT, Kp);

  // P4: flash v7 (split-K, 1024 jobs, v4 inner loop; bf16 partials + ml)
  flash<<<dim3(1024), dim3(256), 0, stream>>>(Qb, Kp, VT, Op, mlbuf);

  // P5: router + flash-combine + mix, then output projection
  router_mix<<<dim3(8192), dim3(256), 0, stream>>>(hid, rb1, rW2, rb2, al, Op, mlbuf, mixed);
  gemm_bt<false><<<dim3(64, 8), dim3(256), 0, stream>>>(mixed, woutT, out,
      128, 128, 128, 1024, 0, 0, 0, 1.f);
}

// Round 19
// 295.305 us; speedup vs baseline: 1.2941x; 1.0083x over previous
//
#include <hip/hip_runtime.h>
#include <hip/hip_bf16.h>

typedef __attribute__((ext_vector_type(8))) short short8;
typedef __attribute__((ext_vector_type(4))) short short4v;
typedef __attribute__((ext_vector_type(4))) float f32x4;
typedef unsigned short u16;

#define T_ 4096
#define D_ 1024
#define ISSL2E (0.08838834764831845f * 1.4426950408889634f)   // 1/sqrt(128) * log2(e)

__device__ __forceinline__ u16 f2bf(float f) {
  union { float f; unsigned u; } v; v.f = f;
  unsigned r = v.u + 0x7FFFu + ((v.u >> 16) & 1u);
  return (u16)(r >> 16);
}
__device__ __forceinline__ float bf2f(u16 u) {
  union { unsigned u; float f; } v; v.u = ((unsigned)u) << 16; return v.f;
}

// ---------- fused prep: pooling + weight transposes + irfft, ONE launch ----------
__global__ __launch_bounds__(256) void prep_all(const float* __restrict__ x,
    const float* __restrict__ Wq, const float* __restrict__ Wk, const float* __restrict__ Wv,
    const float* __restrict__ rW1, const float* __restrict__ Wout, const float* __restrict__ bg,
    u16* __restrict__ p1, u16* __restrict__ p2, u16* __restrict__ p4, u16* __restrict__ p8,
    u16* __restrict__ wqT, u16* __restrict__ kvT, u16* __restrict__ rw1T, u16* __restrict__ woutT,
    u16* __restrict__ crep) {
  const int blk = blockIdx.x;
  const int tid = threadIdx.x;
  if (blk < 1024) {
    const int b = blk >> 9, t0 = (blk & 511) << 3;
    const float* src = x + ((long)b * T_ + t0) * D_;
#pragma unroll
    for (int j = 0; j < 4; ++j) {
      const int c = tid + j * 256;
      float v[8];
#pragma unroll
      for (int r = 0; r < 8; ++r) v[r] = src[r * D_ + c];
#pragma unroll
      for (int r = 0; r < 8; ++r) p1[((long)b * 4096 + t0 + r) * D_ + c] = f2bf(v[r]);
#pragma unroll
      for (int r = 0; r < 4; ++r)
        p2[((long)b * 2048 + (t0 >> 1) + r) * D_ + c] = f2bf((v[2*r] + v[2*r+1]) * 0.5f);
#pragma unroll
      for (int r = 0; r < 2; ++r)
        p4[((long)b * 1024 + (t0 >> 2) + r) * D_ + c] =
            f2bf((v[4*r] + v[4*r+1] + v[4*r+2] + v[4*r+3]) * 0.25f);
      p8[((long)b * 512 + (t0 >> 3)) * D_ + c] =
          f2bf((v[0]+v[1]+v[2]+v[3]+v[4]+v[5]+v[6]+v[7]) * 0.125f);
    }
    return;
  }
  if (blk < 14848) {
    const int idx = (blk - 1024) * 256 + tid;
    if (idx < 1048576) {
      const int h = idx >> 17, wi = idx & 131071;
      const int c = wi >> 10, k = wi & 1023;
      wqT[idx] = f2bf(Wq[(long)h * 131072 + k * 128 + c]);
    } else if (idx < 3145728) {
      const int lid = idx - 1048576;
      const int g = lid >> 19, wi = lid & 524287;
      const int n = wi >> 10, k = wi & 1023;
      const int kv = n >> 8, hh = (n >> 7) & 1, c = n & 127;
      const float* W = kv ? Wv : Wk;
      kvT[lid] = f2bf(W[(long)(2 * g + hh) * 131072 + k * 128 + c]);
    } else if (idx < 3407872) {
      const int lid = idx - 3145728;
      const int n = lid >> 10, k = lid & 1023;
      rw1T[lid] = f2bf(rW1[(long)k * 256 + n]);
    } else if (idx < 3538944) {
      const int lid = idx - 3407872;
      const int n = lid >> 7, k = lid & 127;
      woutT[lid] = f2bf(Wout[(long)k * 1024 + n]);
    }
    return;
  }
  const int rel = blk - 14848;
  const int h = rel >> 4, xi = rel & 15;
  const int Tk = 4096 >> (h >> 1);
  const int mask = Tk - 1;
  if (xi * 256 >= Tk) return;
  const int nb = (Tk >> 1) + 1;
  __shared__ float ct[4096];
  __shared__ float wm[2049];
  const float w0 = 6.283185307179586f / (float)Tk;
  for (int j = tid; j < Tk; j += 256) ct[j] = cosf(w0 * (float)j);
  for (int m = tid; m < nb; m += 256) {
    int band = (m * 8) / nb; if (band > 7) band = 7;
    const float g = 1.f / (1.f + expf(-bg[h * 8 + band]));
    const float sc = (m == 0 || m == nb - 1) ? 1.f : 2.f;
    wm[m] = g * sc / (float)Tk;
  }
  __syncthreads();
  const int n = xi * 256 + tid;
  float acc = 0.f;
  int idx = 0;
  for (int m = 0; m < nb; ++m) {
    acc += wm[m] * ct[idx];
    idx += n;
    if (idx >= Tk) idx -= Tk;
  }
  const u16 bf = f2bf(acc);
  u16* hb = crep + (long)h * 16416;
#pragma unroll
  for (int p = 0; p < 4; ++p) {
    const int q = (n - p) & mask;
    hb[p * 4104 + q] = bf;
    if (q < 8) hb[p * 4104 + q + Tk] = bf;
  }
}

// ---------- async global->LDS ----------
__device__ __forceinline__ void gll16(const void* g, void* l) {
  __builtin_amdgcn_global_load_lds((const __attribute__((address_space(1))) void*)g,
                                   (__attribute__((address_space(3))) void*)l, 16, 0, 0);
}

// ---------- shared bf16 MFMA GEMM core (XOR-swizzled LDS) ----------
// mode: 0 = fp32 C, 1 = bf16 C, 2 = fused K/V transpose write (coalesced via LDS)
__device__ __forceinline__ void gemm_core(const u16* __restrict__ A, const u16* __restrict__ Bt,
    void* __restrict__ Cv, int K, int lda, int ldb, int ldc, int tm, int tn, float alpha,
    int mode, u16 (*lds)[2][128][32],
    u16* KTp = nullptr, u16* VTp = nullptr, int Tkv = 0, int bsel = 0) {
  const int tid = threadIdx.x, lane = tid & 63, wid = tid >> 6;
  const int wr = wid >> 1, wc = wid & 1;
  const int srow = lane >> 2;
  const int scol = ((lane & 3) ^ ((lane >> 3) & 3)) * 8;
  const u16* ga0 = A + (long)(tm + 32 * wid + srow) * lda + scol;
  const u16* ga1 = ga0 + (long)16 * lda;
  const u16* gb0 = Bt + (long)(tn + 32 * wid + srow) * ldb + scol;
  const u16* gb1 = gb0 + (long)16 * ldb;
  f32x4 acc[4][4] = {};
  const int nk = K >> 5;
  gll16(ga0, &lds[0][0][32 * wid][0]);
  gll16(ga1, &lds[0][0][32 * wid + 16][0]);
  gll16(gb0, &lds[0][1][32 * wid][0]);
  gll16(gb1, &lds[0][1][32 * wid + 16][0]);
  int buf = 0;
  const int fr = lane & 15;
  const int fo2 = (((lane >> 4) & 3) ^ ((lane >> 1) & 3)) * 8;
  for (int kt = 0; kt < nk; ++kt) {
    __syncthreads();
    if (kt + 1 < nk) {
      const long ko = (long)(kt + 1) * 32;
      gll16(ga0 + ko, &lds[buf ^ 1][0][32 * wid][0]);
      gll16(ga1 + ko, &lds[buf ^ 1][0][32 * wid + 16][0]);
      gll16(gb0 + ko, &lds[buf ^ 1][1][32 * wid][0]);
      gll16(gb1 + ko, &lds[buf ^ 1][1][32 * wid + 16][0]);
    }
    short8 af[4], bfr[4];
#pragma unroll
    for (int i = 0; i < 4; ++i) {
      af[i]  = *(const short8*)&lds[buf][0][wr * 64 + i * 16 + fr][fo2];
      bfr[i] = *(const short8*)&lds[buf][1][wc * 64 + i * 16 + fr][fo2];
    }
#pragma unroll
    for (int i = 0; i < 4; ++i)
#pragma unroll
      for (int j = 0; j < 4; ++j)
        acc[i][j] = __builtin_amdgcn_mfma_f32_16x16x32_bf16(af[i], bfr[j], acc[i][j], 0, 0, 0);
    buf ^= 1;
  }
  const int er = (lane >> 4) * 4, ec = lane & 15;
  if (mode == 2) {
    // ---- fused K/V transpose, coalesced: acc -> LDS [col][key-quad] -> 256B column stores
    __syncthreads();                       // staging LDS dead; reuse as transpose buffer
    u16* tl = (u16*)lds;                   // 128 cols x 32 quads x 4 u16 = 32 KB exact
    const int kv = (tn >> 8) & 1;          // block-uniform (tn multiple of 128)
    const int hh = (tn >> 7) & 1;
#pragma unroll
    for (int i = 0; i < 4; ++i) {
      const int t0 = wr * 64 + i * 16 + er;          // local key (4-aligned)
      const int q = t0 >> 2;
      // V key-permutation expressed on quads: q' = (q&~15)|q2<<3|q1<<2... (bijective rotate)
      const int qq = kv ? ((q & ~15) | (((q >> 2) & 1) << 3) | ((q & 3) << 1) | ((q >> 3) & 1))
                        : q;
#pragma unroll
      for (int j = 0; j < 4; ++j) {
        const int c = wc * 64 + j * 16 + ec;         // local col 0..127
        const int slot = c * 32 + (qq ^ ((c & 7) << 2));
        short4v v;
#pragma unroll
        for (int r = 0; r < 4; ++r) v[r] = (short)f2bf(acc[i][j][r]);
        *(short4v*)(tl + slot * 4) = v;
      }
    }
    __syncthreads();
    const int tb = tm - bsel * Tkv;                  // group-aligned key base
    u16* dstb = (kv ? VTp : KTp) + (long)(hh * 2 + bsel) * 128 * Tkv + tb;
    const int qs = lane & 31;
    const int ch = lane >> 5;
#pragma unroll
    for (int stp = 0; stp < 16; ++stp) {
      const int c = wid * 32 + stp * 2 + ch;
      const int slot = c * 32 + (qs ^ ((c & 7) << 2));
      short4v v = *(const short4v*)(tl + slot * 4);
      *(short4v*)(dstb + (long)c * Tkv + qs * 4) = v;
    }
  } else if (mode == 1) {
    u16* C = (u16*)Cv;
#pragma unroll
    for (int i = 0; i < 4; ++i)
#pragma unroll
      for (int j = 0; j < 4; ++j)
#pragma unroll
        for (int r = 0; r < 4; ++r)
          C[(long)(tm + wr * 64 + i * 16 + er + r) * ldc + (tn + wc * 64 + j * 16 + ec)] =
              f2bf(acc[i][j][r] * alpha);
  } else {
    float* C = (float*)Cv;
#pragma unroll
    for (int i = 0; i < 4; ++i)
#pragma unroll
      for (int j = 0; j < 4; ++j)
#pragma unroll
        for (int r = 0; r < 4; ++r)
          C[(long)(tm + wr * 64 + i * 16 + er + r) * ldc + (tn + wc * 64 + j * 16 + ec)] =
              acc[i][j][r] * alpha;
  }
}

template <bool OBF>
__global__ __launch_bounds__(256) void gemm_bt(const u16* __restrict__ A, const u16* __restrict__ Bt,
                                               void* __restrict__ Cv, int K, int lda, int ldb, int ldc,
                                               long abs_, long bbs, long cbs, float alpha) {
  __shared__ u16 lds[2][2][128][32];
  const u16* Az = A + (long)blockIdx.z * abs_;
  const u16* Bz = Bt + (long)blockIdx.z * bbs;
  void* Cz = OBF ? (void*)((u16*)Cv + (long)blockIdx.z * cbs)
                 : (void*)((float*)Cv + (long)blockIdx.z * cbs);
  gemm_core(Az, Bz, Cz, K, lda, ldb, ldc, blockIdx.x * 128, blockIdx.y * 128, alpha,
            OBF ? 1 : 0, lds);
}

// ---------- mega-GEMM: Q + KV(direct-transposed) + router hidden ----------
__global__ __launch_bounds__(256) void gemm_p1(const u16* __restrict__ xbf,
    const u16* __restrict__ wqT, const u16* __restrict__ kvT, const u16* __restrict__ rw1T,
    u16* __restrict__ Qb, u16* __restrict__ KT, u16* __restrict__ VT, float* __restrict__ hid) {
  __shared__ u16 lds[2][2][128][32];
  const int bid = blockIdx.x;
  const int id = (bid & 7) * 140 + (bid >> 3);
  if (id < 512) {
    gemm_core(xbf, wqT, Qb, 1024, 1024, 1024, 1024,
              (id >> 3) * 128, (id & 7) * 128, 1.f, 1, lds);
  } else if (id < 992) {
    const int lid = id - 512;
    const int rt = lid >> 2, y = lid & 3;
    int g, lr;
    if (rt < 64)       { g = 0; lr = rt; }
    else if (rt < 96)  { g = 1; lr = rt - 64; }
    else if (rt < 112) { g = 2; lr = rt - 96; }
    else               { g = 3; lr = rt - 112; }
    const long xofs[4] = {0, 8388608, 12582912, 14680064};
    const long ktoff[4] = {0, 2097152, 3145728, 3670016};
    const int Tk = 4096 >> g;
    const int tm = lr * 128;
    const int bsel = (tm >= Tk) ? 1 : 0;
    gemm_core(xbf + xofs[g], kvT + (long)g * 524288, nullptr,
              1024, 1024, 1024, 0, tm, y * 128, 1.f, 2, lds,
              KT + ktoff[g], VT + ktoff[g], Tk, bsel);
  } else {
    const int lid = id - 992;
    gemm_core(xbf, rw1T, hid, 1024, 1024, 1024, 256,
              (lid >> 1) * 128, (lid & 1) * 128, 1.f, 0, lds);
  }
}

// ---------- circulant conv GEMM, BK=128, compact XCD-chunked grid (240 blocks) ----------
__global__ __launch_bounds__(256) void conv_k(const u16* __restrict__ crep,
    const u16* __restrict__ KT, u16* __restrict__ Kp) {
  const int bid = blockIdx.x;
  const int j = (bid & 7) * 30 + (bid >> 3);
  int z, lx;
  if (j < 128)      { z = j >> 5;             lx = j & 31; }
  else if (j < 192) { z = 4 + ((j - 128) >> 4); lx = (j - 128) & 15; }
  else if (j < 224) { z = 8 + ((j - 192) >> 3); lx = (j - 192) & 7; }
  else              { z = 12 + ((j - 224) >> 2); lx = (j - 224) & 3; }
  const int h = z >> 1, b = z & 1, g = h >> 1;
  const int Tk = 4096 >> g, mask = Tk - 1;
  const int tm = lx << 7;
  __shared__ u16 clds[16416];
  __shared__ u16 blds[2][4][128][32];
  const int tid = threadIdx.x, lane = tid & 63, wid = tid >> 6;
  const int wr = wid >> 1, wc = wid & 1;
  const int srow = lane >> 2;
  const int scol = ((lane & 3) ^ ((lane >> 3) & 3)) * 8;
  const int fr = lane & 15, fo = (lane >> 4) * 8;
  const int fo2 = (((lane >> 4) & 3) ^ ((lane >> 1) & 3)) * 8;
  {
    const short8* src = (const short8*)(crep + (long)h * 16416);
    short8* dst = (short8*)clds;
    for (int jj = tid; jj < 2052; jj += 256) dst[jj] = src[jj];
  }
  const long ktofs = 4194304 - (4194304 >> g);
  const u16* Bt = KT + ktofs + (long)((h & 1) * 2 + b) * 128 * Tk;
  u16* out = Kp + ktofs + ((long)(h & 1) << 8) * Tk + ((long)b << 7) * Tk;
  const u16* gb0 = Bt + (long)(32 * wid + srow) * Tk + scol;
  const u16* gb1 = gb0 + (long)16 * Tk;
  f32x4 acc[4][4] = {};
  int base[4];
#pragma unroll
  for (int i = 0; i < 4; ++i) base[i] = (fo - (tm + wr * 64 + i * 16 + fr)) & mask;
  const int p = base[0] & 3;
  const u16* crow = clds + p * 4104;
  const int nk = Tk >> 7;
#pragma unroll
  for (int c = 0; c < 4; ++c) {
    gll16(gb0 + c * 32, &blds[0][c][32 * wid][0]);
    gll16(gb1 + c * 32, &blds[0][c][32 * wid + 16][0]);
  }
  int buf = 0;
  for (int kt = 0; kt < nk; ++kt) {
    __syncthreads();
    if (kt + 1 < nk) {
      const long ko = (long)(kt + 1) * 128;
#pragma unroll
      for (int c = 0; c < 4; ++c) {
        gll16(gb0 + ko + c * 32, &blds[buf ^ 1][c][32 * wid][0]);
        gll16(gb1 + ko + c * 32, &blds[buf ^ 1][c][32 * wid + 16][0]);
      }
    }
#pragma unroll
    for (int c = 0; c < 4; ++c) {
      short8 af[4], bfr[4];
#pragma unroll
      for (int i = 0; i < 4; ++i) {
        const int a0 = base[i] ^ p;
        short4v lo = *(const short4v*)(crow + a0);
        short4v hi = *(const short4v*)(crow + a0 + 4);
        af[i][0] = lo[0]; af[i][1] = lo[1]; af[i][2] = lo[2]; af[i][3] = lo[3];
        af[i][4] = hi[0]; af[i][5] = hi[1]; af[i][6] = hi[2]; af[i][7] = hi[3];
        base[i] = (base[i] + 32) & mask;
        bfr[i] = *(const short8*)&blds[buf][c][wc * 64 + i * 16 + fr][fo2];
      }
#pragma unroll
      for (int i = 0; i < 4; ++i)
#pragma unroll
        for (int jj = 0; jj < 4; ++jj)
          acc[i][jj] = __builtin_amdgcn_mfma_f32_16x16x32_bf16(af[i], bfr[jj], acc[i][jj], 0, 0, 0);
    }
    buf ^= 1;
  }
  const int er = (lane >> 4) * 4, ec = lane & 15;
#pragma unroll
  for (int i = 0; i < 4; ++i)
#pragma unroll
    for (int jj = 0; jj < 4; ++jj)
#pragma unroll
      for (int r = 0; r < 4; ++r)
        out[(long)(tm + wr * 64 + i * 16 + er + r) * 128 + (wc * 64 + jj * 16 + ec)] =
            f2bf(acc[i][jj][r] * ISSL2E);
}

// ---------- flash v7: v4 inner loop, split-K jobs (1024), bf16 partial O + (m,l) ----------
__global__ __launch_bounds__(256, 2) void flash(const u16* __restrict__ Qb,
    const u16* __restrict__ Kp, const u16* __restrict__ VT,
    u16* __restrict__ Op, float* __restrict__ mlb) {
  const int wg = blockIdx.x;
  const int x = wg & 7, s = wg >> 3;
  const int q4 = s >> 5;
  const int lvl = q4 ^ (q4 >> 1);
  const int hh = x >> 2, b = (x >> 1) & 1, kh = x & 1;
  const int h = lvl * 2 + hh;
  const int qtm = (s & 31) << 7;
  const int Tk = 4096 >> lvl;
  const int nt = Tk >> 7;

  __shared__ __align__(16) char smem[65536];
  u16 (*Kl)[4][64][32] = (u16(*)[4][64][32])smem;
  u16 (*Vl)[128][64]   = (u16(*)[128][64])(smem + 32768);

  const int tid = threadIdx.x, lane = tid & 63, wid = tid >> 6;
  const int fr = lane & 15, gs = lane >> 4;
  const int fo = gs * 8;
  const int fo2 = ((gs & 3) ^ ((lane >> 1) & 3)) * 8;

  const long ktofs = 4194304 - (4194304 >> lvl);
  const u16* kbase = Kp + ktofs + (long)(hh * 2 + b) * 128 * Tk + (long)kh * (Tk >> 1) * 128;
  const u16* vbase = VT + ktofs + (long)(hh * 2 + b) * 128 * Tk;

  short8 aq[2][4];
#pragma unroll
  for (int m = 0; m < 2; ++m)
#pragma unroll
    for (int kk = 0; kk < 4; ++kk)
      aq[m][kk] = *(const short8*)(Qb +
          ((long)(b * 4096 + qtm + wid * 32 + m * 16 + fr)) * 1024 + h * 128 + kk * 32 + fo);

  const u16* kptr = kbase + (long)(lane >> 2) * 128 + wid * 32 +
                    (((lane & 3) ^ ((lane >> 3) & 3)) << 3);
  const u16* vptr = vbase + (long)(32 * wid + (lane >> 3)) * Tk + kh * (Tk >> 1) +
                    (((lane & 7) ^ ((lane >> 3) & 7)) << 3);

  const char* kbL  = smem + fr * 64 + fo2 * 2;
  const char* vbL0 = smem + 32768 + fr * 128 + ((((gs    ) ^ (fr & 7)) & 7) << 4);
  const char* vbL1 = smem + 32768 + fr * 128 + ((((gs ^ 4) ^ (fr & 7)) & 7) << 4);

  f32x4 acc[2][8] = {};
  f32x4 accl[2] = {};
  float mr[2] = {-3e38f, -3e38f};

  short8 ones;
#pragma unroll
  for (int i = 0; i < 8; ++i) ones[i] = (short)0x3F80;

#pragma unroll
  for (int i = 0; i < 4; ++i) {
    gll16(kptr + i * 2048, &Kl[0][wid][i * 16][0]);
    gll16(vptr + (long)i * 8 * Tk, &Vl[0][32 * wid + 8 * i][0]);
  }

  int cur = 0;
  for (int kt = 0; kt < nt; ++kt) {
    asm volatile("s_waitcnt vmcnt(0)" ::: "memory");
    __builtin_amdgcn_sched_barrier(0);
    __builtin_amdgcn_s_barrier();
    __builtin_amdgcn_sched_barrier(0);
    if (kt + 1 < nt) {
      const int ktn = kt + 1;
#pragma unroll
      for (int i = 0; i < 4; ++i) {
        gll16(kptr + (long)ktn * 8192 + i * 2048, &Kl[cur ^ 1][wid][i * 16][0]);
        gll16(vptr + (long)ktn * 64 + (long)i * 8 * Tk, &Vl[cur ^ 1][32 * wid + 8 * i][0]);
      }
    }
    const char* kc = kbL + cur * 16384;
    f32x4 sa[2][4] = {};
    __builtin_amdgcn_s_setprio(1);
#pragma unroll
    for (int kk = 0; kk < 4; ++kk) {
      short8 bk[4];
#pragma unroll
      for (int jm = 0; jm < 4; ++jm)
        bk[jm] = *(const short8*)(kc + kk * 4096 + jm * 1024);
#pragma unroll
      for (int m = 0; m < 2; ++m)
#pragma unroll
        for (int jm = 0; jm < 4; ++jm)
          sa[m][jm] = __builtin_amdgcn_mfma_f32_16x16x32_bf16(bk[jm], aq[m][kk], sa[m][jm], 0, 0, 0);
    }
    __builtin_amdgcn_s_setprio(0);
    float tmx[2];
#pragma unroll
    for (int m = 0; m < 2; ++m) {
      float v0 = fmaxf(fmaxf(sa[m][0][0], sa[m][0][1]), fmaxf(sa[m][0][2], sa[m][0][3]));
      float v1 = fmaxf(fmaxf(sa[m][1][0], sa[m][1][1]), fmaxf(sa[m][1][2], sa[m][1][3]));
      float v2 = fmaxf(fmaxf(sa[m][2][0], sa[m][2][1]), fmaxf(sa[m][2][2], sa[m][2][3]));
      float v3 = fmaxf(fmaxf(sa[m][3][0], sa[m][3][1]), fmaxf(sa[m][3][2], sa[m][3][3]));
      float v = fmaxf(fmaxf(v0, v1), fmaxf(v2, v3));
      v = fmaxf(v, __shfl_xor(v, 16));
      v = fmaxf(v, __shfl_xor(v, 32));
      tmx[m] = v;
    }
    const bool need = (tmx[0] > mr[0] + 8.f) | (tmx[1] > mr[1] + 8.f);
    if (__any((int)need)) {
#pragma unroll
      for (int m = 0; m < 2; ++m) {
        const float mn = fmaxf(mr[m], tmx[m]);
        const float av = __builtin_amdgcn_exp2f(mr[m] - mn);
        mr[m] = mn;
#pragma unroll
        for (int jd = 0; jd < 8; ++jd)
#pragma unroll
          for (int r = 0; r < 4; ++r) acc[m][jd][r] *= av;
#pragma unroll
        for (int r = 0; r < 4; ++r) accl[m][r] *= av;
      }
    }
#pragma unroll
    for (int m = 0; m < 2; ++m)
#pragma unroll
      for (int jm = 0; jm < 4; ++jm)
#pragma unroll
        for (int r = 0; r < 4; ++r)
          sa[m][jm][r] = __builtin_amdgcn_exp2f(sa[m][jm][r] - mr[m]);
    unsigned pk[2][4][2];
#pragma unroll
    for (int m = 0; m < 2; ++m)
#pragma unroll
      for (int jm = 0; jm < 4; ++jm) {
        asm("v_cvt_pk_bf16_f32 %0, %1, %2" : "=v"(pk[m][jm][0]) : "v"(sa[m][jm][0]), "v"(sa[m][jm][1]));
        asm("v_cvt_pk_bf16_f32 %0, %1, %2" : "=v"(pk[m][jm][1]) : "v"(sa[m][jm][2]), "v"(sa[m][jm][3]));
      }
    const char* vc0 = vbL0 + cur * 16384;
    const char* vc1 = vbL1 + cur * 16384;
    __builtin_amdgcn_s_setprio(1);
#pragma unroll
    for (int kk = 0; kk < 2; ++kk) {
      short8 pt[2];
#pragma unroll
      for (int m = 0; m < 2; ++m) {
        union { unsigned u[4]; short8 s; } pp;
        pp.u[0] = pk[m][kk][0];     pp.u[1] = pk[m][kk][1];
        pp.u[2] = pk[m][kk + 2][0]; pp.u[3] = pk[m][kk + 2][1];
        pt[m] = pp.s;
      }
      const char* vc = kk ? vc1 : vc0;
#pragma unroll
      for (int jd = 0; jd < 8; ++jd) {
        short8 bb = *(const short8*)(vc + jd * 2048);
#pragma unroll
        for (int m = 0; m < 2; ++m)
          acc[m][jd] = __builtin_amdgcn_mfma_f32_16x16x32_bf16(bb, pt[m], acc[m][jd], 0, 0, 0);
      }
#pragma unroll
      for (int m = 0; m < 2; ++m)
        accl[m] = __builtin_amdgcn_mfma_f32_16x16x32_bf16(ones, pt[m], accl[m], 0, 0, 0);
    }
    __builtin_amdgcn_s_setprio(0);
    cur ^= 1;
  }
  __syncthreads();
  float* Ot = (float*)smem;
  float* ot = Ot + wid * 16 * 132;
  u16* Obase = Op + (long)kh * 8388608;
#pragma unroll
  for (int m = 0; m < 2; ++m) {
#pragma unroll
    for (int jd = 0; jd < 8; ++jd)
      *(f32x4*)&ot[fr * 132 + jd * 16 + gs * 4] = acc[m][jd];
    asm volatile("s_waitcnt lgkmcnt(0)" ::: "memory");
    __builtin_amdgcn_sched_barrier(0);
    const int q = qtm + wid * 32 + m * 16 + (lane >> 2);
    u16* od = Obase + ((long)(b * 4096 + q) * 8 + h) * 128 + (lane & 3) * 32;
#pragma unroll
    for (int j = 0; j < 8; ++j) {
      f32x4 v = *(const f32x4*)&ot[(lane >> 2) * 132 + (lane & 3) * 32 + j * 4];
      short4v sv;
#pragma unroll
      for (int r = 0; r < 4; ++r) sv[r] = (short)f2bf(v[r]);
      *(short4v*)(od + j * 4) = sv;
    }
    asm volatile("s_waitcnt lgkmcnt(0)" ::: "memory");
    __builtin_amdgcn_sched_barrier(0);
    if (gs == 0) {
      const int q2 = qtm + wid * 32 + m * 16 + fr;
      ((float2*)mlb)[(long)kh * 65536 + (long)(b * 4096 + q2) * 8 + h] =
          make_float2(mr[m], accl[m][0]);
    }
  }
}

// ---------- fused router + flash-combine + contra-flow + head mixing ----------
__global__ __launch_bounds__(256) void router_mix(const float* __restrict__ hid,
    const float* __restrict__ rb1, const float* __restrict__ rW2, const float* __restrict__ rb2,
    const float* __restrict__ al, const u16* __restrict__ Op, const float* __restrict__ mlb,
    u16* __restrict__ mixed) {
  const int tok = blockIdx.x;
  const int b = tok >> 12, t = tok & 4095;
  const int rtok = b * 4096 + (4095 - t);
  const int tid = threadIdx.x;
  __shared__ float lred[4][8];
  __shared__ float wgt[8];
  __shared__ float ta[8];
  __shared__ float el[2][8][2];
  const float hv = fmaxf(hid[(long)tok * 256 + tid] + rb1[tid], 0.f);
  const float4* w4 = (const float4*)(rW2 + tid * 8);
  const float4 wa = w4[0], wb = w4[1];
  float part[8] = {hv * wa.x, hv * wa.y, hv * wa.z, hv * wa.w,
                   hv * wb.x, hv * wb.y, hv * wb.z, hv * wb.w};
#pragma unroll
  for (int h = 0; h < 8; ++h) {
    float v = part[h];
#pragma unroll
    for (int o = 1; o < 64; o <<= 1) v += __shfl_xor(v, o);
    if ((tid & 63) == 0) lred[tid >> 6][h] = v;
  }
  if (tid >= 64 && tid < 80) {
    const int j = tid - 64;
    const int h = j & 7, which = j >> 3;
    const long tk = which ? rtok : tok;
    const float2 a = ((const float2*)mlb)[tk * 8 + h];
    const float2 c = ((const float2*)mlb)[65536 + tk * 8 + h];
    const float M = fmaxf(a.x, c.x);
    const float w1 = exp2f(a.x - M), w2 = exp2f(c.x - M);
    const float inv = 1.f / (w1 * a.y + w2 * c.y);
    el[which][h][0] = w1 * inv;
    el[which][h][1] = w2 * inv;
  }
  __syncthreads();
  if (tid < 8) ta[tid] = tanhf(al[tid]);
  if (tid == 0) {
    float lg[8], m = -1e30f;
#pragma unroll
    for (int h = 0; h < 8; ++h) {
      lg[h] = lred[0][h] + lred[1][h] + lred[2][h] + lred[3][h] + rb2[h];
      m = fmaxf(m, lg[h]);
    }
    float s = 0.f;
#pragma unroll
    for (int h = 0; h < 8; ++h) { lg[h] = __expf(lg[h] - m); s += lg[h]; }
    const float inv = 1.f / s;
#pragma unroll
    for (int h = 0; h < 8; ++h) wgt[h] = lg[h] * inv;
  }
  __syncthreads();
  if (tid < 128) {
    const long base = (long)tok * 1024 + tid;
    const long rbase = (long)rtok * 1024 + tid;
    float acc = 0.f;
#pragma unroll
    for (int h = 0; h < 8; ++h) {
      const float o = el[0][h][0] * bf2f(Op[base + h * 128]) +
                      el[0][h][1] * bf2f(Op[8388608 + base + h * 128]);
      const float orv = el[1][h][0] * bf2f(Op[rbase + h * 128]) +
                        el[1][h][1] * bf2f(Op[8388608 + rbase + h * 128]);
      acc += wgt[h] * (o + ta[h] * orv);
    }
    mixed[(long)tok * 128 + tid] = f2bf(acc);
  }
}

extern "C" void kernel_launch(void* const* d_in, const int* in_sizes, int n_in,
                              void* d_out, int out_size, void* d_ws, size_t ws_size,
                              hipStream_t stream) {
  const float* x    = (const float*)d_in[0];
  const float* Wq   = (const float*)d_in[1];
  const float* Wk   = (const float*)d_in[2];
  const float* Wv   = (const float*)d_in[3];
  const float* bg   = (const float*)d_in[4];
  const float* al   = (const float*)d_in[5];
  const float* rW1  = (const float*)d_in[6];
  const float* rb1  = (const float*)d_in[7];
  const float* rW2  = (const float*)d_in[8];
  const float* rb2  = (const float*)d_in[9];
  const float* Wout = (const float*)d_in[10];
  float* out = (float*)d_out;

  // ---- arena (lifetime overlays, ~97 MB) ----
  const size_t MB = 1u << 20;
  char* w = (char*)d_ws;
  u16*   xbf   = (u16*)(w + 0);            // 16 MB [P0-P1]
  u16*   Op    = (u16*)(w + 0);            // 32 MB bf16 [2][...] [P4-P5] overlays dead pools
  u16*   Qb    = (u16*)(w + 32 * MB);      // 16 MB [P1-P4]
  u16*   Kp    = (u16*)(w + 48 * MB);      // 7.5MB [P3-P4]
  u16*   KT    = (u16*)(w + 63 * MB);      // 7.5MB [P1-P3]
  u16*   VT    = (u16*)(w + 70 * MB + 512 * 1024); // 7.5MB [P1-P4]
  float* hid   = (float*)(w + 78 * MB);    //  8 MB [P1-P5]
  u16*   wqT   = (u16*)(w + 86 * MB);      //  2 MB
  u16*   kvT   = (u16*)(w + 88 * MB);      //  4 MB
  u16*   rw1T  = (u16*)(w + 92 * MB);      // 512 KB
  u16*   woutT = (u16*)(w + 92 * MB + 512 * 1024);   // 256 KB
  u16*   crep  = (u16*)(w + 92 * MB + 768 * 1024);   // 257 KB
  u16*   mixed = (u16*)(w + 93 * MB + 512 * 1024);   //  2 MB
  float* mlbuf = (float*)(w + 95 * MB + 512 * 1024); //  1 MB [P4-P5]
  u16*   xp2   = (u16*)(w + 16 * MB);
  u16*   xp4   = (u16*)(w + 24 * MB);
  u16*   xp8   = (u16*)(w + 28 * MB);

  // P0: pooling + weight prep + irfft (one launch)
  prep_all<<<dim3(14976), dim3(256), 0, stream>>>(x, Wq, Wk, Wv, rW1, Wout, bg,
      xbf, xp2, xp4, xp8, wqT, kvT, rw1T, woutT, crep);

  // P1: Q + KV (coalesced direct-transposed KT/VT) + router hidden, one launch
  gemm_p1<<<dim3(1120), dim3(256), 0, stream>>>(xbf, wqT, kvT, rw1T, Qb, KT, VT, hid);

  // P3: circulant conv (BK=128, compact XCD-chunked 240-block grid)
  conv_k<<<dim3(240), dim3(256), 0, stream>>>(crep, KT, Kp);

  // P4: flash v7 (split-K, 1024 jobs, v4 inner loop; bf16 partials + ml)
  flash<<<dim3(1024), dim3(256), 0, stream>>>(Qb, Kp, VT, Op, mlbuf);

  // P5: router + flash-combine + mix, then output projection
  router_mix<<<dim3(8192), dim3(256), 0, stream>>>(hid, rb1, rW2, rb2, al, Op, mlbuf, mixed);
  gemm_bt<false><<<dim3(64, 8), dim3(256), 0, stream>>>(mixed, woutT, out,
      128, 128, 128, 1024, 0, 0, 0, 1.f);
}

// Round 20
// 282.043 us; speedup vs baseline: 1.3550x; 1.0470x over previous
//
#include <hip/hip_runtime.h>
#include <hip/hip_bf16.h>

typedef __attribute__((ext_vector_type(8))) short short8;
typedef __attribute__((ext_vector_type(4))) short short4v;
typedef __attribute__((ext_vector_type(4))) float f32x4;
typedef unsigned short u16;

#define T_ 4096
#define D_ 1024
#define ISSL2E (0.08838834764831845f * 1.4426950408889634f)   // 1/sqrt(128) * log2(e)

__device__ __forceinline__ u16 f2bf(float f) {
  union { float f; unsigned u; } v; v.f = f;
  unsigned r = v.u + 0x7FFFu + ((v.u >> 16) & 1u);
  return (u16)(r >> 16);
}
__device__ __forceinline__ float bf2f(u16 u) {
  union { unsigned u; float f; } v; v.u = ((unsigned)u) << 16; return v.f;
}

// ---------- fused prep: pooling + LDS-tiled weight transposes + irfft ----------
// grid 4608: [0,1024) pooling | [1024,2048) wqT | [2048,4096) kvT
//            [4096,4352) rw1T | [4352,4480) woutT | [4480,4608) irfft
__global__ __launch_bounds__(256) void prep_all(const float* __restrict__ x,
    const float* __restrict__ Wq, const float* __restrict__ Wk, const float* __restrict__ Wv,
    const float* __restrict__ rW1, const float* __restrict__ Wout, const float* __restrict__ bg,
    u16* __restrict__ p1, u16* __restrict__ p2, u16* __restrict__ p4, u16* __restrict__ p8,
    u16* __restrict__ wqT, u16* __restrict__ kvT, u16* __restrict__ rw1T, u16* __restrict__ woutT,
    u16* __restrict__ crep) {
  const int blk = blockIdx.x;
  const int tid = threadIdx.x;
  if (blk < 1024) {                          // ---- pooling ----
    const int b = blk >> 9, t0 = (blk & 511) << 3;
    const float* src = x + ((long)b * T_ + t0) * D_;
#pragma unroll
    for (int j = 0; j < 4; ++j) {
      const int c = tid + j * 256;
      float v[8];
#pragma unroll
      for (int r = 0; r < 8; ++r) v[r] = src[r * D_ + c];
#pragma unroll
      for (int r = 0; r < 8; ++r) p1[((long)b * 4096 + t0 + r) * D_ + c] = f2bf(v[r]);
#pragma unroll
      for (int r = 0; r < 4; ++r)
        p2[((long)b * 2048 + (t0 >> 1) + r) * D_ + c] = f2bf((v[2*r] + v[2*r+1]) * 0.5f);
#pragma unroll
      for (int r = 0; r < 2; ++r)
        p4[((long)b * 1024 + (t0 >> 2) + r) * D_ + c] =
            f2bf((v[4*r] + v[4*r+1] + v[4*r+2] + v[4*r+3]) * 0.25f);
      p8[((long)b * 512 + (t0 >> 3)) * D_ + c] =
          f2bf((v[0]+v[1]+v[2]+v[3]+v[4]+v[5]+v[6]+v[7]) * 0.125f);
    }
    return;
  }
  if (blk < 4480) {                          // ---- LDS-tiled weight transposes ----
    __shared__ float tile[32][33];
    const int ci = tid & 31, r0 = tid >> 5;  // 32 x 8, loop 4
    const float* src; u16* dst;
    int sR = 0, dR = 0;                      // src row stride (floats), dst row stride (u16)
    if (blk < 2048) {                        // wqT: [h][c][k] <- Wq[h][k][c]
      const int rel = blk - 1024;
      const int h = rel >> 7, rem = rel & 127;
      const int k0 = (rem >> 2) * 32, c0 = (rem & 3) * 32;
      src = Wq + (long)h * 131072 + (long)k0 * 128 + c0;   sR = 128;
      dst = wqT + (long)h * 131072 + (long)c0 * 1024 + k0; dR = 1024;
    } else if (blk < 4096) {                 // kvT: [g][kv|hh|c][k] <- W[2g+hh][k][c]
      const int rel = blk - 2048;
      const int g = rel >> 9, rem = rel & 511;
      const int kvh = rem >> 7, rem2 = rem & 127;
      const int kv = kvh >> 1, hh = kvh & 1;
      const int c0 = (rem2 >> 5) * 32, k0 = (rem2 & 31) * 32;
      const float* W = kv ? Wv : Wk;
      src = W + (long)(2 * g + hh) * 131072 + (long)k0 * 128 + c0;  sR = 128;
      dst = kvT + (long)g * 524288 + (long)(kv * 256 + hh * 128 + c0) * 1024 + k0; dR = 1024;
    } else if (blk < 4352) {                 // rw1T: [n][k] <- rW1[k][n]
      const int rel = blk - 4096;
      const int n0 = (rel >> 5) * 32, k0 = (rel & 31) * 32;
      src = rW1 + (long)k0 * 256 + n0;   sR = 256;
      dst = rw1T + (long)n0 * 1024 + k0; dR = 1024;
    } else {                                 // woutT: [n][k] <- Wout[k][n]
      const int rel = blk - 4352;
      const int n0 = (rel >> 2) * 32, k0 = (rel & 3) * 32;
      src = Wout + (long)k0 * 1024 + n0;  sR = 1024;
      dst = woutT + (long)n0 * 128 + k0;  dR = 128;
    }
#pragma unroll
    for (int j = 0; j < 4; ++j) {
      const int r = j * 8 + r0;
      tile[r][ci] = src[(long)r * sR + ci];        // coalesced read (consecutive ci)
    }
    __syncthreads();
#pragma unroll
    for (int j = 0; j < 4; ++j) {
      const int r = j * 8 + r0;
      dst[(long)r * dR + ci] = f2bf(tile[ci][r]);  // coalesced write
    }
    return;
  }
  // ---- irfft: conv kernel c per head, 4 phase-shifted replicas ----
  const int rel = blk - 4480;
  const int h = rel >> 4, xi = rel & 15;
  const int Tk = 4096 >> (h >> 1);
  const int mask = Tk - 1;
  if (xi * 256 >= Tk) return;
  const int nb = (Tk >> 1) + 1;
  __shared__ float ct[4096];
  __shared__ float wm[2049];
  const float w0 = 6.283185307179586f / (float)Tk;
  for (int j = tid; j < Tk; j += 256) ct[j] = cosf(w0 * (float)j);
  for (int m = tid; m < nb; m += 256) {
    int band = (m * 8) / nb; if (band > 7) band = 7;
    const float g = 1.f / (1.f + expf(-bg[h * 8 + band]));
    const float sc = (m == 0 || m == nb - 1) ? 1.f : 2.f;
    wm[m] = g * sc / (float)Tk;
  }
  __syncthreads();
  const int n = xi * 256 + tid;
  float acc = 0.f;
  int idx = 0;
  for (int m = 0; m < nb; ++m) {
    acc += wm[m] * ct[idx];
    idx += n;
    if (idx >= Tk) idx -= Tk;
  }
  const u16 bf = f2bf(acc);
  u16* hb = crep + (long)h * 16416;
#pragma unroll
  for (int p = 0; p < 4; ++p) {
    const int q = (n - p) & mask;
    hb[p * 4104 + q] = bf;
    if (q < 8) hb[p * 4104 + q + Tk] = bf;
  }
}

// ---------- async global->LDS ----------
__device__ __forceinline__ void gll16(const void* g, void* l) {
  __builtin_amdgcn_global_load_lds((const __attribute__((address_space(1))) void*)g,
                                   (__attribute__((address_space(3))) void*)l, 16, 0, 0);
}

// ---------- shared bf16 MFMA GEMM core (XOR-swizzled LDS) ----------
// mode: 0 = fp32 C, 1 = bf16 C, 2 = fused K/V transpose write (coalesced via LDS)
__device__ __forceinline__ void gemm_core(const u16* __restrict__ A, const u16* __restrict__ Bt,
    void* __restrict__ Cv, int K, int lda, int ldb, int ldc, int tm, int tn, float alpha,
    int mode, u16 (*lds)[2][128][32],
    u16* KTp = nullptr, u16* VTp = nullptr, int Tkv = 0, int bsel = 0) {
  const int tid = threadIdx.x, lane = tid & 63, wid = tid >> 6;
  const int wr = wid >> 1, wc = wid & 1;
  const int srow = lane >> 2;
  const int scol = ((lane & 3) ^ ((lane >> 3) & 3)) * 8;
  const u16* ga0 = A + (long)(tm + 32 * wid + srow) * lda + scol;
  const u16* ga1 = ga0 + (long)16 * lda;
  const u16* gb0 = Bt + (long)(tn + 32 * wid + srow) * ldb + scol;
  const u16* gb1 = gb0 + (long)16 * ldb;
  f32x4 acc[4][4] = {};
  const int nk = K >> 5;
  gll16(ga0, &lds[0][0][32 * wid][0]);
  gll16(ga1, &lds[0][0][32 * wid + 16][0]);
  gll16(gb0, &lds[0][1][32 * wid][0]);
  gll16(gb1, &lds[0][1][32 * wid + 16][0]);
  int buf = 0;
  const int fr = lane & 15;
  const int fo2 = (((lane >> 4) & 3) ^ ((lane >> 1) & 3)) * 8;
  for (int kt = 0; kt < nk; ++kt) {
    __syncthreads();
    if (kt + 1 < nk) {
      const long ko = (long)(kt + 1) * 32;
      gll16(ga0 + ko, &lds[buf ^ 1][0][32 * wid][0]);
      gll16(ga1 + ko, &lds[buf ^ 1][0][32 * wid + 16][0]);
      gll16(gb0 + ko, &lds[buf ^ 1][1][32 * wid][0]);
      gll16(gb1 + ko, &lds[buf ^ 1][1][32 * wid + 16][0]);
    }
    short8 af[4], bfr[4];
#pragma unroll
    for (int i = 0; i < 4; ++i) {
      af[i]  = *(const short8*)&lds[buf][0][wr * 64 + i * 16 + fr][fo2];
      bfr[i] = *(const short8*)&lds[buf][1][wc * 64 + i * 16 + fr][fo2];
    }
#pragma unroll
    for (int i = 0; i < 4; ++i)
#pragma unroll
      for (int j = 0; j < 4; ++j)
        acc[i][j] = __builtin_amdgcn_mfma_f32_16x16x32_bf16(af[i], bfr[j], acc[i][j], 0, 0, 0);
    buf ^= 1;
  }
  const int er = (lane >> 4) * 4, ec = lane & 15;
  if (mode == 2) {
    __syncthreads();
    u16* tl = (u16*)lds;
    const int kv = (tn >> 8) & 1;
    const int hh = (tn >> 7) & 1;
#pragma unroll
    for (int i = 0; i < 4; ++i) {
      const int t0 = wr * 64 + i * 16 + er;
      const int q = t0 >> 2;
      const int qq = kv ? ((q & ~15) | (((q >> 2) & 1) << 3) | ((q & 3) << 1) | ((q >> 3) & 1))
                        : q;
#pragma unroll
      for (int j = 0; j < 4; ++j) {
        const int c = wc * 64 + j * 16 + ec;
        const int slot = c * 32 + (qq ^ ((c & 7) << 2));
        short4v v;
#pragma unroll
        for (int r = 0; r < 4; ++r) v[r] = (short)f2bf(acc[i][j][r]);
        *(short4v*)(tl + slot * 4) = v;
      }
    }
    __syncthreads();
    const int tb = tm - bsel * Tkv;
    u16* dstb = (kv ? VTp : KTp) + (long)(hh * 2 + bsel) * 128 * Tkv + tb;
    const int qs = lane & 31;
    const int ch = lane >> 5;
#pragma unroll
    for (int stp = 0; stp < 16; ++stp) {
      const int c = wid * 32 + stp * 2 + ch;
      const int slot = c * 32 + (qs ^ ((c & 7) << 2));
      short4v v = *(const short4v*)(tl + slot * 4);
      *(short4v*)(dstb + (long)c * Tkv + qs * 4) = v;
    }
  } else if (mode == 1) {
    u16* C = (u16*)Cv;
#pragma unroll
    for (int i = 0; i < 4; ++i)
#pragma unroll
      for (int j = 0; j < 4; ++j)
#pragma unroll
        for (int r = 0; r < 4; ++r)
          C[(long)(tm + wr * 64 + i * 16 + er + r) * ldc + (tn + wc * 64 + j * 16 + ec)] =
              f2bf(acc[i][j][r] * alpha);
  } else {
    float* C = (float*)Cv;
#pragma unroll
    for (int i = 0; i < 4; ++i)
#pragma unroll
      for (int j = 0; j < 4; ++j)
#pragma unroll
        for (int r = 0; r < 4; ++r)
          C[(long)(tm + wr * 64 + i * 16 + er + r) * ldc + (tn + wc * 64 + j * 16 + ec)] =
              acc[i][j][r] * alpha;
  }
}

template <bool OBF>
__global__ __launch_bounds__(256) void gemm_bt(const u16* __restrict__ A, const u16* __restrict__ Bt,
                                               void* __restrict__ Cv, int K, int lda, int ldb, int ldc,
                                               long abs_, long bbs, long cbs, float alpha) {
  __shared__ u16 lds[2][2][128][32];
  const u16* Az = A + (long)blockIdx.z * abs_;
  const u16* Bz = Bt + (long)blockIdx.z * bbs;
  void* Cz = OBF ? (void*)((u16*)Cv + (long)blockIdx.z * cbs)
                 : (void*)((float*)Cv + (long)blockIdx.z * cbs);
  gemm_core(Az, Bz, Cz, K, lda, ldb, ldc, blockIdx.x * 128, blockIdx.y * 128, alpha,
            OBF ? 1 : 0, lds);
}

// ---------- mega-GEMM: Q + KV(direct-transposed) + router hidden (bf16) ----------
__global__ __launch_bounds__(256) void gemm_p1(const u16* __restrict__ xbf,
    const u16* __restrict__ wqT, const u16* __restrict__ kvT, const u16* __restrict__ rw1T,
    u16* __restrict__ Qb, u16* __restrict__ KT, u16* __restrict__ VT, u16* __restrict__ hid) {
  __shared__ u16 lds[2][2][128][32];
  const int bid = blockIdx.x;
  const int id = (bid & 7) * 140 + (bid >> 3);
  if (id < 512) {
    gemm_core(xbf, wqT, Qb, 1024, 1024, 1024, 1024,
              (id >> 3) * 128, (id & 7) * 128, 1.f, 1, lds);
  } else if (id < 992) {
    const int lid = id - 512;
    const int rt = lid >> 2, y = lid & 3;
    int g, lr;
    if (rt < 64)       { g = 0; lr = rt; }
    else if (rt < 96)  { g = 1; lr = rt - 64; }
    else if (rt < 112) { g = 2; lr = rt - 96; }
    else               { g = 3; lr = rt - 112; }
    const long xofs[4] = {0, 8388608, 12582912, 14680064};
    const long ktoff[4] = {0, 2097152, 3145728, 3670016};
    const int Tk = 4096 >> g;
    const int tm = lr * 128;
    const int bsel = (tm >= Tk) ? 1 : 0;
    gemm_core(xbf + xofs[g], kvT + (long)g * 524288, nullptr,
              1024, 1024, 1024, 0, tm, y * 128, 1.f, 2, lds,
              KT + ktoff[g], VT + ktoff[g], Tk, bsel);
  } else {
    const int lid = id - 992;
    gemm_core(xbf, rw1T, hid, 1024, 1024, 1024, 256,
              (lid >> 1) * 128, (lid & 1) * 128, 1.f, 1, lds);
  }
}

// ---------- circulant conv GEMM, BK=128, compact XCD-chunked grid (240 blocks) ----------
__global__ __launch_bounds__(256) void conv_k(const u16* __restrict__ crep,
    const u16* __restrict__ KT, u16* __restrict__ Kp) {
  const int bid = blockIdx.x;
  const int j = (bid & 7) * 30 + (bid >> 3);
  int z, lx;
  if (j < 128)      { z = j >> 5;             lx = j & 31; }
  else if (j < 192) { z = 4 + ((j - 128) >> 4); lx = (j - 128) & 15; }
  else if (j < 224) { z = 8 + ((j - 192) >> 3); lx = (j - 192) & 7; }
  else              { z = 12 + ((j - 224) >> 2); lx = (j - 224) & 3; }
  const int h = z >> 1, b = z & 1, g = h >> 1;
  const int Tk = 4096 >> g, mask = Tk - 1;
  const int tm = lx << 7;
  __shared__ u16 clds[16416];
  __shared__ u16 blds[2][4][128][32];
  const int tid = threadIdx.x, lane = tid & 63, wid = tid >> 6;
  const int wr = wid >> 1, wc = wid & 1;
  const int srow = lane >> 2;
  const int scol = ((lane & 3) ^ ((lane >> 3) & 3)) * 8;
  const int fr = lane & 15, fo = (lane >> 4) * 8;
  const int fo2 = (((lane >> 4) & 3) ^ ((lane >> 1) & 3)) * 8;
  {
    const short8* src = (const short8*)(crep + (long)h * 16416);
    short8* dst = (short8*)clds;
    for (int jj = tid; jj < 2052; jj += 256) dst[jj] = src[jj];
  }
  const long ktofs = 4194304 - (4194304 >> g);
  const u16* Bt = KT + ktofs + (long)((h & 1) * 2 + b) * 128 * Tk;
  u16* out = Kp + ktofs + ((long)(h & 1) << 8) * Tk + ((long)b << 7) * Tk;
  const u16* gb0 = Bt + (long)(32 * wid + srow) * Tk + scol;
  const u16* gb1 = gb0 + (long)16 * Tk;
  f32x4 acc[4][4] = {};
  int base[4];
#pragma unroll
  for (int i = 0; i < 4; ++i) base[i] = (fo - (tm + wr * 64 + i * 16 + fr)) & mask;
  const int p = base[0] & 3;
  const u16* crow = clds + p * 4104;
  const int nk = Tk >> 7;
#pragma unroll
  for (int c = 0; c < 4; ++c) {
    gll16(gb0 + c * 32, &blds[0][c][32 * wid][0]);
    gll16(gb1 + c * 32, &blds[0][c][32 * wid + 16][0]);
  }
  int buf = 0;
  for (int kt = 0; kt < nk; ++kt) {
    __syncthreads();
    if (kt + 1 < nk) {
      const long ko = (long)(kt + 1) * 128;
#pragma unroll
      for (int c = 0; c < 4; ++c) {
        gll16(gb0 + ko + c * 32, &blds[buf ^ 1][c][32 * wid][0]);
        gll16(gb1 + ko + c * 32, &blds[buf ^ 1][c][32 * wid + 16][0]);
      }
    }
#pragma unroll
    for (int c = 0; c < 4; ++c) {
      short8 af[4], bfr[4];
#pragma unroll
      for (int i = 0; i < 4; ++i) {
        const int a0 = base[i] ^ p;
        short4v lo = *(const short4v*)(crow + a0);
        short4v hi = *(const short4v*)(crow + a0 + 4);
        af[i][0] = lo[0]; af[i][1] = lo[1]; af[i][2] = lo[2]; af[i][3] = lo[3];
        af[i][4] = hi[0]; af[i][5] = hi[1]; af[i][6] = hi[2]; af[i][7] = hi[3];
        base[i] = (base[i] + 32) & mask;
        bfr[i] = *(const short8*)&blds[buf][c][wc * 64 + i * 16 + fr][fo2];
      }
#pragma unroll
      for (int i = 0; i < 4; ++i)
#pragma unroll
        for (int jj = 0; jj < 4; ++jj)
          acc[i][jj] = __builtin_amdgcn_mfma_f32_16x16x32_bf16(af[i], bfr[jj], acc[i][jj], 0, 0, 0);
    }
    buf ^= 1;
  }
  const int er = (lane >> 4) * 4, ec = lane & 15;
#pragma unroll
  for (int i = 0; i < 4; ++i)
#pragma unroll
    for (int jj = 0; jj < 4; ++jj)
#pragma unroll
      for (int r = 0; r < 4; ++r)
        out[(long)(tm + wr * 64 + i * 16 + er + r) * 128 + (wc * 64 + jj * 16 + ec)] =
            f2bf(acc[i][jj][r] * ISSL2E);
}

// ---------- flash v7: v4 inner loop, split-K jobs (1024), bf16 partial O + (m,l) ----------
__global__ __launch_bounds__(256, 2) void flash(const u16* __restrict__ Qb,
    const u16* __restrict__ Kp, const u16* __restrict__ VT,
    u16* __restrict__ Op, float* __restrict__ mlb) {
  const int wg = blockIdx.x;
  const int x = wg & 7, s = wg >> 3;
  const int q4 = s >> 5;
  const int lvl = q4 ^ (q4 >> 1);
  const int hh = x >> 2, b = (x >> 1) & 1, kh = x & 1;
  const int h = lvl * 2 + hh;
  const int qtm = (s & 31) << 7;
  const int Tk = 4096 >> lvl;
  const int nt = Tk >> 7;

  __shared__ __align__(16) char smem[65536];
  u16 (*Kl)[4][64][32] = (u16(*)[4][64][32])smem;
  u16 (*Vl)[128][64]   = (u16(*)[128][64])(smem + 32768);

  const int tid = threadIdx.x, lane = tid & 63, wid = tid >> 6;
  const int fr = lane & 15, gs = lane >> 4;
  const int fo = gs * 8;
  const int fo2 = ((gs & 3) ^ ((lane >> 1) & 3)) * 8;

  const long ktofs = 4194304 - (4194304 >> lvl);
  const u16* kbase = Kp + ktofs + (long)(hh * 2 + b) * 128 * Tk + (long)kh * (Tk >> 1) * 128;
  const u16* vbase = VT + ktofs + (long)(hh * 2 + b) * 128 * Tk;

  short8 aq[2][4];
#pragma unroll
  for (int m = 0; m < 2; ++m)
#pragma unroll
    for (int kk = 0; kk < 4; ++kk)
      aq[m][kk] = *(const short8*)(Qb +
          ((long)(b * 4096 + qtm + wid * 32 + m * 16 + fr)) * 1024 + h * 128 + kk * 32 + fo);

  const u16* kptr = kbase + (long)(lane >> 2) * 128 + wid * 32 +
                    (((lane & 3) ^ ((lane >> 3) & 3)) << 3);
  const u16* vptr = vbase + (long)(32 * wid + (lane >> 3)) * Tk + kh * (Tk >> 1) +
                    (((lane & 7) ^ ((lane >> 3) & 7)) << 3);

  const char* kbL  = smem + fr * 64 + fo2 * 2;
  const char* vbL0 = smem + 32768 + fr * 128 + ((((gs    ) ^ (fr & 7)) & 7) << 4);
  const char* vbL1 = smem + 32768 + fr * 128 + ((((gs ^ 4) ^ (fr & 7)) & 7) << 4);

  f32x4 acc[2][8] = {};
  f32x4 accl[2] = {};
  float mr[2] = {-3e38f, -3e38f};

  short8 ones;
#pragma unroll
  for (int i = 0; i < 8; ++i) ones[i] = (short)0x3F80;

#pragma unroll
  for (int i = 0; i < 4; ++i) {
    gll16(kptr + i * 2048, &Kl[0][wid][i * 16][0]);
    gll16(vptr + (long)i * 8 * Tk, &Vl[0][32 * wid + 8 * i][0]);
  }

  int cur = 0;
  for (int kt = 0; kt < nt; ++kt) {
    asm volatile("s_waitcnt vmcnt(0)" ::: "memory");
    __builtin_amdgcn_sched_barrier(0);
    __builtin_amdgcn_s_barrier();
    __builtin_amdgcn_sched_barrier(0);
    if (kt + 1 < nt) {
      const int ktn = kt + 1;
#pragma unroll
      for (int i = 0; i < 4; ++i) {
        gll16(kptr + (long)ktn * 8192 + i * 2048, &Kl[cur ^ 1][wid][i * 16][0]);
        gll16(vptr + (long)ktn * 64 + (long)i * 8 * Tk, &Vl[cur ^ 1][32 * wid + 8 * i][0]);
      }
    }
    const char* kc = kbL + cur * 16384;
    f32x4 sa[2][4] = {};
    __builtin_amdgcn_s_setprio(1);
#pragma unroll
    for (int kk = 0; kk < 4; ++kk) {
      short8 bk[4];
#pragma unroll
      for (int jm = 0; jm < 4; ++jm)
        bk[jm] = *(const short8*)(kc + kk * 4096 + jm * 1024);
#pragma unroll
      for (int m = 0; m < 2; ++m)
#pragma unroll
        for (int jm = 0; jm < 4; ++jm)
          sa[m][jm] = __builtin_amdgcn_mfma_f32_16x16x32_bf16(bk[jm], aq[m][kk], sa[m][jm], 0, 0, 0);
    }
    __builtin_amdgcn_s_setprio(0);
    float tmx[2];
#pragma unroll
    for (int m = 0; m < 2; ++m) {
      float v0 = fmaxf(fmaxf(sa[m][0][0], sa[m][0][1]), fmaxf(sa[m][0][2], sa[m][0][3]));
      float v1 = fmaxf(fmaxf(sa[m][1][0], sa[m][1][1]), fmaxf(sa[m][1][2], sa[m][1][3]));
      float v2 = fmaxf(fmaxf(sa[m][2][0], sa[m][2][1]), fmaxf(sa[m][2][2], sa[m][2][3]));
      float v3 = fmaxf(fmaxf(sa[m][3][0], sa[m][3][1]), fmaxf(sa[m][3][2], sa[m][3][3]));
      float v = fmaxf(fmaxf(v0, v1), fmaxf(v2, v3));
      v = fmaxf(v, __shfl_xor(v, 16));
      v = fmaxf(v, __shfl_xor(v, 32));
      tmx[m] = v;
    }
    const bool need = (tmx[0] > mr[0] + 8.f) | (tmx[1] > mr[1] + 8.f);
    if (__any((int)need)) {
#pragma unroll
      for (int m = 0; m < 2; ++m) {
        const float mn = fmaxf(mr[m], tmx[m]);
        const float av = __builtin_amdgcn_exp2f(mr[m] - mn);
        mr[m] = mn;
#pragma unroll
        for (int jd = 0; jd < 8; ++jd)
#pragma unroll
          for (int r = 0; r < 4; ++r) acc[m][jd][r] *= av;
#pragma unroll
        for (int r = 0; r < 4; ++r) accl[m][r] *= av;
      }
    }
#pragma unroll
    for (int m = 0; m < 2; ++m)
#pragma unroll
      for (int jm = 0; jm < 4; ++jm)
#pragma unroll
        for (int r = 0; r < 4; ++r)
          sa[m][jm][r] = __builtin_amdgcn_exp2f(sa[m][jm][r] - mr[m]);
    unsigned pk[2][4][2];
#pragma unroll
    for (int m = 0; m < 2; ++m)
#pragma unroll
      for (int jm = 0; jm < 4; ++jm) {
        asm("v_cvt_pk_bf16_f32 %0, %1, %2" : "=v"(pk[m][jm][0]) : "v"(sa[m][jm][0]), "v"(sa[m][jm][1]));
        asm("v_cvt_pk_bf16_f32 %0, %1, %2" : "=v"(pk[m][jm][1]) : "v"(sa[m][jm][2]), "v"(sa[m][jm][3]));
      }
    const char* vc0 = vbL0 + cur * 16384;
    const char* vc1 = vbL1 + cur * 16384;
    __builtin_amdgcn_s_setprio(1);
#pragma unroll
    for (int kk = 0; kk < 2; ++kk) {
      short8 pt[2];
#pragma unroll
      for (int m = 0; m < 2; ++m) {
        union { unsigned u[4]; short8 s; } pp;
        pp.u[0] = pk[m][kk][0];     pp.u[1] = pk[m][kk][1];
        pp.u[2] = pk[m][kk + 2][0]; pp.u[3] = pk[m][kk + 2][1];
        pt[m] = pp.s;
      }
      const char* vc = kk ? vc1 : vc0;
#pragma unroll
      for (int jd = 0; jd < 8; ++jd) {
        short8 bb = *(const short8*)(vc + jd * 2048);
#pragma unroll
        for (int m = 0; m < 2; ++m)
          acc[m][jd] = __builtin_amdgcn_mfma_f32_16x16x32_bf16(bb, pt[m], acc[m][jd], 0, 0, 0);
      }
#pragma unroll
      for (int m = 0; m < 2; ++m)
        accl[m] = __builtin_amdgcn_mfma_f32_16x16x32_bf16(ones, pt[m], accl[m], 0, 0, 0);
    }
    __builtin_amdgcn_s_setprio(0);
    cur ^= 1;
  }
  __syncthreads();
  float* Ot = (float*)smem;
  float* ot = Ot + wid * 16 * 132;
  u16* Obase = Op + (long)kh * 8388608;
#pragma unroll
  for (int m = 0; m < 2; ++m) {
#pragma unroll
    for (int jd = 0; jd < 8; ++jd)
      *(f32x4*)&ot[fr * 132 + jd * 16 + gs * 4] = acc[m][jd];
    asm volatile("s_waitcnt lgkmcnt(0)" ::: "memory");
    __builtin_amdgcn_sched_barrier(0);
    const int q = qtm + wid * 32 + m * 16 + (lane >> 2);
    u16* od = Obase + ((long)(b * 4096 + q) * 8 + h) * 128 + (lane & 3) * 32;
#pragma unroll
    for (int j = 0; j < 8; ++j) {
      f32x4 v = *(const f32x4*)&ot[(lane >> 2) * 132 + (lane & 3) * 32 + j * 4];
      short4v sv;
#pragma unroll
      for (int r = 0; r < 4; ++r) sv[r] = (short)f2bf(v[r]);
      *(short4v*)(od + j * 4) = sv;
    }
    asm volatile("s_waitcnt lgkmcnt(0)" ::: "memory");
    __builtin_amdgcn_sched_barrier(0);
    if (gs == 0) {
      const int q2 = qtm + wid * 32 + m * 16 + fr;
      ((float2*)mlb)[(long)kh * 65536 + (long)(b * 4096 + q2) * 8 + h] =
          make_float2(mr[m], accl[m][0]);
    }
  }
}

// ---------- fused router + flash-combine + contra-flow + head mixing ----------
__global__ __launch_bounds__(256) void router_mix(const u16* __restrict__ hid,
    const float* __restrict__ rb1, const float* __restrict__ rW2, const float* __restrict__ rb2,
    const float* __restrict__ al, const u16* __restrict__ Op, const float* __restrict__ mlb,
    u16* __restrict__ mixed) {
  const int tok = blockIdx.x;
  const int b = tok >> 12, t = tok & 4095;
  const int rtok = b * 4096 + (4095 - t);
  const int tid = threadIdx.x;
  __shared__ float lred[4][8];
  __shared__ float wgt[8];
  __shared__ float ta[8];
  __shared__ float el[2][8][2];
  const float hv = fmaxf(bf2f(hid[(long)tok * 256 + tid]) + rb1[tid], 0.f);
  const float4* w4 = (const float4*)(rW2 + tid * 8);
  const float4 wa = w4[0], wb = w4[1];
  float part[8] = {hv * wa.x, hv * wa.y, hv * wa.z, hv * wa.w,
                   hv * wb.x, hv * wb.y, hv * wb.z, hv * wb.w};
#pragma unroll
  for (int h = 0; h < 8; ++h) {
    float v = part[h];
#pragma unroll
    for (int o = 1; o < 64; o <<= 1) v += __shfl_xor(v, o);
    if ((tid & 63) == 0) lred[tid >> 6][h] = v;
  }
  if (tid >= 64 && tid < 80) {
    const int j = tid - 64;
    const int h = j & 7, which = j >> 3;
    const long tk = which ? rtok : tok;
    const float2 a = ((const float2*)mlb)[tk * 8 + h];
    const float2 c = ((const float2*)mlb)[65536 + tk * 8 + h];
    const float M = fmaxf(a.x, c.x);
    const float w1 = exp2f(a.x - M), w2 = exp2f(c.x - M);
    const float inv = 1.f / (w1 * a.y + w2 * c.y);
    el[which][h][0] = w1 * inv;
    el[which][h][1] = w2 * inv;
  }
  __syncthreads();
  if (tid < 8) ta[tid] = tanhf(al[tid]);
  if (tid == 0) {
    float lg[8], m = -1e30f;
#pragma unroll
    for (int h = 0; h < 8; ++h) {
      lg[h] = lred[0][h] + lred[1][h] + lred[2][h] + lred[3][h] + rb2[h];
      m = fmaxf(m, lg[h]);
    }
    float s = 0.f;
#pragma unroll
    for (int h = 0; h < 8; ++h) { lg[h] = __expf(lg[h] - m); s += lg[h]; }
    const float inv = 1.f / s;
#pragma unroll
    for (int h = 0; h < 8; ++h) wgt[h] = lg[h] * inv;
  }
  __syncthreads();
  if (tid < 128) {
    const long base = (long)tok * 1024 + tid;
    const long rbase = (long)rtok * 1024 + tid;
    float acc = 0.f;
#pragma unroll
    for (int h = 0; h < 8; ++h) {
      const float o = el[0][h][0] * bf2f(Op[base + h * 128]) +
                      el[0][h][1] * bf2f(Op[8388608 + base + h * 128]);
      const float orv = el[1][h][0] * bf2f(Op[rbase + h * 128]) +
                        el[1][h][1] * bf2f(Op[8388608 + rbase + h * 128]);
      acc += wgt[h] * (o + ta[h] * orv);
    }
    mixed[(long)tok * 128 + tid] = f2bf(acc);
  }
}

extern "C" void kernel_launch(void* const* d_in, const int* in_sizes, int n_in,
                              void* d_out, int out_size, void* d_ws, size_t ws_size,
                              hipStream_t stream) {
  const float* x    = (const float*)d_in[0];
  const float* Wq   = (const float*)d_in[1];
  const float* Wk   = (const float*)d_in[2];
  const float* Wv   = (const float*)d_in[3];
  const float* bg   = (const float*)d_in[4];
  const float* al   = (const float*)d_in[5];
  const float* rW1  = (const float*)d_in[6];
  const float* rb1  = (const float*)d_in[7];
  const float* rW2  = (const float*)d_in[8];
  const float* rb2  = (const float*)d_in[9];
  const float* Wout = (const float*)d_in[10];
  float* out = (float*)d_out;

  // ---- arena (lifetime overlays, ~97 MB) ----
  const size_t MB = 1u << 20;
  char* w = (char*)d_ws;
  u16*   xbf   = (u16*)(w + 0);            // 16 MB [P0-P1]
  u16*   Op    = (u16*)(w + 0);            // 32 MB bf16 [2][...] [P4-P5] overlays dead pools
  u16*   Qb    = (u16*)(w + 32 * MB);      // 16 MB [P1-P4]
  u16*   Kp    = (u16*)(w + 48 * MB);      // 7.5MB [P3-P4]
  u16*   KT    = (u16*)(w + 63 * MB);      // 7.5MB [P1-P3]
  u16*   VT    = (u16*)(w + 70 * MB + 512 * 1024); // 7.5MB [P1-P4]
  u16*   hid   = (u16*)(w + 78 * MB);      //  4 MB bf16 [P1-P5]
  u16*   wqT   = (u16*)(w + 86 * MB);      //  2 MB
  u16*   kvT   = (u16*)(w + 88 * MB);      //  4 MB
  u16*   rw1T  = (u16*)(w + 92 * MB);      // 512 KB
  u16*   woutT = (u16*)(w + 92 * MB + 512 * 1024);   // 256 KB
  u16*   crep  = (u16*)(w + 92 * MB + 768 * 1024);   // 257 KB
  u16*   mixed = (u16*)(w + 93 * MB + 512 * 1024);   //  2 MB
  float* mlbuf = (float*)(w + 95 * MB + 512 * 1024); //  1 MB [P4-P5]
  u16*   xp2   = (u16*)(w + 16 * MB);
  u16*   xp4   = (u16*)(w + 24 * MB);
  u16*   xp8   = (u16*)(w + 28 * MB);

  // P0: pooling + LDS-tiled weight prep + irfft (one launch, 4608 blocks)
  prep_all<<<dim3(4608), dim3(256), 0, stream>>>(x, Wq, Wk, Wv, rW1, Wout, bg,
      xbf, xp2, xp4, xp8, wqT, kvT, rw1T, woutT, crep);

  // P1: Q + KV (coalesced direct-transposed KT/VT) + router hidden (bf16), one launch
  gemm_p1<<<dim3(1120), dim3(256), 0, stream>>>(xbf, wqT, kvT, rw1T, Qb, KT, VT, hid);

  // P3: circulant conv (BK=128, compact XCD-chunked 240-block grid)
  conv_k<<<dim3(240), dim3(256), 0, stream>>>(crep, KT, Kp);

  // P4: flash v7 (split-K, 1024 jobs, v4 inner loop; bf16 partials + ml)
  flash<<<dim3(1024), dim3(256), 0, stream>>>(Qb, Kp, VT, Op, mlbuf);

  // P5: router + flash-combine + mix, then output projection
  router_mix<<<dim3(8192), dim3(256), 0, stream>>>(hid, rb1, rW2, rb2, al, Op, mlbuf, mixed);
  gemm_bt<false><<<dim3(64, 8), dim3(256), 0, stream>>>(mixed, woutT, out,
      128, 128, 128, 1024, 0, 0, 0, 1.f);
}